// Round 3
// baseline (2655.547 us; speedup 1.0000x reference)
//
#include <hip/hip_runtime.h>
#include <math.h>

#define NPTS   8192
#define INCH   1024
#define FDIM   128
#define KNN    10

// ---------------------------------------------------------------------------
// sq[i] = sum_d x[i][d]^2   (one wave per row)  -- unchanged (bit-identical)
// ---------------------------------------------------------------------------
__global__ __launch_bounds__(256) void sq_kernel(const float* __restrict__ x,
                                                 float* __restrict__ sq) {
    int wave = threadIdx.x >> 6;
    int lane = threadIdx.x & 63;
    int row  = blockIdx.x * 4 + wave;
    const float4* xr = (const float4*)(x + (size_t)row * INCH);
    float s = 0.f;
    #pragma unroll
    for (int i = 0; i < 4; ++i) {
        float4 v = xr[lane + i * 64];
        s += v.x * v.x + v.y * v.y + v.z * v.z + v.w * v.w;
    }
    #pragma unroll
    for (int o = 32; o; o >>= 1) s += __shfl_xor(s, o);
    if (lane == 0) sq[row] = s;
}

// ---------------------------------------------------------------------------
// Distance chunk: D[(i-r0)][j] = sq[i] + sq[j] - 2*dot(x_i, x_j)
// 128x128 tile, 256 threads, 8x8 per thread, BK=16.
// Round-3: LDS double-buffer (1 barrier/K-step), 2-step global prefetch,
// granule-XOR swizzle on Bs (kills the 4-way read conflict).
// FMA accumulation order per output element is BIT-IDENTICAL to round-2.
// ---------------------------------------------------------------------------
__global__ __launch_bounds__(256, 4) void dist_kernel(const float* __restrict__ x,
                                                      const float* __restrict__ sq,
                                                      float* __restrict__ D,
                                                      int r0) {
    __shared__ float As[2][16][128];
    __shared__ float Bs[2][16][128];   // granule-swizzled: g' = g ^ ((g>>3)&1)
    int tid = threadIdx.x;
    int tx = tid & 15, ty = tid >> 4;
    int rowBase = r0 + blockIdx.y * 128;
    int colBase = blockIdx.x * 128;

    float acc[8][8];
    #pragma unroll
    for (int i = 0; i < 8; ++i)
        #pragma unroll
        for (int j = 0; j < 8; ++j) acc[i][j] = 0.f;

    int lr = tid >> 1;          // 0..127
    int lk = (tid & 1) * 8;     // 0 or 8
    const float* Arow = x + (size_t)(rowBase + lr) * INCH + lk;
    const float* Brow = x + (size_t)(colBase + lr) * INCH + lk;

    // Bs store granules for this thread (two 16B granules within a 512B row)
    int gs0 = 2 * lr;            // wait: B store uses same (lr,lk) gather as A
    // -- B is staged with the same per-thread (lr, lk) pattern as A; granule
    //    of a float4 at float-col (lk + 0|4) is (lk>>2)+0|1.
    int bg0 = (lk >> 2);                 // granule of b0 within row
    int bg1 = bg0 + 1;                   // granule of b1
    (void)gs0;
    // swizzled float offsets (granule -> granule ^ bit3)
    int bs0 = (bg0 ^ ((bg0 >> 3) & 1)) << 2;
    int bs1 = (bg1 ^ ((bg1 >> 3) & 1)) << 2;

    // read-side swizzled offsets (loop-invariant per thread)
    int rg0 = 2 * tx, rg1 = 2 * tx + 1;
    int rs0 = (rg0 ^ ((rg0 >> 3) & 1)) << 2;
    int rs1 = (rg1 ^ ((rg1 >> 3) & 1)) << 2;

    float4 a0, a1, b0, b1;

    // prologue: load step 0, stage into buf 0, load step 1
    a0 = *(const float4*)(Arow + 0);
    a1 = *(const float4*)(Arow + 4);
    b0 = *(const float4*)(Brow + 0);
    b1 = *(const float4*)(Brow + 4);
    {
        As[0][lk + 0][lr] = a0.x; As[0][lk + 1][lr] = a0.y;
        As[0][lk + 2][lr] = a0.z; As[0][lk + 3][lr] = a0.w;
        As[0][lk + 4][lr] = a1.x; As[0][lk + 5][lr] = a1.y;
        As[0][lk + 6][lr] = a1.z; As[0][lk + 7][lr] = a1.w;
        // Bs staged row-major by k like As, but vector-stored with swizzle.
        // Thread holds B[k=lk..lk+7][col=lr]; store scalar (col-major pattern
        // identical to As; swizzle applies to READ rows).  NOTE: Bs rows are
        // indexed [k][col]; the 4-way conflict is on READS (col granules), so
        // we swizzle column granules.  Scalar stores here: col lr -> granule
        // lr>>2, swizzled.
        int cg = lr >> 2;
        int sc = ((cg ^ ((cg >> 3) & 1)) << 2) | (lr & 3);
        Bs[0][lk + 0][sc] = b0.x; Bs[0][lk + 1][sc] = b0.y;
        Bs[0][lk + 2][sc] = b0.z; Bs[0][lk + 3][sc] = b0.w;
        Bs[0][lk + 4][sc] = b1.x; Bs[0][lk + 5][sc] = b1.y;
        Bs[0][lk + 6][sc] = b1.z; Bs[0][lk + 7][sc] = b1.w;
    }
    a0 = *(const float4*)(Arow + 16);
    a1 = *(const float4*)(Arow + 20);
    b0 = *(const float4*)(Brow + 16);
    b1 = *(const float4*)(Brow + 20);
    __syncthreads();

    int cg = lr >> 2;
    int sc = ((cg ^ ((cg >> 3) & 1)) << 2) | (lr & 3);

    for (int t = 0; t < 64; ++t) {
        int cur = t & 1;
        int nxt = cur ^ 1;
        if (t < 63) {
            // stage step t+1 (regs) into buf nxt
            As[nxt][lk + 0][lr] = a0.x; As[nxt][lk + 1][lr] = a0.y;
            As[nxt][lk + 2][lr] = a0.z; As[nxt][lk + 3][lr] = a0.w;
            As[nxt][lk + 4][lr] = a1.x; As[nxt][lk + 5][lr] = a1.y;
            As[nxt][lk + 6][lr] = a1.z; As[nxt][lk + 7][lr] = a1.w;
            Bs[nxt][lk + 0][sc] = b0.x; Bs[nxt][lk + 1][sc] = b0.y;
            Bs[nxt][lk + 2][sc] = b0.z; Bs[nxt][lk + 3][sc] = b0.w;
            Bs[nxt][lk + 4][sc] = b1.x; Bs[nxt][lk + 5][sc] = b1.y;
            Bs[nxt][lk + 6][sc] = b1.z; Bs[nxt][lk + 7][sc] = b1.w;
        }
        if (t < 62) {
            int k0 = (t + 2) * 16;
            a0 = *(const float4*)(Arow + k0);
            a1 = *(const float4*)(Arow + k0 + 4);
            b0 = *(const float4*)(Brow + k0);
            b1 = *(const float4*)(Brow + k0 + 4);
        }
        #pragma unroll
        for (int k = 0; k < 16; ++k) {
            float4 av0 = *(const float4*)&As[cur][k][ty * 8];
            float4 av1 = *(const float4*)&As[cur][k][ty * 8 + 4];
            float4 bv0 = *(const float4*)(&Bs[cur][k][0] + rs0);
            float4 bv1 = *(const float4*)(&Bs[cur][k][0] + rs1);
            float ar[8] = {av0.x, av0.y, av0.z, av0.w, av1.x, av1.y, av1.z, av1.w};
            float br[8] = {bv0.x, bv0.y, bv0.z, bv0.w, bv1.x, bv1.y, bv1.z, bv1.w};
            #pragma unroll
            for (int i = 0; i < 8; ++i)
                #pragma unroll
                for (int j = 0; j < 8; ++j) acc[i][j] += ar[i] * br[j];
        }
        __syncthreads();
    }

    float sqa[8], sqb[8];
    #pragma unroll
    for (int i = 0; i < 8; ++i) sqa[i] = sq[rowBase + ty * 8 + i];
    #pragma unroll
    for (int j = 0; j < 8; ++j) sqb[j] = sq[colBase + tx * 8 + j];

    #pragma unroll
    for (int i = 0; i < 8; ++i) {
        float4 o0, o1;
        o0.x = sqa[i] + sqb[0] - 2.f * acc[i][0];
        o0.y = sqa[i] + sqb[1] - 2.f * acc[i][1];
        o0.z = sqa[i] + sqb[2] - 2.f * acc[i][2];
        o0.w = sqa[i] + sqb[3] - 2.f * acc[i][3];
        o1.x = sqa[i] + sqb[4] - 2.f * acc[i][4];
        o1.y = sqa[i] + sqb[5] - 2.f * acc[i][5];
        o1.z = sqa[i] + sqb[6] - 2.f * acc[i][6];
        o1.w = sqa[i] + sqb[7] - 2.f * acc[i][7];
        size_t o = (size_t)(rowBase + ty * 8 + i - r0) * NPTS + colBase + tx * 8;
        *(float4*)(D + o)     = o0;
        *(float4*)(D + o + 4) = o1;
    }
}

// ---------------------------------------------------------------------------
// Top-10 per row. key = (sortable(dist) << 32) | col ; 10 smallest keys.
// Exact on the given f32 values (unique keys) -> selection is reproducible.
// ---------------------------------------------------------------------------
__global__ __launch_bounds__(256) void topk_kernel(const float* __restrict__ D,
                                                   int* __restrict__ nn,
                                                   int r0) {
    const float* dr = D + (size_t)blockIdx.x * NPTS;
    int tid = threadIdx.x;
    unsigned long long kv[10];
    #pragma unroll
    for (int p = 0; p < 10; ++p) kv[p] = ~0ull;

    for (int j = tid; j < NPTS; j += 256) {
        float d = dr[j];
        unsigned u = __float_as_uint(d);
        u = (u & 0x80000000u) ? ~u : (u | 0x80000000u);
        unsigned long long key = ((unsigned long long)u << 32) | (unsigned)j;
        if (key < kv[9]) {
            unsigned long long cur = key;
            #pragma unroll
            for (int p = 0; p < 10; ++p) {
                unsigned long long lo = kv[p] < cur ? kv[p] : cur;
                unsigned long long hi = kv[p] < cur ? cur : kv[p];
                kv[p] = lo; cur = hi;
            }
        }
    }

    __shared__ unsigned long long sm4[4];
    __shared__ unsigned long long smWin;
    int lane = tid & 63, wid = tid >> 6;

    for (int r = 0; r < KNN; ++r) {
        unsigned long long h = kv[0];
        #pragma unroll
        for (int o = 32; o; o >>= 1) {
            unsigned long long t = __shfl_xor(h, o);
            h = t < h ? t : h;
        }
        if (lane == 0) sm4[wid] = h;
        __syncthreads();
        if (tid == 0) {
            unsigned long long m = sm4[0];
            #pragma unroll
            for (int i = 1; i < 4; ++i) m = sm4[i] < m ? sm4[i] : m;
            smWin = m;
        }
        __syncthreads();
        unsigned long long m = smWin;
        if (kv[0] == m) {
            #pragma unroll
            for (int p = 0; p < 9; ++p) kv[p] = kv[p + 1];
            kv[9] = ~0ull;
        }
        if (tid == 0)
            nn[(size_t)(r0 + blockIdx.x) * KNN + r] = (int)(m & 0xffffffffu);
        __syncthreads();
    }
}

// ---------------------------------------------------------------------------
// Dv counts (node degrees)
// ---------------------------------------------------------------------------
__global__ void count_kernel(const int* __restrict__ nn, int* __restrict__ Dv) {
    int t = blockIdx.x * 256 + threadIdx.x;
    if (t < NPTS * KNN) atomicAdd(&Dv[nn[t]], 1);
}

// ---------------------------------------------------------------------------
// C[M x 128] = A[M x Kdim] @ B[Kdim x 128], 64x128 tile, 4x8 per thread
// ---------------------------------------------------------------------------
__global__ __launch_bounds__(256) void gemm_n128_kernel(const float* __restrict__ A,
                                                        const float* __restrict__ Bm,
                                                        float* __restrict__ C,
                                                        int Kdim) {
    __shared__ float As[16][64];
    __shared__ float Bs[16][128];
    int tid = threadIdx.x;
    int tx = tid & 15, ty = tid >> 4;
    int rowBase = blockIdx.x * 64;
    float acc[4][8];
    #pragma unroll
    for (int i = 0; i < 4; ++i)
        #pragma unroll
        for (int j = 0; j < 8; ++j) acc[i][j] = 0.f;

    int lr = tid >> 2, lk = (tid & 3) * 4;   // A: 64 rows x 16 k
    int bk = tid >> 4, bc = (tid & 15) * 8;  // B: 16 k x 128 cols

    for (int k0 = 0; k0 < Kdim; k0 += 16) {
        float4 av  = *(const float4*)(A + (size_t)(rowBase + lr) * Kdim + k0 + lk);
        float4 bv0 = *(const float4*)(Bm + (size_t)(k0 + bk) * FDIM + bc);
        float4 bv1 = *(const float4*)(Bm + (size_t)(k0 + bk) * FDIM + bc + 4);
        __syncthreads();
        As[lk + 0][lr] = av.x; As[lk + 1][lr] = av.y;
        As[lk + 2][lr] = av.z; As[lk + 3][lr] = av.w;
        *(float4*)&Bs[bk][bc]     = bv0;
        *(float4*)&Bs[bk][bc + 4] = bv1;
        __syncthreads();
        #pragma unroll
        for (int k = 0; k < 16; ++k) {
            float4 a  = *(const float4*)&As[k][ty * 4];
            float4 c0 = *(const float4*)&Bs[k][tx * 8];
            float4 c1 = *(const float4*)&Bs[k][tx * 8 + 4];
            float ar[4] = {a.x, a.y, a.z, a.w};
            float br[8] = {c0.x, c0.y, c0.z, c0.w, c1.x, c1.y, c1.z, c1.w};
            #pragma unroll
            for (int i = 0; i < 4; ++i)
                #pragma unroll
                for (int j = 0; j < 8; ++j) acc[i][j] += ar[i] * br[j];
        }
    }
    int row = rowBase + ty * 4;
    int col = tx * 8;
    #pragma unroll
    for (int i = 0; i < 4; ++i) {
        float4 o0 = {acc[i][0], acc[i][1], acc[i][2], acc[i][3]};
        float4 o1 = {acc[i][4], acc[i][5], acc[i][6], acc[i][7]};
        *(float4*)(C + (size_t)(row + i) * FDIM + col)     = o0;
        *(float4*)(C + (size_t)(row + i) * FDIM + col + 4) = o1;
    }
}

// ---------------------------------------------------------------------------
// edge_ft[e][c] = mean_{k} t[nn[e][k]][c]   (De == KNN exactly)
// ---------------------------------------------------------------------------
__global__ __launch_bounds__(256) void edge_kernel(const float* __restrict__ t,
                                                   const int* __restrict__ nn,
                                                   float* __restrict__ e) {
    int eid = blockIdx.x * 2 + (threadIdx.x >> 7);
    int c = threadIdx.x & 127;
    const int* nnr = nn + (size_t)eid * KNN;
    float s = 0.f;
    #pragma unroll
    for (int k = 0; k < KNN; ++k)
        s += t[(size_t)nnr[k] * FDIM + c];
    e[(size_t)eid * FDIM + c] = s * (1.f / (float)KNN);
}

// ---------------------------------------------------------------------------
// Edge-parallel scatter: for incidence pair t, v=nn[t], e=t/KNN:
//   acc[v][c] += edge_ft[e][c]   (atomic; balanced over pairs)
// ---------------------------------------------------------------------------
__global__ __launch_bounds__(256) void scatter_kernel(const float* __restrict__ e,
                                                      const int* __restrict__ nn,
                                                      float* __restrict__ acc) {
    int t = blockIdx.x * 2 + (threadIdx.x >> 7);   // incidence pair id
    int c = threadIdx.x & 127;
    int v = nn[t];
    int eid = t / KNN;
    float val = e[(size_t)eid * FDIM + c];
    atomicAdd(&acc[(size_t)v * FDIM + c], val);
}

// ---------------------------------------------------------------------------
// node_ft[v][c] = acc[v][c] / max(Dv,1) + bias[c], leaky relu
// ---------------------------------------------------------------------------
__global__ __launch_bounds__(256) void finish_kernel(const float* __restrict__ acc,
                                                     const int* __restrict__ Dv,
                                                     const float* __restrict__ bias,
                                                     float* __restrict__ out) {
    int v = blockIdx.x * 2 + (threadIdx.x >> 7);
    int c = threadIdx.x & 127;
    int cnt = Dv[v];
    float dn = cnt > 1 ? (float)cnt : 1.f;
    float s = acc[(size_t)v * FDIM + c] / dn + bias[c];
    s = (s >= 0.f) ? s : 0.01f * s;
    out[(size_t)v * FDIM + c] = s;
}

// ---------------------------------------------------------------------------
// pooling partials: part[128][128]; block b reduces rows b*128..b*128+127
// ---------------------------------------------------------------------------
__global__ __launch_bounds__(256) void pool_kernel(const float* __restrict__ feats,
                                                   float* __restrict__ part) {
    int c = threadIdx.x & 127;
    int half = threadIdx.x >> 7;
    int r0 = blockIdx.x * 128 + half;
    float s = 0.f;
    for (int i = 0; i < 64; ++i)
        s += feats[(size_t)(r0 + 2 * i) * FDIM + c];
    part[(size_t)(blockIdx.x * 2 + half) * FDIM + c] = s;
}

__global__ __launch_bounds__(128) void final_kernel(const float* __restrict__ part,
                                                    const float* __restrict__ fcw,
                                                    const float* __restrict__ fcb,
                                                    float* __restrict__ out) {
    __shared__ float pool[FDIM];
    int c = threadIdx.x;
    float s = 0.f;
    for (int i = 0; i < 128; ++i)
        s += part[(size_t)i * FDIM + c];
    s *= (1.f / (float)NPTS);
    out[2 + (size_t)NPTS * FDIM + c] = s;   // feats_pool
    pool[c] = s;
    __syncthreads();
    if (c < 2) {
        float z = fcb[c];
        for (int k = 0; k < FDIM; ++k)
            z += pool[k] * fcw[c * FDIM + k];
        out[c] = 1.f / (1.f + expf(-z));
    }
}

// ---------------------------------------------------------------------------
extern "C" void kernel_launch(void* const* d_in, const int* in_sizes, int n_in,
                              void* d_out, int out_size, void* d_ws, size_t ws_size,
                              hipStream_t stream) {
    const float* x   = (const float*)d_in[0];
    const float* th0 = (const float*)d_in[1];
    const float* b0  = (const float*)d_in[2];
    const float* th1 = (const float*)d_in[3];
    const float* b1  = (const float*)d_in[4];
    const float* fcw = (const float*)d_in[5];
    const float* fcb = (const float*)d_in[6];
    float* out = (float*)d_out;

    char* w = (char*)d_ws;
    size_t off = 0;
    auto alloc = [&](size_t bytes) -> void* {
        void* p = w + off;
        off = (off + bytes + 255) & ~(size_t)255;
        return p;
    };
    float* sq    = (float*)alloc(NPTS * 4);
    int*   nn    = (int*)  alloc(NPTS * KNN * 4);
    int*   Dv    = (int*)  alloc(NPTS * 4);
    float* tbuf  = (float*)alloc((size_t)NPTS * FDIM * 4);
    float* ebuf  = (float*)alloc((size_t)NPTS * FDIM * 4);
    float* hbuf  = (float*)alloc((size_t)NPTS * FDIM * 4);
    float* accb  = (float*)alloc((size_t)NPTS * FDIM * 4);
    float* part  = (float*)alloc(128 * FDIM * 4);

    size_t rem = ws_size > off ? ws_size - off : 0;
    long long chMax = (long long)(rem / ((size_t)NPTS * 4));
    int CH = (int)(chMax > 4096 ? 4096 : chMax);
    CH &= ~127;
    if (CH < 128) CH = 128;   // minimum viable chunk
    float* Dchunk = (float*)(w + off);

    hipMemsetAsync(Dv, 0, NPTS * 4, stream);
    sq_kernel<<<NPTS / 4, 256, 0, stream>>>(x, sq);

    for (int r0 = 0; r0 < NPTS; r0 += CH) {
        int ch = NPTS - r0 < CH ? NPTS - r0 : CH;
        dist_kernel<<<dim3(NPTS / 128, ch / 128), 256, 0, stream>>>(x, sq, Dchunk, r0);
        topk_kernel<<<ch, 256, 0, stream>>>(Dchunk, nn, r0);
    }

    count_kernel<<<(NPTS * KNN + 255) / 256, 256, 0, stream>>>(nn, Dv);

    // layer 0
    gemm_n128_kernel<<<NPTS / 64, 256, 0, stream>>>(x, th0, tbuf, INCH);
    edge_kernel<<<NPTS / 2, 256, 0, stream>>>(tbuf, nn, ebuf);
    hipMemsetAsync(accb, 0, (size_t)NPTS * FDIM * 4, stream);
    scatter_kernel<<<NPTS * KNN / 2, 256, 0, stream>>>(ebuf, nn, accb);
    finish_kernel<<<NPTS / 2, 256, 0, stream>>>(accb, Dv, b0, hbuf);

    // layer 1 -> feats written directly into out+2
    gemm_n128_kernel<<<NPTS / 64, 256, 0, stream>>>(hbuf, th1, tbuf, FDIM);
    edge_kernel<<<NPTS / 2, 256, 0, stream>>>(tbuf, nn, ebuf);
    hipMemsetAsync(accb, 0, (size_t)NPTS * FDIM * 4, stream);
    scatter_kernel<<<NPTS * KNN / 2, 256, 0, stream>>>(ebuf, nn, accb);
    finish_kernel<<<NPTS / 2, 256, 0, stream>>>(accb, Dv, b1, out + 2);

    pool_kernel<<<64, 256, 0, stream>>>(out + 2, part);
    final_kernel<<<1, 128, 0, stream>>>(part, fcw, fcb, out);
}

// Round 4
// 2138.831 us; speedup vs baseline: 1.2416x; 1.2416x over previous
//
#include <hip/hip_runtime.h>
#include <math.h>

#define NPTS   8192
#define INCH   1024
#define FDIM   128
#define KNN    10
#define NTB    (NPTS / 128)   // 64 col tiles

// compare-exchange: a=min, b=max
#define CE(a,b) do { unsigned long long lo_ = (a)<(b)?(a):(b); \
                     unsigned long long hi_ = (a)<(b)?(b):(a); \
                     (a)=lo_; (b)=hi_; } while(0)

// ---------------------------------------------------------------------------
// sq[i] = sum_d x[i][d]^2   (one wave per row)
// ---------------------------------------------------------------------------
__global__ __launch_bounds__(256) void sq_kernel(const float* __restrict__ x,
                                                 float* __restrict__ sq) {
    int wave = threadIdx.x >> 6;
    int lane = threadIdx.x & 63;
    int row  = blockIdx.x * 4 + wave;
    const float4* xr = (const float4*)(x + (size_t)row * INCH);
    float s = 0.f;
    #pragma unroll
    for (int i = 0; i < 4; ++i) {
        float4 v = xr[lane + i * 64];
        s += v.x * v.x + v.y * v.y + v.z * v.z + v.w * v.w;
    }
    #pragma unroll
    for (int o = 32; o; o >>= 1) s += __shfl_xor(s, o);
    if (lane == 0) sq[row] = s;
}

// ---------------------------------------------------------------------------
// Fused distance + per-tile exact top-10.
// 128x128 tile, 256 threads, 8x8 per thread (cols split tx*4 and 64+tx*4),
// BK=16, round-2 staging (2 barriers/K-step). Per row r of the tile, the 16
// owner lanes merge their sorted-8 lists via shfl bitonic -> top-10 of the
// 128 cols, written as sortable u64 keys to cand[r][bx][10].
// FMA accumulation per output element is k-ascending, identical to round 2.
// ---------------------------------------------------------------------------
__global__ __launch_bounds__(256) void distknn_kernel(const float* __restrict__ x,
                                                      const float* __restrict__ sq,
                                                      unsigned long long* __restrict__ cand) {
    __shared__ float As[16][128];
    __shared__ float Bs[16][128];
    int tid = threadIdx.x;
    int tx = tid & 15, ty = tid >> 4;
    int rowBase = blockIdx.y * 128;
    int colBase = blockIdx.x * 128;

    float acc[8][8];
    #pragma unroll
    for (int i = 0; i < 8; ++i)
        #pragma unroll
        for (int j = 0; j < 8; ++j) acc[i][j] = 0.f;

    int lr = tid >> 1;          // 0..127
    int lk = (tid & 1) * 8;     // 0 or 8
    const float* Arow = x + (size_t)(rowBase + lr) * INCH + lk;
    const float* Brow = x + (size_t)(colBase + lr) * INCH + lk;

    for (int k0 = 0; k0 < INCH; k0 += 16) {
        float4 a0 = *(const float4*)(Arow + k0);
        float4 a1 = *(const float4*)(Arow + k0 + 4);
        float4 b0 = *(const float4*)(Brow + k0);
        float4 b1 = *(const float4*)(Brow + k0 + 4);
        __syncthreads();
        As[lk + 0][lr] = a0.x; As[lk + 1][lr] = a0.y;
        As[lk + 2][lr] = a0.z; As[lk + 3][lr] = a0.w;
        As[lk + 4][lr] = a1.x; As[lk + 5][lr] = a1.y;
        As[lk + 6][lr] = a1.z; As[lk + 7][lr] = a1.w;
        Bs[lk + 0][lr] = b0.x; Bs[lk + 1][lr] = b0.y;
        Bs[lk + 2][lr] = b0.z; Bs[lk + 3][lr] = b0.w;
        Bs[lk + 4][lr] = b1.x; Bs[lk + 5][lr] = b1.y;
        Bs[lk + 6][lr] = b1.z; Bs[lk + 7][lr] = b1.w;
        __syncthreads();
        #pragma unroll
        for (int k = 0; k < 16; ++k) {
            float4 av0 = *(const float4*)&As[k][ty * 8];
            float4 av1 = *(const float4*)&As[k][ty * 8 + 4];
            float4 bv0 = *(const float4*)&Bs[k][tx * 4];        // granule tx
            float4 bv1 = *(const float4*)&Bs[k][64 + tx * 4];   // granule 16+tx
            float ar[8] = {av0.x, av0.y, av0.z, av0.w, av1.x, av1.y, av1.z, av1.w};
            float br[8] = {bv0.x, bv0.y, bv0.z, bv0.w, bv1.x, bv1.y, bv1.z, bv1.w};
            #pragma unroll
            for (int i = 0; i < 8; ++i)
                #pragma unroll
                for (int j = 0; j < 8; ++j) acc[i][j] += ar[i] * br[j];
        }
    }

    float sqa[8], sqb[8];
    #pragma unroll
    for (int i = 0; i < 8; ++i) sqa[i] = sq[rowBase + ty * 8 + i];
    #pragma unroll
    for (int j = 0; j < 4; ++j) {
        sqb[j]     = sq[colBase + tx * 4 + j];
        sqb[j + 4] = sq[colBase + 64 + tx * 4 + j];
    }
    unsigned cb0 = colBase + tx * 4;
    unsigned cb1 = colBase + 64 + tx * 4;

    #pragma unroll
    for (int i = 0; i < 8; ++i) {
        unsigned long long L[16];
        #pragma unroll
        for (int j = 0; j < 8; ++j) {
            float dval = sqa[i] + sqb[j] - 2.f * acc[i][j];
            unsigned u = __float_as_uint(dval);
            u = (u & 0x80000000u) ? ~u : (u | 0x80000000u);
            unsigned col = (j < 4) ? (cb0 + j) : (cb1 + (j - 4));
            L[j] = ((unsigned long long)u << 32) | col;
        }
        // Batcher sort-8 ascending (19 CE)
        CE(L[0],L[1]); CE(L[2],L[3]); CE(L[4],L[5]); CE(L[6],L[7]);
        CE(L[0],L[2]); CE(L[1],L[3]); CE(L[4],L[6]); CE(L[5],L[7]);
        CE(L[1],L[2]); CE(L[5],L[6]);
        CE(L[0],L[4]); CE(L[1],L[5]); CE(L[2],L[6]); CE(L[3],L[7]);
        CE(L[2],L[4]); CE(L[3],L[5]);
        CE(L[1],L[2]); CE(L[3],L[4]); CE(L[5],L[6]);
        #pragma unroll
        for (int j = 8; j < 16; ++j) L[j] = ~0ull;

        // 4-step bitonic merge across the 16 owner lanes (masks 1,2,4,8)
        #pragma unroll
        for (int s = 0; s < 4; ++s) {
            int mask = 1 << s;
            unsigned long long M[16];
            #pragma unroll
            for (int q = 0; q < 16; ++q) {
                unsigned long long pv = __shfl_xor(L[15 - q], mask);
                M[q] = L[q] < pv ? L[q] : pv;
            }
            // bitonic merge network, length 16, ascending
            CE(M[0],M[8]);  CE(M[1],M[9]);  CE(M[2],M[10]); CE(M[3],M[11]);
            CE(M[4],M[12]); CE(M[5],M[13]); CE(M[6],M[14]); CE(M[7],M[15]);
            CE(M[0],M[4]);  CE(M[1],M[5]);  CE(M[2],M[6]);  CE(M[3],M[7]);
            CE(M[8],M[12]); CE(M[9],M[13]); CE(M[10],M[14]);CE(M[11],M[15]);
            CE(M[0],M[2]);  CE(M[1],M[3]);  CE(M[4],M[6]);  CE(M[5],M[7]);
            CE(M[8],M[10]); CE(M[9],M[11]); CE(M[12],M[14]);CE(M[13],M[15]);
            CE(M[0],M[1]);  CE(M[2],M[3]);  CE(M[4],M[5]);  CE(M[6],M[7]);
            CE(M[8],M[9]);  CE(M[10],M[11]);CE(M[12],M[13]);CE(M[14],M[15]);
            #pragma unroll
            for (int q = 0; q < 16; ++q) L[q] = M[q];
        }

        if (tx == 0) {
            size_t base = ((size_t)(rowBase + ty * 8 + i) * NTB + blockIdx.x) * KNN;
            cand[base + 0] = L[0]; cand[base + 1] = L[1];
            cand[base + 2] = L[2]; cand[base + 3] = L[3];
            cand[base + 4] = L[4]; cand[base + 5] = L[5];
            cand[base + 6] = L[6]; cand[base + 7] = L[7];
            cand[base + 8] = L[8]; cand[base + 9] = L[9];
        }
    }
}

// ---------------------------------------------------------------------------
// Exact global merge: per row, top-10 of the 640 candidate keys.
// ---------------------------------------------------------------------------
__global__ __launch_bounds__(256) void knnmerge_kernel(const unsigned long long* __restrict__ cand,
                                                       int* __restrict__ nn) {
    const unsigned long long* cr = cand + (size_t)blockIdx.x * (NTB * KNN);
    int tid = threadIdx.x;
    unsigned long long kv[10];
    #pragma unroll
    for (int p = 0; p < 10; ++p) kv[p] = ~0ull;

    for (int j = tid; j < NTB * KNN; j += 256) {
        unsigned long long key = cr[j];
        if (key < kv[9]) {
            unsigned long long cur = key;
            #pragma unroll
            for (int p = 0; p < 10; ++p) {
                unsigned long long lo = kv[p] < cur ? kv[p] : cur;
                unsigned long long hi = kv[p] < cur ? cur : kv[p];
                kv[p] = lo; cur = hi;
            }
        }
    }

    __shared__ unsigned long long sm4[4];
    __shared__ unsigned long long smWin;
    int lane = tid & 63, wid = tid >> 6;

    for (int r = 0; r < KNN; ++r) {
        unsigned long long h = kv[0];
        #pragma unroll
        for (int o = 32; o; o >>= 1) {
            unsigned long long t = __shfl_xor(h, o);
            h = t < h ? t : h;
        }
        if (lane == 0) sm4[wid] = h;
        __syncthreads();
        if (tid == 0) {
            unsigned long long m = sm4[0];
            #pragma unroll
            for (int i = 1; i < 4; ++i) m = sm4[i] < m ? sm4[i] : m;
            smWin = m;
        }
        __syncthreads();
        unsigned long long m = smWin;
        if (kv[0] == m) {
            #pragma unroll
            for (int p = 0; p < 9; ++p) kv[p] = kv[p + 1];
            kv[9] = ~0ull;
        }
        if (tid == 0)
            nn[(size_t)blockIdx.x * KNN + r] = (int)(m & 0xffffffffu);
        __syncthreads();
    }
}

// ---------------------------------------------------------------------------
// Dv counts (node degrees)
// ---------------------------------------------------------------------------
__global__ void count_kernel(const int* __restrict__ nn, int* __restrict__ Dv) {
    int t = blockIdx.x * 256 + threadIdx.x;
    if (t < NPTS * KNN) atomicAdd(&Dv[nn[t]], 1);
}

// ---------------------------------------------------------------------------
// C[M x 128] = A[M x Kdim] @ B[Kdim x 128], 64x128 tile, 4x8 per thread
// ---------------------------------------------------------------------------
__global__ __launch_bounds__(256) void gemm_n128_kernel(const float* __restrict__ A,
                                                        const float* __restrict__ Bm,
                                                        float* __restrict__ C,
                                                        int Kdim) {
    __shared__ float As[16][64];
    __shared__ float Bs[16][128];
    int tid = threadIdx.x;
    int tx = tid & 15, ty = tid >> 4;
    int rowBase = blockIdx.x * 64;
    float acc[4][8];
    #pragma unroll
    for (int i = 0; i < 4; ++i)
        #pragma unroll
        for (int j = 0; j < 8; ++j) acc[i][j] = 0.f;

    int lr = tid >> 2, lk = (tid & 3) * 4;   // A: 64 rows x 16 k
    int bk = tid >> 4, bc = (tid & 15) * 8;  // B: 16 k x 128 cols

    for (int k0 = 0; k0 < Kdim; k0 += 16) {
        float4 av  = *(const float4*)(A + (size_t)(rowBase + lr) * Kdim + k0 + lk);
        float4 bv0 = *(const float4*)(Bm + (size_t)(k0 + bk) * FDIM + bc);
        float4 bv1 = *(const float4*)(Bm + (size_t)(k0 + bk) * FDIM + bc + 4);
        __syncthreads();
        As[lk + 0][lr] = av.x; As[lk + 1][lr] = av.y;
        As[lk + 2][lr] = av.z; As[lk + 3][lr] = av.w;
        *(float4*)&Bs[bk][bc]     = bv0;
        *(float4*)&Bs[bk][bc + 4] = bv1;
        __syncthreads();
        #pragma unroll
        for (int k = 0; k < 16; ++k) {
            float4 a  = *(const float4*)&As[k][ty * 4];
            float4 c0 = *(const float4*)&Bs[k][tx * 8];
            float4 c1 = *(const float4*)&Bs[k][tx * 8 + 4];
            float ar[4] = {a.x, a.y, a.z, a.w};
            float br[8] = {c0.x, c0.y, c0.z, c0.w, c1.x, c1.y, c1.z, c1.w};
            #pragma unroll
            for (int i = 0; i < 4; ++i)
                #pragma unroll
                for (int j = 0; j < 8; ++j) acc[i][j] += ar[i] * br[j];
        }
    }
    int row = rowBase + ty * 4;
    int col = tx * 8;
    #pragma unroll
    for (int i = 0; i < 4; ++i) {
        float4 o0 = {acc[i][0], acc[i][1], acc[i][2], acc[i][3]};
        float4 o1 = {acc[i][4], acc[i][5], acc[i][6], acc[i][7]};
        *(float4*)(C + (size_t)(row + i) * FDIM + col)     = o0;
        *(float4*)(C + (size_t)(row + i) * FDIM + col + 4) = o1;
    }
}

// ---------------------------------------------------------------------------
// edge_ft[e][c] = mean_{k} t[nn[e][k]][c]   (De == KNN exactly)
// ---------------------------------------------------------------------------
__global__ __launch_bounds__(256) void edge_kernel(const float* __restrict__ t,
                                                   const int* __restrict__ nn,
                                                   float* __restrict__ e) {
    int eid = blockIdx.x * 2 + (threadIdx.x >> 7);
    int c = threadIdx.x & 127;
    const int* nnr = nn + (size_t)eid * KNN;
    float s = 0.f;
    #pragma unroll
    for (int k = 0; k < KNN; ++k)
        s += t[(size_t)nnr[k] * FDIM + c];
    e[(size_t)eid * FDIM + c] = s * (1.f / (float)KNN);
}

// ---------------------------------------------------------------------------
// Edge-parallel scatter: acc[v][c] += edge_ft[e][c]
// ---------------------------------------------------------------------------
__global__ __launch_bounds__(256) void scatter_kernel(const float* __restrict__ e,
                                                      const int* __restrict__ nn,
                                                      float* __restrict__ acc) {
    int t = blockIdx.x * 2 + (threadIdx.x >> 7);
    int c = threadIdx.x & 127;
    int v = nn[t];
    int eid = t / KNN;
    float val = e[(size_t)eid * FDIM + c];
    atomicAdd(&acc[(size_t)v * FDIM + c], val);
}

// ---------------------------------------------------------------------------
// node_ft[v][c] = acc[v][c] / max(Dv,1) + bias[c], leaky relu
// ---------------------------------------------------------------------------
__global__ __launch_bounds__(256) void finish_kernel(const float* __restrict__ acc,
                                                     const int* __restrict__ Dv,
                                                     const float* __restrict__ bias,
                                                     float* __restrict__ out) {
    int v = blockIdx.x * 2 + (threadIdx.x >> 7);
    int c = threadIdx.x & 127;
    int cnt = Dv[v];
    float dn = cnt > 1 ? (float)cnt : 1.f;
    float s = acc[(size_t)v * FDIM + c] / dn + bias[c];
    s = (s >= 0.f) ? s : 0.01f * s;
    out[(size_t)v * FDIM + c] = s;
}

// ---------------------------------------------------------------------------
// pooling partials
// ---------------------------------------------------------------------------
__global__ __launch_bounds__(256) void pool_kernel(const float* __restrict__ feats,
                                                   float* __restrict__ part) {
    int c = threadIdx.x & 127;
    int half = threadIdx.x >> 7;
    int r0 = blockIdx.x * 128 + half;
    float s = 0.f;
    for (int i = 0; i < 64; ++i)
        s += feats[(size_t)(r0 + 2 * i) * FDIM + c];
    part[(size_t)(blockIdx.x * 2 + half) * FDIM + c] = s;
}

__global__ __launch_bounds__(128) void final_kernel(const float* __restrict__ part,
                                                    const float* __restrict__ fcw,
                                                    const float* __restrict__ fcb,
                                                    float* __restrict__ out) {
    __shared__ float pool[FDIM];
    int c = threadIdx.x;
    float s = 0.f;
    for (int i = 0; i < 128; ++i)
        s += part[(size_t)i * FDIM + c];
    s *= (1.f / (float)NPTS);
    out[2 + (size_t)NPTS * FDIM + c] = s;
    pool[c] = s;
    __syncthreads();
    if (c < 2) {
        float z = fcb[c];
        for (int k = 0; k < FDIM; ++k)
            z += pool[k] * fcw[c * FDIM + k];
        out[c] = 1.f / (1.f + expf(-z));
    }
}

// ---------------------------------------------------------------------------
extern "C" void kernel_launch(void* const* d_in, const int* in_sizes, int n_in,
                              void* d_out, int out_size, void* d_ws, size_t ws_size,
                              hipStream_t stream) {
    const float* x   = (const float*)d_in[0];
    const float* th0 = (const float*)d_in[1];
    const float* b0  = (const float*)d_in[2];
    const float* th1 = (const float*)d_in[3];
    const float* b1  = (const float*)d_in[4];
    const float* fcw = (const float*)d_in[5];
    const float* fcb = (const float*)d_in[6];
    float* out = (float*)d_out;

    char* w = (char*)d_ws;
    size_t off = 0;
    auto alloc = [&](size_t bytes) -> void* {
        void* p = w + off;
        off = (off + bytes + 255) & ~(size_t)255;
        return p;
    };
    float* sq   = (float*)alloc(NPTS * 4);
    int*   nn   = (int*)  alloc(NPTS * KNN * 4);
    int*   Dv   = (int*)  alloc(NPTS * 4);
    float* tbuf = (float*)alloc((size_t)NPTS * FDIM * 4);
    float* ebuf = (float*)alloc((size_t)NPTS * FDIM * 4);
    float* hbuf = (float*)alloc((size_t)NPTS * FDIM * 4);
    float* accb = (float*)alloc((size_t)NPTS * FDIM * 4);
    float* part = (float*)alloc(128 * FDIM * 4);
    unsigned long long* cand =
        (unsigned long long*)alloc((size_t)NPTS * NTB * KNN * 8);   // 42 MB

    hipMemsetAsync(Dv, 0, NPTS * 4, stream);
    sq_kernel<<<NPTS / 4, 256, 0, stream>>>(x, sq);

    distknn_kernel<<<dim3(NTB, NPTS / 128), 256, 0, stream>>>(x, sq, cand);
    knnmerge_kernel<<<NPTS, 256, 0, stream>>>(cand, nn);

    count_kernel<<<(NPTS * KNN + 255) / 256, 256, 0, stream>>>(nn, Dv);

    // layer 0
    gemm_n128_kernel<<<NPTS / 64, 256, 0, stream>>>(x, th0, tbuf, INCH);
    edge_kernel<<<NPTS / 2, 256, 0, stream>>>(tbuf, nn, ebuf);
    hipMemsetAsync(accb, 0, (size_t)NPTS * FDIM * 4, stream);
    scatter_kernel<<<NPTS * KNN / 2, 256, 0, stream>>>(ebuf, nn, accb);
    finish_kernel<<<NPTS / 2, 256, 0, stream>>>(accb, Dv, b0, hbuf);

    // layer 1 -> feats written directly into out+2
    gemm_n128_kernel<<<NPTS / 64, 256, 0, stream>>>(hbuf, th1, tbuf, FDIM);
    edge_kernel<<<NPTS / 2, 256, 0, stream>>>(tbuf, nn, ebuf);
    hipMemsetAsync(accb, 0, (size_t)NPTS * FDIM * 4, stream);
    scatter_kernel<<<NPTS * KNN / 2, 256, 0, stream>>>(ebuf, nn, accb);
    finish_kernel<<<NPTS / 2, 256, 0, stream>>>(accb, Dv, b1, out + 2);

    pool_kernel<<<64, 256, 0, stream>>>(out + 2, part);
    final_kernel<<<1, 128, 0, stream>>>(part, fcw, fcb, out);
}

// Round 5
// 824.779 us; speedup vs baseline: 3.2197x; 2.5932x over previous
//
#include <hip/hip_runtime.h>
#include <math.h>

#define NPTS  8192
#define INCH  1024
#define FDIM  128
#define KNN   10
#define NCAND 16

typedef __attribute__((ext_vector_type(8))) __bf16          bf16x8;
typedef __attribute__((ext_vector_type(4))) float           f32x4;
typedef __attribute__((ext_vector_type(8))) unsigned short  us8;

// ---------------------------------------------------------------------------
// sq[i] = sum_d x[i][d]^2   (one wave per row)
// ---------------------------------------------------------------------------
__global__ __launch_bounds__(256) void sq_kernel(const float* __restrict__ x,
                                                 float* __restrict__ sq) {
    int wave = threadIdx.x >> 6;
    int lane = threadIdx.x & 63;
    int row  = blockIdx.x * 4 + wave;
    const float4* xr = (const float4*)(x + (size_t)row * INCH);
    float s = 0.f;
    #pragma unroll
    for (int i = 0; i < 4; ++i) {
        float4 v = xr[lane + i * 64];
        s += v.x * v.x + v.y * v.y + v.z * v.z + v.w * v.w;
    }
    #pragma unroll
    for (int o = 32; o; o >>= 1) s += __shfl_xor(s, o);
    if (lane == 0) sq[row] = s;
}

// ---------------------------------------------------------------------------
// f32 -> bf16 (RNE via integer rounding; no type-support risk)
// ---------------------------------------------------------------------------
__global__ __launch_bounds__(256) void tobf16_kernel(const float* __restrict__ x,
                                                     unsigned short* __restrict__ xb) {
    size_t i = ((size_t)blockIdx.x * 256 + threadIdx.x) * 8;
    float4 v0 = *(const float4*)(x + i);
    float4 v1 = *(const float4*)(x + i + 4);
    auto cv = [](float f) -> unsigned short {
        unsigned u = __float_as_uint(f);
        return (unsigned short)((u + 0x7fffu + ((u >> 16) & 1u)) >> 16);
    };
    us8 o;
    o[0] = cv(v0.x); o[1] = cv(v0.y); o[2] = cv(v0.z); o[3] = cv(v0.w);
    o[4] = cv(v1.x); o[5] = cv(v1.y); o[6] = cv(v1.z); o[7] = cv(v1.w);
    *(us8*)(xb + i) = o;
}

// ---------------------------------------------------------------------------
// bf16 MFMA distance tile -> f16 (shifted by -2048) chunk matrix.
// 128x128 tile / block, 4 waves, each wave owns a 64x64 quadrant:
// 4x4 fragments of 16x16x32 MFMA, BK=32, reg-staged LDS with granule swizzle
// g' = (g + (row>>1)) & 3  (same mapping on store and read; bijective/row).
// A-frag: row = lane&15, k = (lane>>4)*8.. ; C: col = lane&15,
// row = (lane>>4)*4 + reg  [per verified gfx950 layouts].
// ---------------------------------------------------------------------------
__global__ __launch_bounds__(256) void mfma_dist_kernel(const unsigned short* __restrict__ xb,
                                                        const float* __restrict__ sq,
                                                        _Float16* __restrict__ Dh,
                                                        int r0) {
    __shared__ unsigned short Asm[128 * 32];
    __shared__ unsigned short Bsm[128 * 32];
    int tid  = threadIdx.x;
    int lane = tid & 63;
    int w    = tid >> 6;
    int rowBase = r0 + blockIdx.y * 128;
    int colBase = blockIdx.x * 128;
    int wrow = (w >> 1) * 64, wcol = (w & 1) * 64;

    f32x4 acc[4][4];
    #pragma unroll
    for (int m = 0; m < 4; ++m)
        #pragma unroll
        for (int n = 0; n < 4; ++n)
            acc[m][n] = (f32x4){0.f, 0.f, 0.f, 0.f};

    // staging: thread t covers row t>>1, k-halfword block (t&1)*16 (32B via 2x16B)
    int sra = tid >> 1;
    int sko = (tid & 1) * 16;
    const unsigned short* gA = xb + (size_t)(rowBase + sra) * INCH + sko;
    const unsigned short* gB = xb + (size_t)(colBase + sra) * INCH + sko;
    int ssw = (sra >> 1) & 3;
    int g0  = (sko >> 3);          // granule 0 or 2
    int wo0 = sra * 32 + (((g0 + 0) + ssw) & 3) * 8;
    int wo1 = sra * 32 + (((g0 + 1) + ssw) & 3) * 8;

    int kg = lane >> 4;            // k-granule of this lane's fragment slice

    for (int k0 = 0; k0 < INCH; k0 += 32) {
        uint4 a0 = *(const uint4*)(gA + k0);
        uint4 a1 = *(const uint4*)(gA + k0 + 8);
        uint4 b0 = *(const uint4*)(gB + k0);
        uint4 b1 = *(const uint4*)(gB + k0 + 8);
        __syncthreads();
        *(uint4*)&Asm[wo0] = a0;  *(uint4*)&Asm[wo1] = a1;
        *(uint4*)&Bsm[wo0] = b0;  *(uint4*)&Bsm[wo1] = b1;
        __syncthreads();

        bf16x8 af[4], bfr[4];
        #pragma unroll
        for (int m = 0; m < 4; ++m) {
            int ar = wrow + m * 16 + (lane & 15);
            int gp = (kg + (ar >> 1)) & 3;
            af[m] = __builtin_bit_cast(bf16x8, *(const uint4*)&Asm[ar * 32 + gp * 8]);
        }
        #pragma unroll
        for (int n = 0; n < 4; ++n) {
            int br = wcol + n * 16 + (lane & 15);
            int gp = (kg + (br >> 1)) & 3;
            bfr[n] = __builtin_bit_cast(bf16x8, *(const uint4*)&Bsm[br * 32 + gp * 8]);
        }
        #pragma unroll
        for (int m = 0; m < 4; ++m)
            #pragma unroll
            for (int n = 0; n < 4; ++n)
                acc[m][n] = __builtin_amdgcn_mfma_f32_16x16x32_bf16(af[m], bfr[n],
                                                                    acc[m][n], 0, 0, 0);
    }

    int rg = lane >> 4;
    #pragma unroll
    for (int m = 0; m < 4; ++m) {
        int rl = blockIdx.y * 128 + wrow + m * 16 + rg * 4;   // chunk-local row
        float sa0 = sq[r0 + rl + 0], sa1 = sq[r0 + rl + 1];
        float sa2 = sq[r0 + rl + 2], sa3 = sq[r0 + rl + 3];
        #pragma unroll
        for (int n = 0; n < 4; ++n) {
            int c = colBase + wcol + n * 16 + (lane & 15);
            float sb = sq[c];
            _Float16* dp = Dh + (size_t)rl * NPTS + c;
            dp[0 * NPTS] = (_Float16)(sa0 + sb - 2.f * acc[m][n][0] - 2048.f);
            dp[1 * NPTS] = (_Float16)(sa1 + sb - 2.f * acc[m][n][1] - 2048.f);
            dp[2 * NPTS] = (_Float16)(sa2 + sb - 2.f * acc[m][n][2] - 2048.f);
            dp[3 * NPTS] = (_Float16)(sa3 + sb - 2.f * acc[m][n][3] - 2048.f);
        }
    }
}

// ---------------------------------------------------------------------------
// Per row: approx top-16 candidate indices from the f16 chunk row.
// Sortable 16-bit key from f16 bits; tie-break by index (set only matters).
// ---------------------------------------------------------------------------
__global__ __launch_bounds__(256) void topk16_kernel(const _Float16* __restrict__ Dh,
                                                     int* __restrict__ cand, int r0) {
    const unsigned short* dr = (const unsigned short*)(Dh + (size_t)blockIdx.x * NPTS);
    int tid = threadIdx.x;
    unsigned long long kv[NCAND];
    #pragma unroll
    for (int p = 0; p < NCAND; ++p) kv[p] = ~0ull;

    for (int it = 0; it < NPTS / (256 * 8); ++it) {
        int j0 = (it * 256 + tid) * 8;
        us8 v = *(const us8*)(dr + j0);
        #pragma unroll
        for (int e = 0; e < 8; ++e) {
            unsigned h = v[e];
            unsigned k16 = (h & 0x8000u) ? (~h & 0xffffu) : (h | 0x8000u);
            unsigned long long key = ((unsigned long long)k16 << 32) | (unsigned)(j0 + e);
            if (key < kv[NCAND - 1]) {
                unsigned long long cur = key;
                #pragma unroll
                for (int p = 0; p < NCAND; ++p) {
                    unsigned long long lo = kv[p] < cur ? kv[p] : cur;
                    unsigned long long hi = kv[p] < cur ? cur : kv[p];
                    kv[p] = lo; cur = hi;
                }
            }
        }
    }

    __shared__ unsigned long long sm4[4];
    __shared__ unsigned long long smWin;
    int lane = tid & 63, wid = tid >> 6;

    for (int r = 0; r < NCAND; ++r) {
        unsigned long long h = kv[0];
        #pragma unroll
        for (int o = 32; o; o >>= 1) {
            unsigned long long t = __shfl_xor(h, o);
            h = t < h ? t : h;
        }
        if (lane == 0) sm4[wid] = h;
        __syncthreads();
        if (tid == 0) {
            unsigned long long m = sm4[0];
            #pragma unroll
            for (int i = 1; i < 4; ++i) m = sm4[i] < m ? sm4[i] : m;
            smWin = m;
        }
        __syncthreads();
        unsigned long long m = smWin;
        if (kv[0] == m) {
            #pragma unroll
            for (int p = 0; p < NCAND - 1; ++p) kv[p] = kv[p + 1];
            kv[NCAND - 1] = ~0ull;
        }
        if (tid == 0)
            cand[(size_t)(r0 + blockIdx.x) * NCAND + r] = (int)(m & 0xffffffffu);
        __syncthreads();
    }
}

// ---------------------------------------------------------------------------
// Exact fp32 rescore of the 16 candidates -> final top-10 (u64 key ranking,
// tie-break by lower index; one wave per row).
// ---------------------------------------------------------------------------
__global__ __launch_bounds__(64) void rescore_kernel(const float* __restrict__ x,
                                                     const float* __restrict__ sq,
                                                     const int* __restrict__ cand,
                                                     int* __restrict__ nn) {
    int row  = blockIdx.x;
    int lane = threadIdx.x;
    const float4* xr4 = (const float4*)(x + (size_t)row * INCH);
    float4 xr[4];
    #pragma unroll
    for (int q = 0; q < 4; ++q) xr[q] = xr4[lane + 64 * q];
    float sqr = sq[row];

    unsigned long long kv[KNN];
    #pragma unroll
    for (int p = 0; p < KNN; ++p) kv[p] = ~0ull;

    for (int c = 0; c < NCAND; ++c) {
        int cnd = cand[(size_t)row * NCAND + c];
        const float4* xc4 = (const float4*)(x + (size_t)cnd * INCH);
        float dp = 0.f;
        #pragma unroll
        for (int q = 0; q < 4; ++q) {
            float4 vc = xc4[lane + 64 * q];
            dp += xr[q].x * vc.x + xr[q].y * vc.y + xr[q].z * vc.z + xr[q].w * vc.w;
        }
        #pragma unroll
        for (int o = 32; o; o >>= 1) dp += __shfl_xor(dp, o);
        float d = sqr + sq[cnd] - 2.f * dp;
        unsigned u = __float_as_uint(d);
        u = (u & 0x80000000u) ? ~u : (u | 0x80000000u);
        unsigned long long key = ((unsigned long long)u << 32) | (unsigned)cnd;
        if (key < kv[KNN - 1]) {
            unsigned long long cur = key;
            #pragma unroll
            for (int p = 0; p < KNN; ++p) {
                unsigned long long lo = kv[p] < cur ? kv[p] : cur;
                unsigned long long hi = kv[p] < cur ? cur : kv[p];
                kv[p] = lo; cur = hi;
            }
        }
    }
    if (lane < KNN)
        nn[(size_t)row * KNN + lane] = (int)(kv[lane] & 0xffffffffu);
}

// ---------------------------------------------------------------------------
// Dv counts (node degrees)
// ---------------------------------------------------------------------------
__global__ void count_kernel(const int* __restrict__ nn, int* __restrict__ Dv) {
    int t = blockIdx.x * 256 + threadIdx.x;
    if (t < NPTS * KNN) atomicAdd(&Dv[nn[t]], 1);
}

// ---------------------------------------------------------------------------
// C[M x 128] = A[M x Kdim] @ B[Kdim x 128], 64x128 tile, 4x8 per thread
// ---------------------------------------------------------------------------
__global__ __launch_bounds__(256) void gemm_n128_kernel(const float* __restrict__ A,
                                                        const float* __restrict__ Bm,
                                                        float* __restrict__ C,
                                                        int Kdim) {
    __shared__ float As[16][64];
    __shared__ float Bs[16][128];
    int tid = threadIdx.x;
    int tx = tid & 15, ty = tid >> 4;
    int rowBase = blockIdx.x * 64;
    float acc[4][8];
    #pragma unroll
    for (int i = 0; i < 4; ++i)
        #pragma unroll
        for (int j = 0; j < 8; ++j) acc[i][j] = 0.f;

    int lr = tid >> 2, lk = (tid & 3) * 4;
    int bk = tid >> 4, bc = (tid & 15) * 8;

    for (int k0 = 0; k0 < Kdim; k0 += 16) {
        float4 av  = *(const float4*)(A + (size_t)(rowBase + lr) * Kdim + k0 + lk);
        float4 bv0 = *(const float4*)(Bm + (size_t)(k0 + bk) * FDIM + bc);
        float4 bv1 = *(const float4*)(Bm + (size_t)(k0 + bk) * FDIM + bc + 4);
        __syncthreads();
        As[lk + 0][lr] = av.x; As[lk + 1][lr] = av.y;
        As[lk + 2][lr] = av.z; As[lk + 3][lr] = av.w;
        *(float4*)&Bs[bk][bc]     = bv0;
        *(float4*)&Bs[bk][bc + 4] = bv1;
        __syncthreads();
        #pragma unroll
        for (int k = 0; k < 16; ++k) {
            float4 a  = *(const float4*)&As[k][ty * 4];
            float4 c0 = *(const float4*)&Bs[k][tx * 8];
            float4 c1 = *(const float4*)&Bs[k][tx * 8 + 4];
            float ar[4] = {a.x, a.y, a.z, a.w};
            float br[8] = {c0.x, c0.y, c0.z, c0.w, c1.x, c1.y, c1.z, c1.w};
            #pragma unroll
            for (int i = 0; i < 4; ++i)
                #pragma unroll
                for (int j = 0; j < 8; ++j) acc[i][j] += ar[i] * br[j];
        }
    }
    int row = rowBase + ty * 4;
    int col = tx * 8;
    #pragma unroll
    for (int i = 0; i < 4; ++i) {
        float4 o0 = {acc[i][0], acc[i][1], acc[i][2], acc[i][3]};
        float4 o1 = {acc[i][4], acc[i][5], acc[i][6], acc[i][7]};
        *(float4*)(C + (size_t)(row + i) * FDIM + col)     = o0;
        *(float4*)(C + (size_t)(row + i) * FDIM + col + 4) = o1;
    }
}

// ---------------------------------------------------------------------------
// edge_ft[e][c] = mean_{k} t[nn[e][k]][c]
// ---------------------------------------------------------------------------
__global__ __launch_bounds__(256) void edge_kernel(const float* __restrict__ t,
                                                   const int* __restrict__ nn,
                                                   float* __restrict__ e) {
    int eid = blockIdx.x * 2 + (threadIdx.x >> 7);
    int c = threadIdx.x & 127;
    const int* nnr = nn + (size_t)eid * KNN;
    float s = 0.f;
    #pragma unroll
    for (int k = 0; k < KNN; ++k)
        s += t[(size_t)nnr[k] * FDIM + c];
    e[(size_t)eid * FDIM + c] = s * (1.f / (float)KNN);
}

// ---------------------------------------------------------------------------
// Edge-parallel scatter: acc[v][c] += edge_ft[e][c]
// ---------------------------------------------------------------------------
__global__ __launch_bounds__(256) void scatter_kernel(const float* __restrict__ e,
                                                      const int* __restrict__ nn,
                                                      float* __restrict__ acc) {
    int t = blockIdx.x * 2 + (threadIdx.x >> 7);
    int c = threadIdx.x & 127;
    int v = nn[t];
    int eid = t / KNN;
    float val = e[(size_t)eid * FDIM + c];
    atomicAdd(&acc[(size_t)v * FDIM + c], val);
}

// ---------------------------------------------------------------------------
// node_ft[v][c] = acc[v][c] / max(Dv,1) + bias[c], leaky relu
// ---------------------------------------------------------------------------
__global__ __launch_bounds__(256) void finish_kernel(const float* __restrict__ acc,
                                                     const int* __restrict__ Dv,
                                                     const float* __restrict__ bias,
                                                     float* __restrict__ out) {
    int v = blockIdx.x * 2 + (threadIdx.x >> 7);
    int c = threadIdx.x & 127;
    int cnt = Dv[v];
    float dn = cnt > 1 ? (float)cnt : 1.f;
    float s = acc[(size_t)v * FDIM + c] / dn + bias[c];
    s = (s >= 0.f) ? s : 0.01f * s;
    out[(size_t)v * FDIM + c] = s;
}

// ---------------------------------------------------------------------------
// pooling partials + final
// ---------------------------------------------------------------------------
__global__ __launch_bounds__(256) void pool_kernel(const float* __restrict__ feats,
                                                   float* __restrict__ part) {
    int c = threadIdx.x & 127;
    int half = threadIdx.x >> 7;
    int r0 = blockIdx.x * 128 + half;
    float s = 0.f;
    for (int i = 0; i < 64; ++i)
        s += feats[(size_t)(r0 + 2 * i) * FDIM + c];
    part[(size_t)(blockIdx.x * 2 + half) * FDIM + c] = s;
}

__global__ __launch_bounds__(128) void final_kernel(const float* __restrict__ part,
                                                    const float* __restrict__ fcw,
                                                    const float* __restrict__ fcb,
                                                    float* __restrict__ out) {
    __shared__ float pool[FDIM];
    int c = threadIdx.x;
    float s = 0.f;
    for (int i = 0; i < 128; ++i)
        s += part[(size_t)i * FDIM + c];
    s *= (1.f / (float)NPTS);
    out[2 + (size_t)NPTS * FDIM + c] = s;
    pool[c] = s;
    __syncthreads();
    if (c < 2) {
        float z = fcb[c];
        for (int k = 0; k < FDIM; ++k)
            z += pool[k] * fcw[c * FDIM + k];
        out[c] = 1.f / (1.f + expf(-z));
    }
}

// ---------------------------------------------------------------------------
extern "C" void kernel_launch(void* const* d_in, const int* in_sizes, int n_in,
                              void* d_out, int out_size, void* d_ws, size_t ws_size,
                              hipStream_t stream) {
    const float* x   = (const float*)d_in[0];
    const float* th0 = (const float*)d_in[1];
    const float* b0  = (const float*)d_in[2];
    const float* th1 = (const float*)d_in[3];
    const float* b1  = (const float*)d_in[4];
    const float* fcw = (const float*)d_in[5];
    const float* fcb = (const float*)d_in[6];
    float* out = (float*)d_out;

    char* w = (char*)d_ws;
    size_t off = 0;
    auto alloc = [&](size_t bytes) -> void* {
        void* p = w + off;
        off = (off + bytes + 255) & ~(size_t)255;
        return p;
    };
    float* sq    = (float*)alloc(NPTS * 4);
    int*   nn    = (int*)  alloc(NPTS * KNN * 4);
    int*   Dv    = (int*)  alloc(NPTS * 4);
    int*   cand  = (int*)  alloc((size_t)NPTS * NCAND * 4);
    float* tbuf  = (float*)alloc((size_t)NPTS * FDIM * 4);
    float* ebuf  = (float*)alloc((size_t)NPTS * FDIM * 4);
    float* hbuf  = (float*)alloc((size_t)NPTS * FDIM * 4);
    float* accb  = (float*)alloc((size_t)NPTS * FDIM * 4);
    float* part  = (float*)alloc(128 * FDIM * 4);
    unsigned short* xbf = (unsigned short*)alloc((size_t)NPTS * INCH * 2);

    size_t rem = ws_size > off ? ws_size - off : 0;
    long long chMax = (long long)(rem / ((size_t)NPTS * 2));
    int CH = (int)(chMax > 4096 ? 4096 : chMax);
    CH &= ~127;
    if (CH < 128) CH = 128;
    _Float16* Dh = (_Float16*)(w + off);

    hipMemsetAsync(Dv, 0, NPTS * 4, stream);
    sq_kernel<<<NPTS / 4, 256, 0, stream>>>(x, sq);
    tobf16_kernel<<<(NPTS * INCH) / (256 * 8), 256, 0, stream>>>(x, xbf);

    for (int r0 = 0; r0 < NPTS; r0 += CH) {
        int ch = NPTS - r0 < CH ? NPTS - r0 : CH;
        mfma_dist_kernel<<<dim3(NPTS / 128, ch / 128), 256, 0, stream>>>(xbf, sq, Dh, r0);
        topk16_kernel<<<ch, 256, 0, stream>>>(Dh, cand, r0);
    }

    rescore_kernel<<<NPTS, 64, 0, stream>>>(x, sq, cand, nn);

    count_kernel<<<(NPTS * KNN + 255) / 256, 256, 0, stream>>>(nn, Dv);

    // layer 0
    gemm_n128_kernel<<<NPTS / 64, 256, 0, stream>>>(x, th0, tbuf, INCH);
    edge_kernel<<<NPTS / 2, 256, 0, stream>>>(tbuf, nn, ebuf);
    hipMemsetAsync(accb, 0, (size_t)NPTS * FDIM * 4, stream);
    scatter_kernel<<<NPTS * KNN / 2, 256, 0, stream>>>(ebuf, nn, accb);
    finish_kernel<<<NPTS / 2, 256, 0, stream>>>(accb, Dv, b0, hbuf);

    // layer 1 -> feats written directly into out+2
    gemm_n128_kernel<<<NPTS / 64, 256, 0, stream>>>(hbuf, th1, tbuf, FDIM);
    edge_kernel<<<NPTS / 2, 256, 0, stream>>>(tbuf, nn, ebuf);
    hipMemsetAsync(accb, 0, (size_t)NPTS * FDIM * 4, stream);
    scatter_kernel<<<NPTS * KNN / 2, 256, 0, stream>>>(ebuf, nn, accb);
    finish_kernel<<<NPTS / 2, 256, 0, stream>>>(accb, Dv, b1, out + 2);

    pool_kernel<<<64, 256, 0, stream>>>(out + 2, part);
    final_kernel<<<1, 128, 0, stream>>>(part, fcw, fcb, out);
}

// Round 6
// 648.740 us; speedup vs baseline: 4.0934x; 1.2714x over previous
//
#include <hip/hip_runtime.h>
#include <math.h>

#define NPTS  8192
#define INCH  1024
#define FDIM  128
#define KNN   10
#define NCAND 16

typedef __attribute__((ext_vector_type(8))) __bf16          bf16x8;
typedef __attribute__((ext_vector_type(4))) float           f32x4;
typedef __attribute__((ext_vector_type(8))) unsigned short  us8;

// u32 compare-exchange: a=min, b=max  (v_min_u32 + v_max_u32)
#define CE32(a,b) do { unsigned lo_ = min((a),(b)); unsigned hi_ = max((a),(b)); \
                       (a)=lo_; (b)=hi_; } while(0)

// ---------------------------------------------------------------------------
// sq[i] = sum_d x[i][d]^2   (one wave per row)
// ---------------------------------------------------------------------------
__global__ __launch_bounds__(256) void sq_kernel(const float* __restrict__ x,
                                                 float* __restrict__ sq) {
    int wave = threadIdx.x >> 6;
    int lane = threadIdx.x & 63;
    int row  = blockIdx.x * 4 + wave;
    const float4* xr = (const float4*)(x + (size_t)row * INCH);
    float s = 0.f;
    #pragma unroll
    for (int i = 0; i < 4; ++i) {
        float4 v = xr[lane + i * 64];
        s += v.x * v.x + v.y * v.y + v.z * v.z + v.w * v.w;
    }
    #pragma unroll
    for (int o = 32; o; o >>= 1) s += __shfl_xor(s, o);
    if (lane == 0) sq[row] = s;
}

// ---------------------------------------------------------------------------
// f32 -> bf16 (RNE)
// ---------------------------------------------------------------------------
__global__ __launch_bounds__(256) void tobf16_kernel(const float* __restrict__ x,
                                                     unsigned short* __restrict__ xb) {
    size_t i = ((size_t)blockIdx.x * 256 + threadIdx.x) * 8;
    float4 v0 = *(const float4*)(x + i);
    float4 v1 = *(const float4*)(x + i + 4);
    auto cv = [](float f) -> unsigned short {
        unsigned u = __float_as_uint(f);
        return (unsigned short)((u + 0x7fffu + ((u >> 16) & 1u)) >> 16);
    };
    us8 o;
    o[0] = cv(v0.x); o[1] = cv(v0.y); o[2] = cv(v0.z); o[3] = cv(v0.w);
    o[4] = cv(v1.x); o[5] = cv(v1.y); o[6] = cv(v1.z); o[7] = cv(v1.w);
    *(us8*)(xb + i) = o;
}

// ---------------------------------------------------------------------------
// bf16 MFMA distance tile -> f16 (shifted by -2048) chunk matrix.
// (unchanged from round 5 — verified correct)
// ---------------------------------------------------------------------------
__global__ __launch_bounds__(256) void mfma_dist_kernel(const unsigned short* __restrict__ xb,
                                                        const float* __restrict__ sq,
                                                        _Float16* __restrict__ Dh,
                                                        int r0) {
    __shared__ unsigned short Asm[128 * 32];
    __shared__ unsigned short Bsm[128 * 32];
    int tid  = threadIdx.x;
    int lane = tid & 63;
    int w    = tid >> 6;
    int rowBase = r0 + blockIdx.y * 128;
    int colBase = blockIdx.x * 128;
    int wrow = (w >> 1) * 64, wcol = (w & 1) * 64;

    f32x4 acc[4][4];
    #pragma unroll
    for (int m = 0; m < 4; ++m)
        #pragma unroll
        for (int n = 0; n < 4; ++n)
            acc[m][n] = (f32x4){0.f, 0.f, 0.f, 0.f};

    int sra = tid >> 1;
    int sko = (tid & 1) * 16;
    const unsigned short* gA = xb + (size_t)(rowBase + sra) * INCH + sko;
    const unsigned short* gB = xb + (size_t)(colBase + sra) * INCH + sko;
    int ssw = (sra >> 1) & 3;
    int g0  = (sko >> 3);
    int wo0 = sra * 32 + (((g0 + 0) + ssw) & 3) * 8;
    int wo1 = sra * 32 + (((g0 + 1) + ssw) & 3) * 8;

    int kg = lane >> 4;

    for (int k0 = 0; k0 < INCH; k0 += 32) {
        uint4 a0 = *(const uint4*)(gA + k0);
        uint4 a1 = *(const uint4*)(gA + k0 + 8);
        uint4 b0 = *(const uint4*)(gB + k0);
        uint4 b1 = *(const uint4*)(gB + k0 + 8);
        __syncthreads();
        *(uint4*)&Asm[wo0] = a0;  *(uint4*)&Asm[wo1] = a1;
        *(uint4*)&Bsm[wo0] = b0;  *(uint4*)&Bsm[wo1] = b1;
        __syncthreads();

        bf16x8 af[4], bfr[4];
        #pragma unroll
        for (int m = 0; m < 4; ++m) {
            int ar = wrow + m * 16 + (lane & 15);
            int gp = (kg + (ar >> 1)) & 3;
            af[m] = __builtin_bit_cast(bf16x8, *(const uint4*)&Asm[ar * 32 + gp * 8]);
        }
        #pragma unroll
        for (int n = 0; n < 4; ++n) {
            int br = wcol + n * 16 + (lane & 15);
            int gp = (kg + (br >> 1)) & 3;
            bfr[n] = __builtin_bit_cast(bf16x8, *(const uint4*)&Bsm[br * 32 + gp * 8]);
        }
        #pragma unroll
        for (int m = 0; m < 4; ++m)
            #pragma unroll
            for (int n = 0; n < 4; ++n)
                acc[m][n] = __builtin_amdgcn_mfma_f32_16x16x32_bf16(af[m], bfr[n],
                                                                    acc[m][n], 0, 0, 0);
    }

    int rg = lane >> 4;
    #pragma unroll
    for (int m = 0; m < 4; ++m) {
        int rl = blockIdx.y * 128 + wrow + m * 16 + rg * 4;
        float sa0 = sq[r0 + rl + 0], sa1 = sq[r0 + rl + 1];
        float sa2 = sq[r0 + rl + 2], sa3 = sq[r0 + rl + 3];
        #pragma unroll
        for (int n = 0; n < 4; ++n) {
            int c = colBase + wcol + n * 16 + (lane & 15);
            float sb = sq[c];
            _Float16* dp = Dh + (size_t)rl * NPTS + c;
            dp[0 * NPTS] = (_Float16)(sa0 + sb - 2.f * acc[m][n][0] - 2048.f);
            dp[1 * NPTS] = (_Float16)(sa1 + sb - 2.f * acc[m][n][1] - 2048.f);
            dp[2 * NPTS] = (_Float16)(sa2 + sb - 2.f * acc[m][n][2] - 2048.f);
            dp[3 * NPTS] = (_Float16)(sa3 + sb - 2.f * acc[m][n][3] - 2048.f);
        }
    }
}

// ---------------------------------------------------------------------------
// Per row: exact top-16 (on f16 keys) candidate indices.
// One WAVE per row, zero barriers. u32 keys: (sortable_f16 << 13) | col.
// Per lane: 16 groups of 8 -> Batcher sort-8 -> conditional lower-half merge
// into sorted-16; then 6-step shfl_xor bitonic wave reduction.
// Key ordering identical to round-5's u64 keys -> same candidate SET.
// ---------------------------------------------------------------------------
__global__ __launch_bounds__(256) void topk16_kernel(const _Float16* __restrict__ Dh,
                                                     int* __restrict__ cand, int r0) {
    int wid  = threadIdx.x >> 6;
    int lane = threadIdx.x & 63;
    int row  = blockIdx.x * 4 + wid;   // chunk-local row
    const unsigned short* dr = (const unsigned short*)(Dh + (size_t)row * NPTS);

    unsigned kv[16];
    #pragma unroll
    for (int p = 0; p < 16; ++p) kv[p] = 0xffffffffu;

    for (int g = 0; g < 16; ++g) {
        int j0 = (g * 64 + lane) * 8;
        us8 v = *(const us8*)(dr + j0);
        unsigned s[8];
        #pragma unroll
        for (int e = 0; e < 8; ++e) {
            unsigned h = v[e];
            unsigned k16 = (h & 0x8000u) ? (~h & 0xffffu) : (h | 0x8000u);
            s[e] = (k16 << 13) | (unsigned)(j0 + e);
        }
        // Batcher sort-8 ascending (19 CE, branchless)
        CE32(s[0],s[1]); CE32(s[2],s[3]); CE32(s[4],s[5]); CE32(s[6],s[7]);
        CE32(s[0],s[2]); CE32(s[1],s[3]); CE32(s[4],s[6]); CE32(s[5],s[7]);
        CE32(s[1],s[2]); CE32(s[5],s[6]);
        CE32(s[0],s[4]); CE32(s[1],s[5]); CE32(s[2],s[6]); CE32(s[3],s[7]);
        CE32(s[2],s[4]); CE32(s[3],s[5]);
        CE32(s[1],s[2]); CE32(s[3],s[4]); CE32(s[5],s[6]);

        if (s[0] < kv[15]) {
            // lower-16 of merge(kv asc16, s asc8): M[q<8]=kv[q],
            // M[q>=8]=min(kv[q], s[15-q]); M is bitonic -> merge-sort it.
            unsigned M[16];
            #pragma unroll
            for (int q = 0; q < 8; ++q) M[q] = kv[q];
            #pragma unroll
            for (int q = 8; q < 16; ++q) M[q] = min(kv[q], s[15 - q]);
            #pragma unroll
            for (int d = 8; d; d >>= 1)
                #pragma unroll
                for (int q = 0; q < 16; ++q)
                    if (!(q & d)) CE32(M[q], M[q + d]);
            #pragma unroll
            for (int q = 0; q < 16; ++q) kv[q] = M[q];
        }
    }

    // wave bitonic reduction: after 6 steps every lane holds global top-16
    #pragma unroll
    for (int st = 0; st < 6; ++st) {
        unsigned M[16];
        #pragma unroll
        for (int q = 0; q < 16; ++q) {
            unsigned pv = (unsigned)__shfl_xor((int)kv[15 - q], 1 << st);
            M[q] = min(kv[q], pv);
        }
        #pragma unroll
        for (int d = 8; d; d >>= 1)
            #pragma unroll
            for (int q = 0; q < 16; ++q)
                if (!(q & d)) CE32(M[q], M[q + d]);
        #pragma unroll
        for (int q = 0; q < 16; ++q) kv[q] = M[q];
    }

    if (lane == 0) {
        #pragma unroll
        for (int r = 0; r < 16; ++r)
            cand[(size_t)(r0 + row) * NCAND + r] = (int)(kv[r] & 0x1fffu);
    }
}

// ---------------------------------------------------------------------------
// Exact fp32 rescore of the 16 candidates -> final top-10
// ---------------------------------------------------------------------------
__global__ __launch_bounds__(64) void rescore_kernel(const float* __restrict__ x,
                                                     const float* __restrict__ sq,
                                                     const int* __restrict__ cand,
                                                     int* __restrict__ nn) {
    int row  = blockIdx.x;
    int lane = threadIdx.x;
    const float4* xr4 = (const float4*)(x + (size_t)row * INCH);
    float4 xr[4];
    #pragma unroll
    for (int q = 0; q < 4; ++q) xr[q] = xr4[lane + 64 * q];
    float sqr = sq[row];

    unsigned long long kv[KNN];
    #pragma unroll
    for (int p = 0; p < KNN; ++p) kv[p] = ~0ull;

    for (int c = 0; c < NCAND; ++c) {
        int cnd = cand[(size_t)row * NCAND + c];
        const float4* xc4 = (const float4*)(x + (size_t)cnd * INCH);
        float dp = 0.f;
        #pragma unroll
        for (int q = 0; q < 4; ++q) {
            float4 vc = xc4[lane + 64 * q];
            dp += xr[q].x * vc.x + xr[q].y * vc.y + xr[q].z * vc.z + xr[q].w * vc.w;
        }
        #pragma unroll
        for (int o = 32; o; o >>= 1) dp += __shfl_xor(dp, o);
        float d = sqr + sq[cnd] - 2.f * dp;
        unsigned u = __float_as_uint(d);
        u = (u & 0x80000000u) ? ~u : (u | 0x80000000u);
        unsigned long long key = ((unsigned long long)u << 32) | (unsigned)cnd;
        if (key < kv[KNN - 1]) {
            unsigned long long cur = key;
            #pragma unroll
            for (int p = 0; p < KNN; ++p) {
                unsigned long long lo = kv[p] < cur ? kv[p] : cur;
                unsigned long long hi = kv[p] < cur ? cur : kv[p];
                kv[p] = lo; cur = hi;
            }
        }
    }
    if (lane < KNN)
        nn[(size_t)row * KNN + lane] = (int)(kv[lane] & 0xffffffffu);
}

// ---------------------------------------------------------------------------
// Dv counts (node degrees)
// ---------------------------------------------------------------------------
__global__ void count_kernel(const int* __restrict__ nn, int* __restrict__ Dv) {
    int t = blockIdx.x * 256 + threadIdx.x;
    if (t < NPTS * KNN) atomicAdd(&Dv[nn[t]], 1);
}

// ---------------------------------------------------------------------------
// C[M x 128] = A[M x Kdim] @ B[Kdim x 128], 64x128 tile, 4x8 per thread
// ---------------------------------------------------------------------------
__global__ __launch_bounds__(256) void gemm_n128_kernel(const float* __restrict__ A,
                                                        const float* __restrict__ Bm,
                                                        float* __restrict__ C,
                                                        int Kdim) {
    __shared__ float As[16][64];
    __shared__ float Bs[16][128];
    int tid = threadIdx.x;
    int tx = tid & 15, ty = tid >> 4;
    int rowBase = blockIdx.x * 64;
    float acc[4][8];
    #pragma unroll
    for (int i = 0; i < 4; ++i)
        #pragma unroll
        for (int j = 0; j < 8; ++j) acc[i][j] = 0.f;

    int lr = tid >> 2, lk = (tid & 3) * 4;
    int bk = tid >> 4, bc = (tid & 15) * 8;

    for (int k0 = 0; k0 < Kdim; k0 += 16) {
        float4 av  = *(const float4*)(A + (size_t)(rowBase + lr) * Kdim + k0 + lk);
        float4 bv0 = *(const float4*)(Bm + (size_t)(k0 + bk) * FDIM + bc);
        float4 bv1 = *(const float4*)(Bm + (size_t)(k0 + bk) * FDIM + bc + 4);
        __syncthreads();
        As[lk + 0][lr] = av.x; As[lk + 1][lr] = av.y;
        As[lk + 2][lr] = av.z; As[lk + 3][lr] = av.w;
        *(float4*)&Bs[bk][bc]     = bv0;
        *(float4*)&Bs[bk][bc + 4] = bv1;
        __syncthreads();
        #pragma unroll
        for (int k = 0; k < 16; ++k) {
            float4 a  = *(const float4*)&As[k][ty * 4];
            float4 c0 = *(const float4*)&Bs[k][tx * 8];
            float4 c1 = *(const float4*)&Bs[k][tx * 8 + 4];
            float ar[4] = {a.x, a.y, a.z, a.w};
            float br[8] = {c0.x, c0.y, c0.z, c0.w, c1.x, c1.y, c1.z, c1.w};
            #pragma unroll
            for (int i = 0; i < 4; ++i)
                #pragma unroll
                for (int j = 0; j < 8; ++j) acc[i][j] += ar[i] * br[j];
        }
    }
    int row = rowBase + ty * 4;
    int col = tx * 8;
    #pragma unroll
    for (int i = 0; i < 4; ++i) {
        float4 o0 = {acc[i][0], acc[i][1], acc[i][2], acc[i][3]};
        float4 o1 = {acc[i][4], acc[i][5], acc[i][6], acc[i][7]};
        *(float4*)(C + (size_t)(row + i) * FDIM + col)     = o0;
        *(float4*)(C + (size_t)(row + i) * FDIM + col + 4) = o1;
    }
}

// ---------------------------------------------------------------------------
// edge_ft[e][c] = mean_{k} t[nn[e][k]][c]
// ---------------------------------------------------------------------------
__global__ __launch_bounds__(256) void edge_kernel(const float* __restrict__ t,
                                                   const int* __restrict__ nn,
                                                   float* __restrict__ e) {
    int eid = blockIdx.x * 2 + (threadIdx.x >> 7);
    int c = threadIdx.x & 127;
    const int* nnr = nn + (size_t)eid * KNN;
    float s = 0.f;
    #pragma unroll
    for (int k = 0; k < KNN; ++k)
        s += t[(size_t)nnr[k] * FDIM + c];
    e[(size_t)eid * FDIM + c] = s * (1.f / (float)KNN);
}

// ---------------------------------------------------------------------------
// Edge-parallel scatter: acc[v][c] += edge_ft[e][c]
// ---------------------------------------------------------------------------
__global__ __launch_bounds__(256) void scatter_kernel(const float* __restrict__ e,
                                                      const int* __restrict__ nn,
                                                      float* __restrict__ acc) {
    int t = blockIdx.x * 2 + (threadIdx.x >> 7);
    int c = threadIdx.x & 127;
    int v = nn[t];
    int eid = t / KNN;
    float val = e[(size_t)eid * FDIM + c];
    atomicAdd(&acc[(size_t)v * FDIM + c], val);
}

// ---------------------------------------------------------------------------
// node_ft[v][c] = acc[v][c] / max(Dv,1) + bias[c], leaky relu
// ---------------------------------------------------------------------------
__global__ __launch_bounds__(256) void finish_kernel(const float* __restrict__ acc,
                                                     const int* __restrict__ Dv,
                                                     const float* __restrict__ bias,
                                                     float* __restrict__ out) {
    int v = blockIdx.x * 2 + (threadIdx.x >> 7);
    int c = threadIdx.x & 127;
    int cnt = Dv[v];
    float dn = cnt > 1 ? (float)cnt : 1.f;
    float s = acc[(size_t)v * FDIM + c] / dn + bias[c];
    s = (s >= 0.f) ? s : 0.01f * s;
    out[(size_t)v * FDIM + c] = s;
}

// ---------------------------------------------------------------------------
// pooling partials + final
// ---------------------------------------------------------------------------
__global__ __launch_bounds__(256) void pool_kernel(const float* __restrict__ feats,
                                                   float* __restrict__ part) {
    int c = threadIdx.x & 127;
    int half = threadIdx.x >> 7;
    int r0 = blockIdx.x * 128 + half;
    float s = 0.f;
    for (int i = 0; i < 64; ++i)
        s += feats[(size_t)(r0 + 2 * i) * FDIM + c];
    part[(size_t)(blockIdx.x * 2 + half) * FDIM + c] = s;
}

__global__ __launch_bounds__(128) void final_kernel(const float* __restrict__ part,
                                                    const float* __restrict__ fcw,
                                                    const float* __restrict__ fcb,
                                                    float* __restrict__ out) {
    __shared__ float pool[FDIM];
    int c = threadIdx.x;
    float s = 0.f;
    for (int i = 0; i < 128; ++i)
        s += part[(size_t)i * FDIM + c];
    s *= (1.f / (float)NPTS);
    out[2 + (size_t)NPTS * FDIM + c] = s;
    pool[c] = s;
    __syncthreads();
    if (c < 2) {
        float z = fcb[c];
        for (int k = 0; k < FDIM; ++k)
            z += pool[k] * fcw[c * FDIM + k];
        out[c] = 1.f / (1.f + expf(-z));
    }
}

// ---------------------------------------------------------------------------
extern "C" void kernel_launch(void* const* d_in, const int* in_sizes, int n_in,
                              void* d_out, int out_size, void* d_ws, size_t ws_size,
                              hipStream_t stream) {
    const float* x   = (const float*)d_in[0];
    const float* th0 = (const float*)d_in[1];
    const float* b0  = (const float*)d_in[2];
    const float* th1 = (const float*)d_in[3];
    const float* b1  = (const float*)d_in[4];
    const float* fcw = (const float*)d_in[5];
    const float* fcb = (const float*)d_in[6];
    float* out = (float*)d_out;

    char* w = (char*)d_ws;
    size_t off = 0;
    auto alloc = [&](size_t bytes) -> void* {
        void* p = w + off;
        off = (off + bytes + 255) & ~(size_t)255;
        return p;
    };
    float* sq    = (float*)alloc(NPTS * 4);
    int*   nn    = (int*)  alloc(NPTS * KNN * 4);
    int*   Dv    = (int*)  alloc(NPTS * 4);
    int*   cand  = (int*)  alloc((size_t)NPTS * NCAND * 4);
    float* tbuf  = (float*)alloc((size_t)NPTS * FDIM * 4);
    float* ebuf  = (float*)alloc((size_t)NPTS * FDIM * 4);
    float* hbuf  = (float*)alloc((size_t)NPTS * FDIM * 4);
    float* accb  = (float*)alloc((size_t)NPTS * FDIM * 4);
    float* part  = (float*)alloc(128 * FDIM * 4);
    unsigned short* xbf = (unsigned short*)alloc((size_t)NPTS * INCH * 2);

    size_t rem = ws_size > off ? ws_size - off : 0;
    long long chMax = (long long)(rem / ((size_t)NPTS * 2));
    int CH = (int)(chMax > 8192 ? 8192 : chMax);
    CH &= ~127;
    if (CH < 128) CH = 128;
    _Float16* Dh = (_Float16*)(w + off);

    hipMemsetAsync(Dv, 0, NPTS * 4, stream);
    sq_kernel<<<NPTS / 4, 256, 0, stream>>>(x, sq);
    tobf16_kernel<<<(NPTS * INCH) / (256 * 8), 256, 0, stream>>>(x, xbf);

    for (int r0 = 0; r0 < NPTS; r0 += CH) {
        int ch = NPTS - r0 < CH ? NPTS - r0 : CH;
        mfma_dist_kernel<<<dim3(NPTS / 128, ch / 128), 256, 0, stream>>>(xbf, sq, Dh, r0);
        topk16_kernel<<<ch / 4, 256, 0, stream>>>(Dh, cand, r0);
    }

    rescore_kernel<<<NPTS, 64, 0, stream>>>(x, sq, cand, nn);

    count_kernel<<<(NPTS * KNN + 255) / 256, 256, 0, stream>>>(nn, Dv);

    // layer 0
    gemm_n128_kernel<<<NPTS / 64, 256, 0, stream>>>(x, th0, tbuf, INCH);
    edge_kernel<<<NPTS / 2, 256, 0, stream>>>(tbuf, nn, ebuf);
    hipMemsetAsync(accb, 0, (size_t)NPTS * FDIM * 4, stream);
    scatter_kernel<<<NPTS * KNN / 2, 256, 0, stream>>>(ebuf, nn, accb);
    finish_kernel<<<NPTS / 2, 256, 0, stream>>>(accb, Dv, b0, hbuf);

    // layer 1 -> feats written directly into out+2
    gemm_n128_kernel<<<NPTS / 64, 256, 0, stream>>>(hbuf, th1, tbuf, FDIM);
    edge_kernel<<<NPTS / 2, 256, 0, stream>>>(tbuf, nn, ebuf);
    hipMemsetAsync(accb, 0, (size_t)NPTS * FDIM * 4, stream);
    scatter_kernel<<<NPTS * KNN / 2, 256, 0, stream>>>(ebuf, nn, accb);
    finish_kernel<<<NPTS / 2, 256, 0, stream>>>(accb, Dv, b1, out + 2);

    pool_kernel<<<64, 256, 0, stream>>>(out + 2, part);
    final_kernel<<<1, 128, 0, stream>>>(part, fcw, fcb, out);
}

// Round 7
// 632.256 us; speedup vs baseline: 4.2001x; 1.0261x over previous
//
#include <hip/hip_runtime.h>
#include <math.h>

#define NPTS  8192
#define INCH  1024
#define FDIM  128
#define KNN   10
#define NCAND 16

typedef __attribute__((ext_vector_type(8))) __bf16          bf16x8;
typedef __attribute__((ext_vector_type(4))) float           f32x4;
typedef __attribute__((ext_vector_type(8))) unsigned short  us8;
typedef __attribute__((ext_vector_type(4))) unsigned short  us4;

// u32 compare-exchange: a=min, b=max  (v_min_u32 + v_max_u32)
#define CE32(a,b) do { unsigned lo_ = min((a),(b)); unsigned hi_ = max((a),(b)); \
                       (a)=lo_; (b)=hi_; } while(0)

// async global->LDS, 16 bytes per lane (dest = wave-uniform base + lane*16)
__device__ __forceinline__ void gload16(const void* g, void* l) {
    __builtin_amdgcn_global_load_lds(
        (const __attribute__((address_space(1))) unsigned int*)g,
        (__attribute__((address_space(3))) unsigned int*)l, 16, 0, 0);
}

// ---------------------------------------------------------------------------
// prep: sq[i] = sum x[i][d]^2 (bit-identical order to prior rounds) AND
// xb = bf16(x) in the same pass.  One wave per row.
// ---------------------------------------------------------------------------
__global__ __launch_bounds__(256) void prep_kernel(const float* __restrict__ x,
                                                   float* __restrict__ sq,
                                                   unsigned short* __restrict__ xb) {
    int wave = threadIdx.x >> 6;
    int lane = threadIdx.x & 63;
    int row  = blockIdx.x * 4 + wave;
    const float4* xr = (const float4*)(x + (size_t)row * INCH);
    unsigned short* xo = xb + (size_t)row * INCH;
    auto cv = [](float f) -> unsigned short {
        unsigned u = __float_as_uint(f);
        return (unsigned short)((u + 0x7fffu + ((u >> 16) & 1u)) >> 16);
    };
    float s = 0.f;
    #pragma unroll
    for (int i = 0; i < 4; ++i) {
        float4 v = xr[lane + i * 64];
        s += v.x * v.x + v.y * v.y + v.z * v.z + v.w * v.w;
        us4 o; o[0] = cv(v.x); o[1] = cv(v.y); o[2] = cv(v.z); o[3] = cv(v.w);
        *(us4*)(xo + (size_t)(lane + i * 64) * 4) = o;
    }
    #pragma unroll
    for (int o = 32; o; o >>= 1) s += __shfl_xor(s, o);
    if (lane == 0) sq[row] = s;
}

// ---------------------------------------------------------------------------
// bf16 MFMA distance tile -> f16 (shifted by -2048) chunk matrix.
// m97 structure: 128x128 tile, 4 waves (64x64 quadrant each, 4x4 frags of
// 16x16x32), BK=32, double-buffered LINEAR LDS [128][32]hw staged via
// global_load_lds width=16, ONE barrier per K-step.
// MFMA operand values and accumulation order identical to round 6.
// ---------------------------------------------------------------------------
__global__ __launch_bounds__(256) void mfma_dist_kernel(const unsigned short* __restrict__ xb,
                                                        const float* __restrict__ sq,
                                                        _Float16* __restrict__ Dh,
                                                        int r0) {
    __shared__ unsigned short Asm[2][128 * 32];
    __shared__ unsigned short Bsm[2][128 * 32];
    int tid  = threadIdx.x;
    int lane = tid & 63;
    int w    = tid >> 6;
    int rowBase = r0 + blockIdx.y * 128;
    int colBase = blockIdx.x * 128;
    int wrow = (w >> 1) * 64, wcol = (w & 1) * 64;

    f32x4 acc[4][4];
    #pragma unroll
    for (int m = 0; m < 4; ++m)
        #pragma unroll
        for (int n = 0; n < 4; ++n)
            acc[m][n] = (f32x4){0.f, 0.f, 0.f, 0.f};

    // staging: slot s covers LDS bytes s*16 (row s>>2, halfword col (s&3)*8).
    // wave w owns slots [w*128, w*128+128): two 64-lane calls each for A and B.
    int s0 = w * 128 + lane;
    int s1 = s0 + 64;
    const unsigned short* gA0 = xb + (size_t)(rowBase + (s0 >> 2)) * INCH + (s0 & 3) * 8;
    const unsigned short* gA1 = xb + (size_t)(rowBase + (s1 >> 2)) * INCH + (s1 & 3) * 8;
    const unsigned short* gB0 = xb + (size_t)(colBase + (s0 >> 2)) * INCH + (s0 & 3) * 8;
    const unsigned short* gB1 = xb + (size_t)(colBase + (s1 >> 2)) * INCH + (s1 & 3) * 8;
    int ldsc0 = w * 1024;         // halfword index of wave base, call 0
    int ldsc1 = w * 1024 + 512;   // call 1

    // fragment read offsets (linear layout): row ar, k-granule kg = lane>>4
    int kg = lane >> 4;
    int arq = lane & 15;

    // prologue: stage K-step 0 into buf 0
    gload16(gA0, &Asm[0][ldsc0]); gload16(gA1, &Asm[0][ldsc1]);
    gload16(gB0, &Bsm[0][ldsc0]); gload16(gB1, &Bsm[0][ldsc1]);
    __syncthreads();

    #pragma unroll 2
    for (int t = 0; t < 32; ++t) {
        int cur = t & 1;
        if (t < 31) {           // stage K-step t+1 into the other buffer
            int k0 = (t + 1) * 32;
            gload16(gA0 + k0, &Asm[cur ^ 1][ldsc0]);
            gload16(gA1 + k0, &Asm[cur ^ 1][ldsc1]);
            gload16(gB0 + k0, &Bsm[cur ^ 1][ldsc0]);
            gload16(gB1 + k0, &Bsm[cur ^ 1][ldsc1]);
        }
        bf16x8 af[4], bfr[4];
        #pragma unroll
        for (int m = 0; m < 4; ++m) {
            int ar = wrow + m * 16 + arq;
            af[m] = __builtin_bit_cast(bf16x8, *(const uint4*)&Asm[cur][ar * 32 + kg * 8]);
        }
        #pragma unroll
        for (int n = 0; n < 4; ++n) {
            int br = wcol + n * 16 + arq;
            bfr[n] = __builtin_bit_cast(bf16x8, *(const uint4*)&Bsm[cur][br * 32 + kg * 8]);
        }
        #pragma unroll
        for (int m = 0; m < 4; ++m)
            #pragma unroll
            for (int n = 0; n < 4; ++n)
                acc[m][n] = __builtin_amdgcn_mfma_f32_16x16x32_bf16(af[m], bfr[n],
                                                                    acc[m][n], 0, 0, 0);
        __syncthreads();
    }

    int rg = lane >> 4;
    #pragma unroll
    for (int m = 0; m < 4; ++m) {
        int rl = blockIdx.y * 128 + wrow + m * 16 + rg * 4;   // chunk-local row
        float sa0 = sq[r0 + rl + 0], sa1 = sq[r0 + rl + 1];
        float sa2 = sq[r0 + rl + 2], sa3 = sq[r0 + rl + 3];
        #pragma unroll
        for (int n = 0; n < 4; ++n) {
            int c = colBase + wcol + n * 16 + (lane & 15);
            float sb = sq[c];
            _Float16* dp = Dh + (size_t)rl * NPTS + c;
            dp[0 * NPTS] = (_Float16)(sa0 + sb - 2.f * acc[m][n][0] - 2048.f);
            dp[1 * NPTS] = (_Float16)(sa1 + sb - 2.f * acc[m][n][1] - 2048.f);
            dp[2 * NPTS] = (_Float16)(sa2 + sb - 2.f * acc[m][n][2] - 2048.f);
            dp[3 * NPTS] = (_Float16)(sa3 + sb - 2.f * acc[m][n][3] - 2048.f);
        }
    }
}

// ---------------------------------------------------------------------------
// Per row: exact top-16 (on f16 keys) candidate indices.
// One WAVE per row, zero barriers. u32 keys: (sortable_f16 << 13) | col.
// ---------------------------------------------------------------------------
__global__ __launch_bounds__(256) void topk16_kernel(const _Float16* __restrict__ Dh,
                                                     int* __restrict__ cand, int r0) {
    int wid  = threadIdx.x >> 6;
    int lane = threadIdx.x & 63;
    int row  = blockIdx.x * 4 + wid;   // chunk-local row
    const unsigned short* dr = (const unsigned short*)(Dh + (size_t)row * NPTS);

    unsigned kv[16];
    #pragma unroll
    for (int p = 0; p < 16; ++p) kv[p] = 0xffffffffu;

    for (int g = 0; g < 16; ++g) {
        int j0 = (g * 64 + lane) * 8;
        us8 v = *(const us8*)(dr + j0);
        unsigned s[8];
        #pragma unroll
        for (int e = 0; e < 8; ++e) {
            unsigned h = v[e];
            unsigned k16 = (h & 0x8000u) ? (~h & 0xffffu) : (h | 0x8000u);
            s[e] = (k16 << 13) | (unsigned)(j0 + e);
        }
        // Batcher sort-8 ascending (19 CE, branchless)
        CE32(s[0],s[1]); CE32(s[2],s[3]); CE32(s[4],s[5]); CE32(s[6],s[7]);
        CE32(s[0],s[2]); CE32(s[1],s[3]); CE32(s[4],s[6]); CE32(s[5],s[7]);
        CE32(s[1],s[2]); CE32(s[5],s[6]);
        CE32(s[0],s[4]); CE32(s[1],s[5]); CE32(s[2],s[6]); CE32(s[3],s[7]);
        CE32(s[2],s[4]); CE32(s[3],s[5]);
        CE32(s[1],s[2]); CE32(s[3],s[4]); CE32(s[5],s[6]);

        if (s[0] < kv[15]) {
            unsigned M[16];
            #pragma unroll
            for (int q = 0; q < 8; ++q) M[q] = kv[q];
            #pragma unroll
            for (int q = 8; q < 16; ++q) M[q] = min(kv[q], s[15 - q]);
            #pragma unroll
            for (int d = 8; d; d >>= 1)
                #pragma unroll
                for (int q = 0; q < 16; ++q)
                    if (!(q & d)) CE32(M[q], M[q + d]);
            #pragma unroll
            for (int q = 0; q < 16; ++q) kv[q] = M[q];
        }
    }

    #pragma unroll
    for (int st = 0; st < 6; ++st) {
        unsigned M[16];
        #pragma unroll
        for (int q = 0; q < 16; ++q) {
            unsigned pv = (unsigned)__shfl_xor((int)kv[15 - q], 1 << st);
            M[q] = min(kv[q], pv);
        }
        #pragma unroll
        for (int d = 8; d; d >>= 1)
            #pragma unroll
            for (int q = 0; q < 16; ++q)
                if (!(q & d)) CE32(M[q], M[q + d]);
        #pragma unroll
        for (int q = 0; q < 16; ++q) kv[q] = M[q];
    }

    if (lane == 0) {
        #pragma unroll
        for (int r = 0; r < 16; ++r)
            cand[(size_t)(r0 + row) * NCAND + r] = (int)(kv[r] & 0x1fffu);
    }
}

// ---------------------------------------------------------------------------
// Exact fp32 rescore of the 16 candidates -> final top-10
// ---------------------------------------------------------------------------
__global__ __launch_bounds__(64) void rescore_kernel(const float* __restrict__ x,
                                                     const float* __restrict__ sq,
                                                     const int* __restrict__ cand,
                                                     int* __restrict__ nn) {
    int row  = blockIdx.x;
    int lane = threadIdx.x;
    const float4* xr4 = (const float4*)(x + (size_t)row * INCH);
    float4 xr[4];
    #pragma unroll
    for (int q = 0; q < 4; ++q) xr[q] = xr4[lane + 64 * q];
    float sqr = sq[row];

    unsigned long long kv[KNN];
    #pragma unroll
    for (int p = 0; p < KNN; ++p) kv[p] = ~0ull;

    for (int c = 0; c < NCAND; ++c) {
        int cnd = cand[(size_t)row * NCAND + c];
        const float4* xc4 = (const float4*)(x + (size_t)cnd * INCH);
        float dp = 0.f;
        #pragma unroll
        for (int q = 0; q < 4; ++q) {
            float4 vc = xc4[lane + 64 * q];
            dp += xr[q].x * vc.x + xr[q].y * vc.y + xr[q].z * vc.z + xr[q].w * vc.w;
        }
        #pragma unroll
        for (int o = 32; o; o >>= 1) dp += __shfl_xor(dp, o);
        float d = sqr + sq[cnd] - 2.f * dp;
        unsigned u = __float_as_uint(d);
        u = (u & 0x80000000u) ? ~u : (u | 0x80000000u);
        unsigned long long key = ((unsigned long long)u << 32) | (unsigned)cnd;
        if (key < kv[KNN - 1]) {
            unsigned long long cur = key;
            #pragma unroll
            for (int p = 0; p < KNN; ++p) {
                unsigned long long lo = kv[p] < cur ? kv[p] : cur;
                unsigned long long hi = kv[p] < cur ? cur : kv[p];
                kv[p] = lo; cur = hi;
            }
        }
    }
    if (lane < KNN)
        nn[(size_t)row * KNN + lane] = (int)(kv[lane] & 0xffffffffu);
}

// ---------------------------------------------------------------------------
// Dv counts (node degrees)
// ---------------------------------------------------------------------------
__global__ void count_kernel(const int* __restrict__ nn, int* __restrict__ Dv) {
    int t = blockIdx.x * 256 + threadIdx.x;
    if (t < NPTS * KNN) atomicAdd(&Dv[nn[t]], 1);
}

// ---------------------------------------------------------------------------
// C[M x 128] = A[M x Kdim] @ B[Kdim x 128], 64x128 tile, 4x8 per thread
// ---------------------------------------------------------------------------
__global__ __launch_bounds__(256) void gemm_n128_kernel(const float* __restrict__ A,
                                                        const float* __restrict__ Bm,
                                                        float* __restrict__ C,
                                                        int Kdim) {
    __shared__ float As[16][64];
    __shared__ float Bs[16][128];
    int tid = threadIdx.x;
    int tx = tid & 15, ty = tid >> 4;
    int rowBase = blockIdx.x * 64;
    float acc[4][8];
    #pragma unroll
    for (int i = 0; i < 4; ++i)
        #pragma unroll
        for (int j = 0; j < 8; ++j) acc[i][j] = 0.f;

    int lr = tid >> 2, lk = (tid & 3) * 4;
    int bk = tid >> 4, bc = (tid & 15) * 8;

    for (int k0 = 0; k0 < Kdim; k0 += 16) {
        float4 av  = *(const float4*)(A + (size_t)(rowBase + lr) * Kdim + k0 + lk);
        float4 bv0 = *(const float4*)(Bm + (size_t)(k0 + bk) * FDIM + bc);
        float4 bv1 = *(const float4*)(Bm + (size_t)(k0 + bk) * FDIM + bc + 4);
        __syncthreads();
        As[lk + 0][lr] = av.x; As[lk + 1][lr] = av.y;
        As[lk + 2][lr] = av.z; As[lk + 3][lr] = av.w;
        *(float4*)&Bs[bk][bc]     = bv0;
        *(float4*)&Bs[bk][bc + 4] = bv1;
        __syncthreads();
        #pragma unroll
        for (int k = 0; k < 16; ++k) {
            float4 a  = *(const float4*)&As[k][ty * 4];
            float4 c0 = *(const float4*)&Bs[k][tx * 8];
            float4 c1 = *(const float4*)&Bs[k][tx * 8 + 4];
            float ar[4] = {a.x, a.y, a.z, a.w};
            float br[8] = {c0.x, c0.y, c0.z, c0.w, c1.x, c1.y, c1.z, c1.w};
            #pragma unroll
            for (int i = 0; i < 4; ++i)
                #pragma unroll
                for (int j = 0; j < 8; ++j) acc[i][j] += ar[i] * br[j];
        }
    }
    int row = rowBase + ty * 4;
    int col = tx * 8;
    #pragma unroll
    for (int i = 0; i < 4; ++i) {
        float4 o0 = {acc[i][0], acc[i][1], acc[i][2], acc[i][3]};
        float4 o1 = {acc[i][4], acc[i][5], acc[i][6], acc[i][7]};
        *(float4*)(C + (size_t)(row + i) * FDIM + col)     = o0;
        *(float4*)(C + (size_t)(row + i) * FDIM + col + 4) = o1;
    }
}

// ---------------------------------------------------------------------------
// Fused edge mean + scatter: edge e's mean feature is atomically added to
// acc[v] for each of its 10 member nodes (same addend set as before).
// ---------------------------------------------------------------------------
__global__ __launch_bounds__(256) void edge_scatter_kernel(const float* __restrict__ t,
                                                           const int* __restrict__ nn,
                                                           float* __restrict__ acc) {
    int eid = blockIdx.x * 2 + (threadIdx.x >> 7);
    int c = threadIdx.x & 127;
    const int* nnr = nn + (size_t)eid * KNN;
    int idx[KNN];
    #pragma unroll
    for (int k = 0; k < KNN; ++k) idx[k] = nnr[k];
    float s = 0.f;
    #pragma unroll
    for (int k = 0; k < KNN; ++k)
        s += t[(size_t)idx[k] * FDIM + c];
    s *= (1.f / (float)KNN);
    #pragma unroll
    for (int k = 0; k < KNN; ++k)
        atomicAdd(&acc[(size_t)idx[k] * FDIM + c], s);
}

// ---------------------------------------------------------------------------
// node_ft[v][c] = acc[v][c] / max(Dv,1) + bias[c], leaky relu
// ---------------------------------------------------------------------------
__global__ __launch_bounds__(256) void finish_kernel(const float* __restrict__ acc,
                                                     const int* __restrict__ Dv,
                                                     const float* __restrict__ bias,
                                                     float* __restrict__ out) {
    int v = blockIdx.x * 2 + (threadIdx.x >> 7);
    int c = threadIdx.x & 127;
    int cnt = Dv[v];
    float dn = cnt > 1 ? (float)cnt : 1.f;
    float s = acc[(size_t)v * FDIM + c] / dn + bias[c];
    s = (s >= 0.f) ? s : 0.01f * s;
    out[(size_t)v * FDIM + c] = s;
}

// ---------------------------------------------------------------------------
// pooling partials + final
// ---------------------------------------------------------------------------
__global__ __launch_bounds__(256) void pool_kernel(const float* __restrict__ feats,
                                                   float* __restrict__ part) {
    int c = threadIdx.x & 127;
    int half = threadIdx.x >> 7;
    int r0 = blockIdx.x * 128 + half;
    float s = 0.f;
    for (int i = 0; i < 64; ++i)
        s += feats[(size_t)(r0 + 2 * i) * FDIM + c];
    part[(size_t)(blockIdx.x * 2 + half) * FDIM + c] = s;
}

__global__ __launch_bounds__(128) void final_kernel(const float* __restrict__ part,
                                                    const float* __restrict__ fcw,
                                                    const float* __restrict__ fcb,
                                                    float* __restrict__ out) {
    __shared__ float pool[FDIM];
    int c = threadIdx.x;
    float s = 0.f;
    for (int i = 0; i < 128; ++i)
        s += part[(size_t)i * FDIM + c];
    s *= (1.f / (float)NPTS);
    out[2 + (size_t)NPTS * FDIM + c] = s;
    pool[c] = s;
    __syncthreads();
    if (c < 2) {
        float z = fcb[c];
        for (int k = 0; k < FDIM; ++k)
            z += pool[k] * fcw[c * FDIM + k];
        out[c] = 1.f / (1.f + expf(-z));
    }
}

// ---------------------------------------------------------------------------
extern "C" void kernel_launch(void* const* d_in, const int* in_sizes, int n_in,
                              void* d_out, int out_size, void* d_ws, size_t ws_size,
                              hipStream_t stream) {
    const float* x   = (const float*)d_in[0];
    const float* th0 = (const float*)d_in[1];
    const float* b0  = (const float*)d_in[2];
    const float* th1 = (const float*)d_in[3];
    const float* b1  = (const float*)d_in[4];
    const float* fcw = (const float*)d_in[5];
    const float* fcb = (const float*)d_in[6];
    float* out = (float*)d_out;

    char* w = (char*)d_ws;
    size_t off = 0;
    auto alloc = [&](size_t bytes) -> void* {
        void* p = w + off;
        off = (off + bytes + 255) & ~(size_t)255;
        return p;
    };
    float* sq    = (float*)alloc(NPTS * 4);
    int*   nn    = (int*)  alloc(NPTS * KNN * 4);
    int*   Dv    = (int*)  alloc(NPTS * 4);
    int*   cand  = (int*)  alloc((size_t)NPTS * NCAND * 4);
    float* tbuf  = (float*)alloc((size_t)NPTS * FDIM * 4);
    float* hbuf  = (float*)alloc((size_t)NPTS * FDIM * 4);
    float* accb  = (float*)alloc((size_t)NPTS * FDIM * 4);
    float* part  = (float*)alloc(128 * FDIM * 4);
    unsigned short* xbf = (unsigned short*)alloc((size_t)NPTS * INCH * 2);

    size_t rem = ws_size > off ? ws_size - off : 0;
    long long chMax = (long long)(rem / ((size_t)NPTS * 2));
    int CH = (int)(chMax > 8192 ? 8192 : chMax);
    CH &= ~127;
    if (CH < 128) CH = 128;
    _Float16* Dh = (_Float16*)(w + off);

    hipMemsetAsync(Dv, 0, NPTS * 4, stream);
    prep_kernel<<<NPTS / 4, 256, 0, stream>>>(x, sq, xbf);

    for (int r0 = 0; r0 < NPTS; r0 += CH) {
        int ch = NPTS - r0 < CH ? NPTS - r0 : CH;
        mfma_dist_kernel<<<dim3(NPTS / 128, ch / 128), 256, 0, stream>>>(xbf, sq, Dh, r0);
        topk16_kernel<<<ch / 4, 256, 0, stream>>>(Dh, cand, r0);
    }

    rescore_kernel<<<NPTS, 64, 0, stream>>>(x, sq, cand, nn);

    count_kernel<<<(NPTS * KNN + 255) / 256, 256, 0, stream>>>(nn, Dv);

    // layer 0
    gemm_n128_kernel<<<NPTS / 64, 256, 0, stream>>>(x, th0, tbuf, INCH);
    hipMemsetAsync(accb, 0, (size_t)NPTS * FDIM * 4, stream);
    edge_scatter_kernel<<<NPTS / 2, 256, 0, stream>>>(tbuf, nn, accb);
    finish_kernel<<<NPTS / 2, 256, 0, stream>>>(accb, Dv, b0, hbuf);

    // layer 1 -> feats written directly into out+2
    gemm_n128_kernel<<<NPTS / 64, 256, 0, stream>>>(hbuf, th1, tbuf, FDIM);
    hipMemsetAsync(accb, 0, (size_t)NPTS * FDIM * 4, stream);
    edge_scatter_kernel<<<NPTS / 2, 256, 0, stream>>>(tbuf, nn, accb);
    finish_kernel<<<NPTS / 2, 256, 0, stream>>>(accb, Dv, b1, out + 2);

    pool_kernel<<<64, 256, 0, stream>>>(out + 2, part);
    final_kernel<<<1, 128, 0, stream>>>(part, fcw, fcb, out);
}

// Round 8
// 610.932 us; speedup vs baseline: 4.3467x; 1.0349x over previous
//
#include <hip/hip_runtime.h>
#include <math.h>

#define NPTS  8192
#define INCH  1024
#define FDIM  128
#define KNN   10
#define NCAND 16

typedef __attribute__((ext_vector_type(8))) __bf16          bf16x8;
typedef __attribute__((ext_vector_type(4))) float           f32x4;
typedef __attribute__((ext_vector_type(8))) unsigned short  us8;
typedef __attribute__((ext_vector_type(4))) unsigned short  us4;

// u32 compare-exchange: a=min, b=max  (v_min_u32 + v_max_u32)
#define CE32(a,b) do { unsigned lo_ = min((a),(b)); unsigned hi_ = max((a),(b)); \
                       (a)=lo_; (b)=hi_; } while(0)

// async global->LDS, 16 bytes per lane (dest = wave-uniform base + lane*16)
__device__ __forceinline__ void gload16(const void* g, void* l) {
    __builtin_amdgcn_global_load_lds(
        (const __attribute__((address_space(1))) unsigned int*)g,
        (__attribute__((address_space(3))) unsigned int*)l, 16, 0, 0);
}

// ---------------------------------------------------------------------------
// prep: sq[i] = sum x[i][d]^2 (bit-identical order) AND xb = bf16(x).
// ---------------------------------------------------------------------------
__global__ __launch_bounds__(256) void prep_kernel(const float* __restrict__ x,
                                                   float* __restrict__ sq,
                                                   unsigned short* __restrict__ xb) {
    int wave = threadIdx.x >> 6;
    int lane = threadIdx.x & 63;
    int row  = blockIdx.x * 4 + wave;
    const float4* xr = (const float4*)(x + (size_t)row * INCH);
    unsigned short* xo = xb + (size_t)row * INCH;
    auto cv = [](float f) -> unsigned short {
        unsigned u = __float_as_uint(f);
        return (unsigned short)((u + 0x7fffu + ((u >> 16) & 1u)) >> 16);
    };
    float s = 0.f;
    #pragma unroll
    for (int i = 0; i < 4; ++i) {
        float4 v = xr[lane + i * 64];
        s += v.x * v.x + v.y * v.y + v.z * v.z + v.w * v.w;
        us4 o; o[0] = cv(v.x); o[1] = cv(v.y); o[2] = cv(v.z); o[3] = cv(v.w);
        *(us4*)(xo + (size_t)(lane + i * 64) * 4) = o;
    }
    #pragma unroll
    for (int o = 32; o; o >>= 1) s += __shfl_xor(s, o);
    if (lane == 0) sq[row] = s;
}

// ---------------------------------------------------------------------------
// bf16 MFMA distance tile -> f16 (shifted by -2048) chunk matrix.
// 128x128 tile, 4 waves x (64x64 quadrant, 4x4 frags of 16x16x32), BK=32,
// double-buffered LINEAR LDS staged via global_load_lds width=16 with
// PRE-SWIZZLED global source:  LDS slot (row r, granule g) holds global
// k-granule (g - (r>>1)) & 3;  reads use gp = (kg + (ar>>1)) & 3.
// -> ds_read bank conflicts bounded at 2-way (free);  MFMA operand values
// and accumulation order bit-identical to rounds 5-7.
// ---------------------------------------------------------------------------
__global__ __launch_bounds__(256) void mfma_dist_kernel(const unsigned short* __restrict__ xb,
                                                        const float* __restrict__ sq,
                                                        _Float16* __restrict__ Dh,
                                                        int r0) {
    __shared__ unsigned short Asm[2][128 * 32];
    __shared__ unsigned short Bsm[2][128 * 32];
    int tid  = threadIdx.x;
    int lane = tid & 63;
    int w    = tid >> 6;
    int rowBase = r0 + blockIdx.y * 128;
    int colBase = blockIdx.x * 128;
    int wrow = (w >> 1) * 64, wcol = (w & 1) * 64;

    f32x4 acc[4][4];
    #pragma unroll
    for (int m = 0; m < 4; ++m)
        #pragma unroll
        for (int n = 0; n < 4; ++n)
            acc[m][n] = (f32x4){0.f, 0.f, 0.f, 0.f};

    // staging slots: wave w owns slots [w*128, w*128+128), two calls per matrix
    int s0 = w * 128 + lane;
    int s1 = s0 + 64;
    int r0s = s0 >> 2, g0s = s0 & 3, d0s = (g0s - (r0s >> 1)) & 3;
    int r1s = s1 >> 2, g1s = s1 & 3, d1s = (g1s - (r1s >> 1)) & 3;
    const unsigned short* gA0 = xb + (size_t)(rowBase + r0s) * INCH + d0s * 8;
    const unsigned short* gA1 = xb + (size_t)(rowBase + r1s) * INCH + d1s * 8;
    const unsigned short* gB0 = xb + (size_t)(colBase + r0s) * INCH + d0s * 8;
    const unsigned short* gB1 = xb + (size_t)(colBase + r1s) * INCH + d1s * 8;
    int ldsc0 = w * 1024;         // halfword index of wave base, call 0
    int ldsc1 = w * 1024 + 512;   // call 1

    int kg = lane >> 4;
    int arq = lane & 15;

    // prologue: stage K-step 0 into buf 0
    gload16(gA0, &Asm[0][ldsc0]); gload16(gA1, &Asm[0][ldsc1]);
    gload16(gB0, &Bsm[0][ldsc0]); gload16(gB1, &Bsm[0][ldsc1]);
    __syncthreads();

    #pragma unroll 2
    for (int t = 0; t < 32; ++t) {
        int cur = t & 1;
        if (t < 31) {           // stage K-step t+1 into the other buffer
            int k0 = (t + 1) * 32;
            gload16(gA0 + k0, &Asm[cur ^ 1][ldsc0]);
            gload16(gA1 + k0, &Asm[cur ^ 1][ldsc1]);
            gload16(gB0 + k0, &Bsm[cur ^ 1][ldsc0]);
            gload16(gB1 + k0, &Bsm[cur ^ 1][ldsc1]);
        }
        bf16x8 af[4], bfr[4];
        #pragma unroll
        for (int m = 0; m < 4; ++m) {
            int ar = wrow + m * 16 + arq;
            int gp = (kg + (ar >> 1)) & 3;
            af[m] = __builtin_bit_cast(bf16x8, *(const uint4*)&Asm[cur][ar * 32 + gp * 8]);
        }
        #pragma unroll
        for (int n = 0; n < 4; ++n) {
            int br = wcol + n * 16 + arq;
            int gp = (kg + (br >> 1)) & 3;
            bfr[n] = __builtin_bit_cast(bf16x8, *(const uint4*)&Bsm[cur][br * 32 + gp * 8]);
        }
        #pragma unroll
        for (int m = 0; m < 4; ++m)
            #pragma unroll
            for (int n = 0; n < 4; ++n)
                acc[m][n] = __builtin_amdgcn_mfma_f32_16x16x32_bf16(af[m], bfr[n],
                                                                    acc[m][n], 0, 0, 0);
        __syncthreads();
    }

    int rg = lane >> 4;
    #pragma unroll
    for (int m = 0; m < 4; ++m) {
        int rl = blockIdx.y * 128 + wrow + m * 16 + rg * 4;   // chunk-local row
        float sa0 = sq[r0 + rl + 0], sa1 = sq[r0 + rl + 1];
        float sa2 = sq[r0 + rl + 2], sa3 = sq[r0 + rl + 3];
        #pragma unroll
        for (int n = 0; n < 4; ++n) {
            int c = colBase + wcol + n * 16 + (lane & 15);
            float sb = sq[c];
            _Float16* dp = Dh + (size_t)rl * NPTS + c;
            dp[0 * NPTS] = (_Float16)(sa0 + sb - 2.f * acc[m][n][0] - 2048.f);
            dp[1 * NPTS] = (_Float16)(sa1 + sb - 2.f * acc[m][n][1] - 2048.f);
            dp[2 * NPTS] = (_Float16)(sa2 + sb - 2.f * acc[m][n][2] - 2048.f);
            dp[3 * NPTS] = (_Float16)(sa3 + sb - 2.f * acc[m][n][3] - 2048.f);
        }
    }
}

// ---------------------------------------------------------------------------
// Per row: exact top-16 (on f16 keys) candidate indices.
// One WAVE per row, zero barriers. u32 keys: (sortable_f16 << 13) | col.
// ---------------------------------------------------------------------------
__global__ __launch_bounds__(256) void topk16_kernel(const _Float16* __restrict__ Dh,
                                                     int* __restrict__ cand, int r0) {
    int wid  = threadIdx.x >> 6;
    int lane = threadIdx.x & 63;
    int row  = blockIdx.x * 4 + wid;   // chunk-local row
    const unsigned short* dr = (const unsigned short*)(Dh + (size_t)row * NPTS);

    unsigned kv[16];
    #pragma unroll
    for (int p = 0; p < 16; ++p) kv[p] = 0xffffffffu;

    for (int g = 0; g < 16; ++g) {
        int j0 = (g * 64 + lane) * 8;
        us8 v = *(const us8*)(dr + j0);
        unsigned s[8];
        #pragma unroll
        for (int e = 0; e < 8; ++e) {
            unsigned h = v[e];
            unsigned k16 = (h & 0x8000u) ? (~h & 0xffffu) : (h | 0x8000u);
            s[e] = (k16 << 13) | (unsigned)(j0 + e);
        }
        // Batcher sort-8 ascending (19 CE, branchless)
        CE32(s[0],s[1]); CE32(s[2],s[3]); CE32(s[4],s[5]); CE32(s[6],s[7]);
        CE32(s[0],s[2]); CE32(s[1],s[3]); CE32(s[4],s[6]); CE32(s[5],s[7]);
        CE32(s[1],s[2]); CE32(s[5],s[6]);
        CE32(s[0],s[4]); CE32(s[1],s[5]); CE32(s[2],s[6]); CE32(s[3],s[7]);
        CE32(s[2],s[4]); CE32(s[3],s[5]);
        CE32(s[1],s[2]); CE32(s[3],s[4]); CE32(s[5],s[6]);

        if (s[0] < kv[15]) {
            unsigned M[16];
            #pragma unroll
            for (int q = 0; q < 8; ++q) M[q] = kv[q];
            #pragma unroll
            for (int q = 8; q < 16; ++q) M[q] = min(kv[q], s[15 - q]);
            #pragma unroll
            for (int d = 8; d; d >>= 1)
                #pragma unroll
                for (int q = 0; q < 16; ++q)
                    if (!(q & d)) CE32(M[q], M[q + d]);
            #pragma unroll
            for (int q = 0; q < 16; ++q) kv[q] = M[q];
        }
    }

    #pragma unroll
    for (int st = 0; st < 6; ++st) {
        unsigned M[16];
        #pragma unroll
        for (int q = 0; q < 16; ++q) {
            unsigned pv = (unsigned)__shfl_xor((int)kv[15 - q], 1 << st);
            M[q] = min(kv[q], pv);
        }
        #pragma unroll
        for (int d = 8; d; d >>= 1)
            #pragma unroll
            for (int q = 0; q < 16; ++q)
                if (!(q & d)) CE32(M[q], M[q + d]);
        #pragma unroll
        for (int q = 0; q < 16; ++q) kv[q] = M[q];
    }

    if (lane == 0) {
        #pragma unroll
        for (int r = 0; r < 16; ++r)
            cand[(size_t)(r0 + row) * NCAND + r] = (int)(kv[r] & 0x1fffu);
    }
}

// ---------------------------------------------------------------------------
// Exact fp32 rescore of the 16 candidates -> final top-10 + Dv counts.
// 4 waves per row: wave w handles candidates {w, w+4, w+8, w+12}; 16 keys
// merged in LDS; wave 0 bitonic-sorts across lanes (u64 keys, same ordering
// and tie-break as prior rounds -> identical nn).
// ---------------------------------------------------------------------------
__global__ __launch_bounds__(256) void rescore_kernel(const float* __restrict__ x,
                                                      const float* __restrict__ sq,
                                                      const int* __restrict__ cand,
                                                      int* __restrict__ nn,
                                                      int* __restrict__ Dv) {
    __shared__ unsigned long long keys[NCAND];
    int row  = blockIdx.x;
    int wv   = threadIdx.x >> 6;
    int lane = threadIdx.x & 63;
    const float4* xr4 = (const float4*)(x + (size_t)row * INCH);
    float4 xr[4];
    #pragma unroll
    for (int q = 0; q < 4; ++q) xr[q] = xr4[lane + 64 * q];
    float sqr = sq[row];

    #pragma unroll
    for (int i = 0; i < 4; ++i) {
        int c = wv + i * 4;
        int cnd = cand[(size_t)row * NCAND + c];
        const float4* xc4 = (const float4*)(x + (size_t)cnd * INCH);
        float dp = 0.f;
        #pragma unroll
        for (int q = 0; q < 4; ++q) {
            float4 vc = xc4[lane + 64 * q];
            dp += xr[q].x * vc.x + xr[q].y * vc.y + xr[q].z * vc.z + xr[q].w * vc.w;
        }
        #pragma unroll
        for (int o = 32; o; o >>= 1) dp += __shfl_xor(dp, o);
        if (lane == 0) {
            float d = sqr + sq[cnd] - 2.f * dp;
            unsigned u = __float_as_uint(d);
            u = (u & 0x80000000u) ? ~u : (u | 0x80000000u);
            keys[c] = ((unsigned long long)u << 32) | (unsigned)cnd;
        }
    }
    __syncthreads();

    if (wv == 0) {
        unsigned long long v = (lane < NCAND) ? keys[lane] : ~0ull;
        // full-wave bitonic sort ascending (64 lanes; pads are max)
        #pragma unroll
        for (int k = 2; k <= 64; k <<= 1) {
            #pragma unroll
            for (int j = k >> 1; j > 0; j >>= 1) {
                unsigned long long pv = __shfl_xor(v, j);
                bool lower = (lane & j) == 0;
                bool asc   = (lane & k) == 0;
                unsigned long long mn = v < pv ? v : pv;
                unsigned long long mx = v < pv ? pv : v;
                v = (lower == asc) ? mn : mx;
            }
        }
        if (lane < KNN) {
            int idx = (int)(v & 0xffffffffu);
            nn[(size_t)row * KNN + lane] = idx;
            atomicAdd(&Dv[idx], 1);
        }
    }
}

// ---------------------------------------------------------------------------
// C[M x 128] = A[M x Kdim] @ B[Kdim x 128], 64x128 tile, 4x8 per thread
// ---------------------------------------------------------------------------
__global__ __launch_bounds__(256) void gemm_n128_kernel(const float* __restrict__ A,
                                                        const float* __restrict__ Bm,
                                                        float* __restrict__ C,
                                                        int Kdim) {
    __shared__ float As[16][64];
    __shared__ float Bs[16][128];
    int tid = threadIdx.x;
    int tx = tid & 15, ty = tid >> 4;
    int rowBase = blockIdx.x * 64;
    float acc[4][8];
    #pragma unroll
    for (int i = 0; i < 4; ++i)
        #pragma unroll
        for (int j = 0; j < 8; ++j) acc[i][j] = 0.f;

    int lr = tid >> 2, lk = (tid & 3) * 4;
    int bk = tid >> 4, bc = (tid & 15) * 8;

    for (int k0 = 0; k0 < Kdim; k0 += 16) {
        float4 av  = *(const float4*)(A + (size_t)(rowBase + lr) * Kdim + k0 + lk);
        float4 bv0 = *(const float4*)(Bm + (size_t)(k0 + bk) * FDIM + bc);
        float4 bv1 = *(const float4*)(Bm + (size_t)(k0 + bk) * FDIM + bc + 4);
        __syncthreads();
        As[lk + 0][lr] = av.x; As[lk + 1][lr] = av.y;
        As[lk + 2][lr] = av.z; As[lk + 3][lr] = av.w;
        *(float4*)&Bs[bk][bc]     = bv0;
        *(float4*)&Bs[bk][bc + 4] = bv1;
        __syncthreads();
        #pragma unroll
        for (int k = 0; k < 16; ++k) {
            float4 a  = *(const float4*)&As[k][ty * 4];
            float4 c0 = *(const float4*)&Bs[k][tx * 8];
            float4 c1 = *(const float4*)&Bs[k][tx * 8 + 4];
            float ar[4] = {a.x, a.y, a.z, a.w};
            float br[8] = {c0.x, c0.y, c0.z, c0.w, c1.x, c1.y, c1.z, c1.w};
            #pragma unroll
            for (int i = 0; i < 4; ++i)
                #pragma unroll
                for (int j = 0; j < 8; ++j) acc[i][j] += ar[i] * br[j];
        }
    }
    int row = rowBase + ty * 4;
    int col = tx * 8;
    #pragma unroll
    for (int i = 0; i < 4; ++i) {
        float4 o0 = {acc[i][0], acc[i][1], acc[i][2], acc[i][3]};
        float4 o1 = {acc[i][4], acc[i][5], acc[i][6], acc[i][7]};
        *(float4*)(C + (size_t)(row + i) * FDIM + col)     = o0;
        *(float4*)(C + (size_t)(row + i) * FDIM + col + 4) = o1;
    }
}

// ---------------------------------------------------------------------------
// Fused edge mean + scatter
// ---------------------------------------------------------------------------
__global__ __launch_bounds__(256) void edge_scatter_kernel(const float* __restrict__ t,
                                                           const int* __restrict__ nn,
                                                           float* __restrict__ acc) {
    int eid = blockIdx.x * 2 + (threadIdx.x >> 7);
    int c = threadIdx.x & 127;
    const int* nnr = nn + (size_t)eid * KNN;
    int idx[KNN];
    #pragma unroll
    for (int k = 0; k < KNN; ++k) idx[k] = nnr[k];
    float s = 0.f;
    #pragma unroll
    for (int k = 0; k < KNN; ++k)
        s += t[(size_t)idx[k] * FDIM + c];
    s *= (1.f / (float)KNN);
    #pragma unroll
    for (int k = 0; k < KNN; ++k)
        atomicAdd(&acc[(size_t)idx[k] * FDIM + c], s);
}

// ---------------------------------------------------------------------------
// node_ft[v][c] = acc[v][c] / max(Dv,1) + bias[c], leaky relu
// ---------------------------------------------------------------------------
__global__ __launch_bounds__(256) void finish_kernel(const float* __restrict__ acc,
                                                     const int* __restrict__ Dv,
                                                     const float* __restrict__ bias,
                                                     float* __restrict__ out) {
    int v = blockIdx.x * 2 + (threadIdx.x >> 7);
    int c = threadIdx.x & 127;
    int cnt = Dv[v];
    float dn = cnt > 1 ? (float)cnt : 1.f;
    float s = acc[(size_t)v * FDIM + c] / dn + bias[c];
    s = (s >= 0.f) ? s : 0.01f * s;
    out[(size_t)v * FDIM + c] = s;
}

// ---------------------------------------------------------------------------
// pooling partials + final
// ---------------------------------------------------------------------------
__global__ __launch_bounds__(256) void pool_kernel(const float* __restrict__ feats,
                                                   float* __restrict__ part) {
    int c = threadIdx.x & 127;
    int half = threadIdx.x >> 7;
    int r0 = blockIdx.x * 128 + half;
    float s = 0.f;
    for (int i = 0; i < 64; ++i)
        s += feats[(size_t)(r0 + 2 * i) * FDIM + c];
    part[(size_t)(blockIdx.x * 2 + half) * FDIM + c] = s;
}

__global__ __launch_bounds__(128) void final_kernel(const float* __restrict__ part,
                                                    const float* __restrict__ fcw,
                                                    const float* __restrict__ fcb,
                                                    float* __restrict__ out) {
    __shared__ float pool[FDIM];
    int c = threadIdx.x;
    float s = 0.f;
    for (int i = 0; i < 128; ++i)
        s += part[(size_t)i * FDIM + c];
    s *= (1.f / (float)NPTS);
    out[2 + (size_t)NPTS * FDIM + c] = s;
    pool[c] = s;
    __syncthreads();
    if (c < 2) {
        float z = fcb[c];
        for (int k = 0; k < FDIM; ++k)
            z += pool[k] * fcw[c * FDIM + k];
        out[c] = 1.f / (1.f + expf(-z));
    }
}

// ---------------------------------------------------------------------------
extern "C" void kernel_launch(void* const* d_in, const int* in_sizes, int n_in,
                              void* d_out, int out_size, void* d_ws, size_t ws_size,
                              hipStream_t stream) {
    const float* x   = (const float*)d_in[0];
    const float* th0 = (const float*)d_in[1];
    const float* b0  = (const float*)d_in[2];
    const float* th1 = (const float*)d_in[3];
    const float* b1  = (const float*)d_in[4];
    const float* fcw = (const float*)d_in[5];
    const float* fcb = (const float*)d_in[6];
    float* out = (float*)d_out;

    char* w = (char*)d_ws;
    size_t off = 0;
    auto alloc = [&](size_t bytes) -> void* {
        void* p = w + off;
        off = (off + bytes + 255) & ~(size_t)255;
        return p;
    };
    float* sq    = (float*)alloc(NPTS * 4);
    int*   nn    = (int*)  alloc(NPTS * KNN * 4);
    int*   Dv    = (int*)  alloc(NPTS * 4);
    int*   cand  = (int*)  alloc((size_t)NPTS * NCAND * 4);
    float* tbuf  = (float*)alloc((size_t)NPTS * FDIM * 4);
    float* hbuf  = (float*)alloc((size_t)NPTS * FDIM * 4);
    float* accb  = (float*)alloc((size_t)NPTS * FDIM * 4);
    float* part  = (float*)alloc(128 * FDIM * 4);
    unsigned short* xbf = (unsigned short*)alloc((size_t)NPTS * INCH * 2);

    size_t rem = ws_size > off ? ws_size - off : 0;
    long long chMax = (long long)(rem / ((size_t)NPTS * 2));
    int CH = (int)(chMax > 8192 ? 8192 : chMax);
    CH &= ~127;
    if (CH < 128) CH = 128;
    _Float16* Dh = (_Float16*)(w + off);

    hipMemsetAsync(Dv, 0, NPTS * 4, stream);
    prep_kernel<<<NPTS / 4, 256, 0, stream>>>(x, sq, xbf);

    for (int r0 = 0; r0 < NPTS; r0 += CH) {
        int ch = NPTS - r0 < CH ? NPTS - r0 : CH;
        mfma_dist_kernel<<<dim3(NPTS / 128, ch / 128), 256, 0, stream>>>(xbf, sq, Dh, r0);
        topk16_kernel<<<ch / 4, 256, 0, stream>>>(Dh, cand, r0);
    }

    rescore_kernel<<<NPTS, 256, 0, stream>>>(x, sq, cand, nn, Dv);

    // layer 0
    gemm_n128_kernel<<<NPTS / 64, 256, 0, stream>>>(x, th0, tbuf, INCH);
    hipMemsetAsync(accb, 0, (size_t)NPTS * FDIM * 4, stream);
    edge_scatter_kernel<<<NPTS / 2, 256, 0, stream>>>(tbuf, nn, accb);
    finish_kernel<<<NPTS / 2, 256, 0, stream>>>(accb, Dv, b0, hbuf);

    // layer 1 -> feats written directly into out+2
    gemm_n128_kernel<<<NPTS / 64, 256, 0, stream>>>(hbuf, th1, tbuf, FDIM);
    hipMemsetAsync(accb, 0, (size_t)NPTS * FDIM * 4, stream);
    edge_scatter_kernel<<<NPTS / 2, 256, 0, stream>>>(tbuf, nn, accb);
    finish_kernel<<<NPTS / 2, 256, 0, stream>>>(accb, Dv, b1, out + 2);

    pool_kernel<<<64, 256, 0, stream>>>(out + 2, part);
    final_kernel<<<1, 128, 0, stream>>>(part, fcw, fcb, out);
}

// Round 9
// 557.574 us; speedup vs baseline: 4.7627x; 1.0957x over previous
//
#include <hip/hip_runtime.h>
#include <math.h>

#define NPTS  8192
#define INCH  1024
#define FDIM  128
#define KNN   10
#define NCAND 16
#define NTILE (NPTS / 128)   // 64

typedef __attribute__((ext_vector_type(8))) __bf16          bf16x8;
typedef __attribute__((ext_vector_type(4))) float           f32x4;
typedef __attribute__((ext_vector_type(8))) unsigned short  us8;
typedef __attribute__((ext_vector_type(4))) unsigned short  us4;
typedef __attribute__((ext_vector_type(4))) _Float16        f16x4;

// u32 compare-exchange: a=min, b=max  (v_min_u32 + v_max_u32)
#define CE32(a,b) do { unsigned lo_ = min((a),(b)); unsigned hi_ = max((a),(b)); \
                       (a)=lo_; (b)=hi_; } while(0)

// async global->LDS, 16 bytes per lane (dest = wave-uniform base + lane*16)
__device__ __forceinline__ void gload16(const void* g, void* l) {
    __builtin_amdgcn_global_load_lds(
        (const __attribute__((address_space(1))) unsigned int*)g,
        (__attribute__((address_space(3))) unsigned int*)l, 16, 0, 0);
}

// ---------------------------------------------------------------------------
// prep: sq[i] = sum x[i][d]^2 (bit-identical order) AND xb = bf16(x).
// ---------------------------------------------------------------------------
__global__ __launch_bounds__(256) void prep_kernel(const float* __restrict__ x,
                                                   float* __restrict__ sq,
                                                   unsigned short* __restrict__ xb) {
    int wave = threadIdx.x >> 6;
    int lane = threadIdx.x & 63;
    int row  = blockIdx.x * 4 + wave;
    const float4* xr = (const float4*)(x + (size_t)row * INCH);
    unsigned short* xo = xb + (size_t)row * INCH;
    auto cv = [](float f) -> unsigned short {
        unsigned u = __float_as_uint(f);
        return (unsigned short)((u + 0x7fffu + ((u >> 16) & 1u)) >> 16);
    };
    float s = 0.f;
    #pragma unroll
    for (int i = 0; i < 4; ++i) {
        float4 v = xr[lane + i * 64];
        s += v.x * v.x + v.y * v.y + v.z * v.z + v.w * v.w;
        us4 o; o[0] = cv(v.x); o[1] = cv(v.y); o[2] = cv(v.z); o[3] = cv(v.w);
        *(us4*)(xo + (size_t)(lane + i * 64) * 4) = o;
    }
    #pragma unroll
    for (int o = 32; o; o >>= 1) s += __shfl_xor(s, o);
    if (lane == 0) sq[row] = s;
}

// ---------------------------------------------------------------------------
// bf16 MFMA distance tile -> f16 (shifted by -2048) chunk matrix.
// 128x128 tile, 4 waves x (64x64 quadrant, 4x4 frags of 16x16x32), BK=32,
// double-buffered LINEAR LDS staged via global_load_lds width=16 with
// PRE-SWIZZLED global source (bank conflicts 0, verified round 8).
// SYM=true: linear blockIdx -> upper-triangle tile pair (by <= bx); each
// off-diagonal block also writes the transposed tile (same bits: MFMA k-tree
// order is role-symmetric, fp add commutes).  SYM=false: rectangular chunk
// grid (fallback when ws can't hold full D).
// ---------------------------------------------------------------------------
template <bool SYM>
__global__ __launch_bounds__(256) void mfma_dist_kernel(const unsigned short* __restrict__ xb,
                                                        const float* __restrict__ sq,
                                                        _Float16* __restrict__ Dh,
                                                        int r0) {
    __shared__ unsigned short Asm[2][128 * 32];
    __shared__ unsigned short Bsm[2][128 * 32];
    int bx, byy;
    if (SYM) {
        int t = blockIdx.x;
        bx = (int)((sqrtf(8.0f * (float)t + 1.0f) - 1.0f) * 0.5f);
        while ((bx + 1) * (bx + 2) / 2 <= t) ++bx;
        while (bx * (bx + 1) / 2 > t) --bx;
        byy = t - bx * (bx + 1) / 2;          // byy <= bx
    } else {
        bx = blockIdx.x; byy = blockIdx.y;
    }
    int tid  = threadIdx.x;
    int lane = tid & 63;
    int w    = tid >> 6;
    int rowBase = r0 + byy * 128;
    int colBase = bx * 128;
    int wrow = (w >> 1) * 64, wcol = (w & 1) * 64;

    f32x4 acc[4][4];
    #pragma unroll
    for (int m = 0; m < 4; ++m)
        #pragma unroll
        for (int n = 0; n < 4; ++n)
            acc[m][n] = (f32x4){0.f, 0.f, 0.f, 0.f};

    // staging slots: wave w owns slots [w*128, w*128+128), two calls per matrix
    int s0 = w * 128 + lane;
    int s1 = s0 + 64;
    int r0s = s0 >> 2, g0s = s0 & 3, d0s = (g0s - (r0s >> 1)) & 3;
    int r1s = s1 >> 2, g1s = s1 & 3, d1s = (g1s - (r1s >> 1)) & 3;
    const unsigned short* gA0 = xb + (size_t)(rowBase + r0s) * INCH + d0s * 8;
    const unsigned short* gA1 = xb + (size_t)(rowBase + r1s) * INCH + d1s * 8;
    const unsigned short* gB0 = xb + (size_t)(colBase + r0s) * INCH + d0s * 8;
    const unsigned short* gB1 = xb + (size_t)(colBase + r1s) * INCH + d1s * 8;
    int ldsc0 = w * 1024;         // halfword index of wave base, call 0
    int ldsc1 = w * 1024 + 512;   // call 1

    int kg = lane >> 4;
    int arq = lane & 15;

    // prologue: stage K-step 0 into buf 0
    gload16(gA0, &Asm[0][ldsc0]); gload16(gA1, &Asm[0][ldsc1]);
    gload16(gB0, &Bsm[0][ldsc0]); gload16(gB1, &Bsm[0][ldsc1]);
    __syncthreads();

    #pragma unroll 2
    for (int t = 0; t < 32; ++t) {
        int cur = t & 1;
        if (t < 31) {           // stage K-step t+1 into the other buffer
            int k0 = (t + 1) * 32;
            gload16(gA0 + k0, &Asm[cur ^ 1][ldsc0]);
            gload16(gA1 + k0, &Asm[cur ^ 1][ldsc1]);
            gload16(gB0 + k0, &Bsm[cur ^ 1][ldsc0]);
            gload16(gB1 + k0, &Bsm[cur ^ 1][ldsc1]);
        }
        bf16x8 af[4], bfr[4];
        #pragma unroll
        for (int m = 0; m < 4; ++m) {
            int ar = wrow + m * 16 + arq;
            int gp = (kg + (ar >> 1)) & 3;
            af[m] = __builtin_bit_cast(bf16x8, *(const uint4*)&Asm[cur][ar * 32 + gp * 8]);
        }
        #pragma unroll
        for (int n = 0; n < 4; ++n) {
            int br = wcol + n * 16 + arq;
            int gp = (kg + (br >> 1)) & 3;
            bfr[n] = __builtin_bit_cast(bf16x8, *(const uint4*)&Bsm[cur][br * 32 + gp * 8]);
        }
        #pragma unroll
        for (int m = 0; m < 4; ++m)
            #pragma unroll
            for (int n = 0; n < 4; ++n)
                acc[m][n] = __builtin_amdgcn_mfma_f32_16x16x32_bf16(af[m], bfr[n],
                                                                    acc[m][n], 0, 0, 0);
        __syncthreads();
    }

    int rg = lane >> 4;
    bool doT = SYM && (byy != bx);
    #pragma unroll
    for (int m = 0; m < 4; ++m) {
        int rl = byy * 128 + wrow + m * 16 + rg * 4;   // chunk-local row
        float sa0 = sq[r0 + rl + 0], sa1 = sq[r0 + rl + 1];
        float sa2 = sq[r0 + rl + 2], sa3 = sq[r0 + rl + 3];
        #pragma unroll
        for (int n = 0; n < 4; ++n) {
            int c = colBase + wcol + n * 16 + (lane & 15);
            float sb = sq[c];
            _Float16 h0 = (_Float16)(sa0 + sb - 2.f * acc[m][n][0] - 2048.f);
            _Float16 h1 = (_Float16)(sa1 + sb - 2.f * acc[m][n][1] - 2048.f);
            _Float16 h2 = (_Float16)(sa2 + sb - 2.f * acc[m][n][2] - 2048.f);
            _Float16 h3 = (_Float16)(sa3 + sb - 2.f * acc[m][n][3] - 2048.f);
            _Float16* dp = Dh + (size_t)rl * NPTS + c;
            dp[0 * NPTS] = h0;
            dp[1 * NPTS] = h1;
            dp[2 * NPTS] = h2;
            dp[3 * NPTS] = h3;
            if (doT) {
                f16x4 tv; tv[0] = h0; tv[1] = h1; tv[2] = h2; tv[3] = h3;
                *(f16x4*)(Dh + (size_t)c * NPTS + (r0 + rl)) = tv;
            }
        }
    }
}

// ---------------------------------------------------------------------------
// Per row: exact top-16 (on f16 keys) candidate indices.
// One WAVE per row, zero barriers. u32 keys: (sortable_f16 << 13) | col.
// ---------------------------------------------------------------------------
__global__ __launch_bounds__(256) void topk16_kernel(const _Float16* __restrict__ Dh,
                                                     int* __restrict__ cand, int r0) {
    int wid  = threadIdx.x >> 6;
    int lane = threadIdx.x & 63;
    int row  = blockIdx.x * 4 + wid;   // chunk-local row
    const unsigned short* dr = (const unsigned short*)(Dh + (size_t)row * NPTS);

    unsigned kv[16];
    #pragma unroll
    for (int p = 0; p < 16; ++p) kv[p] = 0xffffffffu;

    for (int g = 0; g < 16; ++g) {
        int j0 = (g * 64 + lane) * 8;
        us8 v = *(const us8*)(dr + j0);
        unsigned s[8];
        #pragma unroll
        for (int e = 0; e < 8; ++e) {
            unsigned h = v[e];
            unsigned k16 = (h & 0x8000u) ? (~h & 0xffffu) : (h | 0x8000u);
            s[e] = (k16 << 13) | (unsigned)(j0 + e);
        }
        // Batcher sort-8 ascending (19 CE, branchless)
        CE32(s[0],s[1]); CE32(s[2],s[3]); CE32(s[4],s[5]); CE32(s[6],s[7]);
        CE32(s[0],s[2]); CE32(s[1],s[3]); CE32(s[4],s[6]); CE32(s[5],s[7]);
        CE32(s[1],s[2]); CE32(s[5],s[6]);
        CE32(s[0],s[4]); CE32(s[1],s[5]); CE32(s[2],s[6]); CE32(s[3],s[7]);
        CE32(s[2],s[4]); CE32(s[3],s[5]);
        CE32(s[1],s[2]); CE32(s[3],s[4]); CE32(s[5],s[6]);

        if (s[0] < kv[15]) {
            unsigned M[16];
            #pragma unroll
            for (int q = 0; q < 8; ++q) M[q] = kv[q];
            #pragma unroll
            for (int q = 8; q < 16; ++q) M[q] = min(kv[q], s[15 - q]);
            #pragma unroll
            for (int d = 8; d; d >>= 1)
                #pragma unroll
                for (int q = 0; q < 16; ++q)
                    if (!(q & d)) CE32(M[q], M[q + d]);
            #pragma unroll
            for (int q = 0; q < 16; ++q) kv[q] = M[q];
        }
    }

    #pragma unroll
    for (int st = 0; st < 6; ++st) {
        unsigned M[16];
        #pragma unroll
        for (int q = 0; q < 16; ++q) {
            unsigned pv = (unsigned)__shfl_xor((int)kv[15 - q], 1 << st);
            M[q] = min(kv[q], pv);
        }
        #pragma unroll
        for (int d = 8; d; d >>= 1)
            #pragma unroll
            for (int q = 0; q < 16; ++q)
                if (!(q & d)) CE32(M[q], M[q + d]);
        #pragma unroll
        for (int q = 0; q < 16; ++q) kv[q] = M[q];
    }

    if (lane == 0) {
        #pragma unroll
        for (int r = 0; r < 16; ++r)
            cand[(size_t)(r0 + row) * NCAND + r] = (int)(kv[r] & 0x1fffu);
    }
}

// ---------------------------------------------------------------------------
// Exact fp32 rescore of the 16 candidates -> final top-10 + Dv counts.
// ---------------------------------------------------------------------------
__global__ __launch_bounds__(256) void rescore_kernel(const float* __restrict__ x,
                                                      const float* __restrict__ sq,
                                                      const int* __restrict__ cand,
                                                      int* __restrict__ nn,
                                                      int* __restrict__ Dv) {
    __shared__ unsigned long long keys[NCAND];
    int row  = blockIdx.x;
    int wv   = threadIdx.x >> 6;
    int lane = threadIdx.x & 63;
    const float4* xr4 = (const float4*)(x + (size_t)row * INCH);
    float4 xr[4];
    #pragma unroll
    for (int q = 0; q < 4; ++q) xr[q] = xr4[lane + 64 * q];
    float sqr = sq[row];

    #pragma unroll
    for (int i = 0; i < 4; ++i) {
        int c = wv + i * 4;
        int cnd = cand[(size_t)row * NCAND + c];
        const float4* xc4 = (const float4*)(x + (size_t)cnd * INCH);
        float dp = 0.f;
        #pragma unroll
        for (int q = 0; q < 4; ++q) {
            float4 vc = xc4[lane + 64 * q];
            dp += xr[q].x * vc.x + xr[q].y * vc.y + xr[q].z * vc.z + xr[q].w * vc.w;
        }
        #pragma unroll
        for (int o = 32; o; o >>= 1) dp += __shfl_xor(dp, o);
        if (lane == 0) {
            float d = sqr + sq[cnd] - 2.f * dp;
            unsigned u = __float_as_uint(d);
            u = (u & 0x80000000u) ? ~u : (u | 0x80000000u);
            keys[c] = ((unsigned long long)u << 32) | (unsigned)cnd;
        }
    }
    __syncthreads();

    if (wv == 0) {
        unsigned long long v = (lane < NCAND) ? keys[lane] : ~0ull;
        #pragma unroll
        for (int k = 2; k <= 64; k <<= 1) {
            #pragma unroll
            for (int j = k >> 1; j > 0; j >>= 1) {
                unsigned long long pv = __shfl_xor(v, j);
                bool lower = (lane & j) == 0;
                bool asc   = (lane & k) == 0;
                unsigned long long mn = v < pv ? v : pv;
                unsigned long long mx = v < pv ? pv : v;
                v = (lower == asc) ? mn : mx;
            }
        }
        if (lane < KNN) {
            int idx = (int)(v & 0xffffffffu);
            nn[(size_t)row * KNN + lane] = idx;
            atomicAdd(&Dv[idx], 1);
        }
    }
}

// ---------------------------------------------------------------------------
// C[M x 128] = A[M x Kdim] @ B[Kdim x 128], 64x128 tile, 4x8 per thread
// ---------------------------------------------------------------------------
__global__ __launch_bounds__(256) void gemm_n128_kernel(const float* __restrict__ A,
                                                        const float* __restrict__ Bm,
                                                        float* __restrict__ C,
                                                        int Kdim) {
    __shared__ float As[16][64];
    __shared__ float Bs[16][128];
    int tid = threadIdx.x;
    int tx = tid & 15, ty = tid >> 4;
    int rowBase = blockIdx.x * 64;
    float acc[4][8];
    #pragma unroll
    for (int i = 0; i < 4; ++i)
        #pragma unroll
        for (int j = 0; j < 8; ++j) acc[i][j] = 0.f;

    int lr = tid >> 2, lk = (tid & 3) * 4;
    int bk = tid >> 4, bc = (tid & 15) * 8;

    for (int k0 = 0; k0 < Kdim; k0 += 16) {
        float4 av  = *(const float4*)(A + (size_t)(rowBase + lr) * Kdim + k0 + lk);
        float4 bv0 = *(const float4*)(Bm + (size_t)(k0 + bk) * FDIM + bc);
        float4 bv1 = *(const float4*)(Bm + (size_t)(k0 + bk) * FDIM + bc + 4);
        __syncthreads();
        As[lk + 0][lr] = av.x; As[lk + 1][lr] = av.y;
        As[lk + 2][lr] = av.z; As[lk + 3][lr] = av.w;
        *(float4*)&Bs[bk][bc]     = bv0;
        *(float4*)&Bs[bk][bc + 4] = bv1;
        __syncthreads();
        #pragma unroll
        for (int k = 0; k < 16; ++k) {
            float4 a  = *(const float4*)&As[k][ty * 4];
            float4 c0 = *(const float4*)&Bs[k][tx * 8];
            float4 c1 = *(const float4*)&Bs[k][tx * 8 + 4];
            float ar[4] = {a.x, a.y, a.z, a.w};
            float br[8] = {c0.x, c0.y, c0.z, c0.w, c1.x, c1.y, c1.z, c1.w};
            #pragma unroll
            for (int i = 0; i < 4; ++i)
                #pragma unroll
                for (int j = 0; j < 8; ++j) acc[i][j] += ar[i] * br[j];
        }
    }
    int row = rowBase + ty * 4;
    int col = tx * 8;
    #pragma unroll
    for (int i = 0; i < 4; ++i) {
        float4 o0 = {acc[i][0], acc[i][1], acc[i][2], acc[i][3]};
        float4 o1 = {acc[i][4], acc[i][5], acc[i][6], acc[i][7]};
        *(float4*)(C + (size_t)(row + i) * FDIM + col)     = o0;
        *(float4*)(C + (size_t)(row + i) * FDIM + col + 4) = o1;
    }
}

// ---------------------------------------------------------------------------
// Fused edge mean + scatter
// ---------------------------------------------------------------------------
__global__ __launch_bounds__(256) void edge_scatter_kernel(const float* __restrict__ t,
                                                           const int* __restrict__ nn,
                                                           float* __restrict__ acc) {
    int eid = blockIdx.x * 2 + (threadIdx.x >> 7);
    int c = threadIdx.x & 127;
    const int* nnr = nn + (size_t)eid * KNN;
    int idx[KNN];
    #pragma unroll
    for (int k = 0; k < KNN; ++k) idx[k] = nnr[k];
    float s = 0.f;
    #pragma unroll
    for (int k = 0; k < KNN; ++k)
        s += t[(size_t)idx[k] * FDIM + c];
    s *= (1.f / (float)KNN);
    #pragma unroll
    for (int k = 0; k < KNN; ++k)
        atomicAdd(&acc[(size_t)idx[k] * FDIM + c], s);
}

// ---------------------------------------------------------------------------
// node_ft[v][c] = acc[v][c] / max(Dv,1) + bias[c], leaky relu
// ---------------------------------------------------------------------------
__global__ __launch_bounds__(256) void finish_kernel(const float* __restrict__ acc,
                                                     const int* __restrict__ Dv,
                                                     const float* __restrict__ bias,
                                                     float* __restrict__ out) {
    int v = blockIdx.x * 2 + (threadIdx.x >> 7);
    int c = threadIdx.x & 127;
    int cnt = Dv[v];
    float dn = cnt > 1 ? (float)cnt : 1.f;
    float s = acc[(size_t)v * FDIM + c] / dn + bias[c];
    s = (s >= 0.f) ? s : 0.01f * s;
    out[(size_t)v * FDIM + c] = s;
}

// ---------------------------------------------------------------------------
// pooling partials + final
// ---------------------------------------------------------------------------
__global__ __launch_bounds__(256) void pool_kernel(const float* __restrict__ feats,
                                                   float* __restrict__ part) {
    int c = threadIdx.x & 127;
    int half = threadIdx.x >> 7;
    int r0 = blockIdx.x * 128 + half;
    float s = 0.f;
    for (int i = 0; i < 64; ++i)
        s += feats[(size_t)(r0 + 2 * i) * FDIM + c];
    part[(size_t)(blockIdx.x * 2 + half) * FDIM + c] = s;
}

__global__ __launch_bounds__(128) void final_kernel(const float* __restrict__ part,
                                                    const float* __restrict__ fcw,
                                                    const float* __restrict__ fcb,
                                                    float* __restrict__ out) {
    __shared__ float pool[FDIM];
    int c = threadIdx.x;
    float s = 0.f;
    for (int i = 0; i < 128; ++i)
        s += part[(size_t)i * FDIM + c];
    s *= (1.f / (float)NPTS);
    out[2 + (size_t)NPTS * FDIM + c] = s;
    pool[c] = s;
    __syncthreads();
    if (c < 2) {
        float z = fcb[c];
        for (int k = 0; k < FDIM; ++k)
            z += pool[k] * fcw[c * FDIM + k];
        out[c] = 1.f / (1.f + expf(-z));
    }
}

// ---------------------------------------------------------------------------
extern "C" void kernel_launch(void* const* d_in, const int* in_sizes, int n_in,
                              void* d_out, int out_size, void* d_ws, size_t ws_size,
                              hipStream_t stream) {
    const float* x   = (const float*)d_in[0];
    const float* th0 = (const float*)d_in[1];
    const float* b0  = (const float*)d_in[2];
    const float* th1 = (const float*)d_in[3];
    const float* b1  = (const float*)d_in[4];
    const float* fcw = (const float*)d_in[5];
    const float* fcb = (const float*)d_in[6];
    float* out = (float*)d_out;

    char* w = (char*)d_ws;
    size_t off = 0;
    auto alloc = [&](size_t bytes) -> void* {
        void* p = w + off;
        off = (off + bytes + 255) & ~(size_t)255;
        return p;
    };
    float* sq    = (float*)alloc(NPTS * 4);
    int*   nn    = (int*)  alloc(NPTS * KNN * 4);
    int*   Dv    = (int*)  alloc(NPTS * 4);
    int*   cand  = (int*)  alloc((size_t)NPTS * NCAND * 4);
    float* tbuf  = (float*)alloc((size_t)NPTS * FDIM * 4);
    float* hbuf  = (float*)alloc((size_t)NPTS * FDIM * 4);
    float* accb  = (float*)alloc((size_t)NPTS * FDIM * 4);
    float* part  = (float*)alloc(128 * FDIM * 4);
    unsigned short* xbf = (unsigned short*)alloc((size_t)NPTS * INCH * 2);

    size_t rem = ws_size > off ? ws_size - off : 0;
    long long chMax = (long long)(rem / ((size_t)NPTS * 2));
    int CH = (int)(chMax > 8192 ? 8192 : chMax);
    CH &= ~127;
    if (CH < 128) CH = 128;
    _Float16* Dh = (_Float16*)(w + off);

    hipMemsetAsync(Dv, 0, NPTS * 4, stream);
    prep_kernel<<<NPTS / 4, 256, 0, stream>>>(x, sq, xbf);

    if (CH >= NPTS) {
        // symmetric path: 2080 upper-triangle tile pairs, one dispatch
        mfma_dist_kernel<true><<<NTILE * (NTILE + 1) / 2, 256, 0, stream>>>(xbf, sq, Dh, 0);
        topk16_kernel<<<NPTS / 4, 256, 0, stream>>>(Dh, cand, 0);
    } else {
        for (int r0 = 0; r0 < NPTS; r0 += CH) {
            int ch = NPTS - r0 < CH ? NPTS - r0 : CH;
            mfma_dist_kernel<false><<<dim3(NTILE, ch / 128), 256, 0, stream>>>(xbf, sq, Dh, r0);
            topk16_kernel<<<ch / 4, 256, 0, stream>>>(Dh, cand, r0);
        }
    }

    rescore_kernel<<<NPTS, 256, 0, stream>>>(x, sq, cand, nn, Dv);

    // layer 0
    gemm_n128_kernel<<<NPTS / 64, 256, 0, stream>>>(x, th0, tbuf, INCH);
    hipMemsetAsync(accb, 0, (size_t)NPTS * FDIM * 4, stream);
    edge_scatter_kernel<<<NPTS / 2, 256, 0, stream>>>(tbuf, nn, accb);
    finish_kernel<<<NPTS / 2, 256, 0, stream>>>(accb, Dv, b0, hbuf);

    // layer 1 -> feats written directly into out+2
    gemm_n128_kernel<<<NPTS / 64, 256, 0, stream>>>(hbuf, th1, tbuf, FDIM);
    hipMemsetAsync(accb, 0, (size_t)NPTS * FDIM * 4, stream);
    edge_scatter_kernel<<<NPTS / 2, 256, 0, stream>>>(tbuf, nn, accb);
    finish_kernel<<<NPTS / 2, 256, 0, stream>>>(accb, Dv, b1, out + 2);

    pool_kernel<<<64, 256, 0, stream>>>(out + 2, part);
    final_kernel<<<1, 128, 0, stream>>>(part, fcw, fcb, out);
}

// Round 10
// 431.808 us; speedup vs baseline: 6.1498x; 1.2913x over previous
//
#include <hip/hip_runtime.h>
#include <math.h>

#define NPTS  8192
#define INCH  1024
#define FDIM  128
#define KNN   10
#define NCAND 16
#define NTILE (NPTS / 128)   // 64

typedef __attribute__((ext_vector_type(8))) __bf16          bf16x8;
typedef __attribute__((ext_vector_type(4))) float           f32x4;
typedef __attribute__((ext_vector_type(8))) unsigned short  us8;
typedef __attribute__((ext_vector_type(4))) unsigned short  us4;
typedef __attribute__((ext_vector_type(4))) _Float16        f16x4;

// u32 compare-exchange: a=min, b=max  (v_min_u32 + v_max_u32)
#define CE32(a,b) do { unsigned lo_ = min((a),(b)); unsigned hi_ = max((a),(b)); \
                       (a)=lo_; (b)=hi_; } while(0)

__device__ __forceinline__ unsigned short f2bf(float f) {
    unsigned u = __float_as_uint(f);
    return (unsigned short)((u + 0x7fffu + ((u >> 16) & 1u)) >> 16);
}

// async global->LDS, 16 bytes per lane (dest = wave-uniform base + lane*16)
__device__ __forceinline__ void gload16(const void* g, void* l) {
    __builtin_amdgcn_global_load_lds(
        (const __attribute__((address_space(1))) unsigned int*)g,
        (__attribute__((address_space(3))) unsigned int*)l, 16, 0, 0);
}

// ---------------------------------------------------------------------------
// prep: sq[i] = sum x[i][d]^2 (bit-identical order) AND xb = bf16(x).
// ---------------------------------------------------------------------------
__global__ __launch_bounds__(256) void prep_kernel(const float* __restrict__ x,
                                                   float* __restrict__ sq,
                                                   unsigned short* __restrict__ xb) {
    int wave = threadIdx.x >> 6;
    int lane = threadIdx.x & 63;
    int row  = blockIdx.x * 4 + wave;
    const float4* xr = (const float4*)(x + (size_t)row * INCH);
    unsigned short* xo = xb + (size_t)row * INCH;
    float s = 0.f;
    #pragma unroll
    for (int i = 0; i < 4; ++i) {
        float4 v = xr[lane + i * 64];
        s += v.x * v.x + v.y * v.y + v.z * v.z + v.w * v.w;
        us4 o; o[0] = f2bf(v.x); o[1] = f2bf(v.y); o[2] = f2bf(v.z); o[3] = f2bf(v.w);
        *(us4*)(xo + (size_t)(lane + i * 64) * 4) = o;
    }
    #pragma unroll
    for (int o = 32; o; o >>= 1) s += __shfl_xor(s, o);
    if (lane == 0) sq[row] = s;
}

// ---------------------------------------------------------------------------
// theta transpose+convert: th[K][128] f32 -> out[128][K] bf16 (64x64 LDS tiles)
// ---------------------------------------------------------------------------
__global__ __launch_bounds__(256) void thT_kernel(const float* __restrict__ th,
                                                  unsigned short* __restrict__ out,
                                                  int K) {
    __shared__ unsigned short T[64][68];
    int k0 = blockIdx.x * 64;
    int n0 = blockIdx.y * 64;
    int t = threadIdx.x;
    int r  = t >> 2;            // k offset 0..63
    int cs = (t & 3) * 16;      // col seg
    const float* src = th + (size_t)(k0 + r) * FDIM + n0 + cs;
    #pragma unroll
    for (int i = 0; i < 4; ++i) {
        float4 v = *(const float4*)(src + i * 4);
        us4 o; o[0] = f2bf(v.x); o[1] = f2bf(v.y); o[2] = f2bf(v.z); o[3] = f2bf(v.w);
        *(us4*)&T[r][cs + i * 4] = o;
    }
    __syncthreads();
    int n  = t >> 2;            // col within tile
    int ks = (t & 3) * 16;
    unsigned short* dst = out + (size_t)(n0 + n) * K + k0 + ks;
    #pragma unroll
    for (int i = 0; i < 16; ++i)
        dst[i] = T[ks + i][n];
}

// ---------------------------------------------------------------------------
// bf16 MFMA distance tile -> f16 ( max(d,0)*0.25 ) matrix.
// 128x128 tile, 4 waves x (64x64 quadrant, 4x4 frags 16x16x32), BK=32,
// double-buffered LINEAR LDS staged via global_load_lds width=16 with
// PRE-SWIZZLED global source (bank conflicts 0, verified round 8).
// SYM=true: upper-triangle tile pairs; transposed tile goes through a padded
// LDS buffer so global writes are per-lane 128B-contiguous (no partial-line
// RMW amplification).  MFMA values/accum order identical to rounds 5-9.
// ---------------------------------------------------------------------------
union SharedU {
    struct { unsigned short A[2][4096], B[2][4096]; } s;   // 32 KB staging
    _Float16 T[128 * 136];                                  // 34.8 KB transpose
};

template <bool SYM>
__global__ __launch_bounds__(256) void mfma_dist_kernel(const unsigned short* __restrict__ xb,
                                                        const float* __restrict__ sq,
                                                        _Float16* __restrict__ Dh,
                                                        int r0) {
    __shared__ SharedU smem;
    int bx, byy;
    if (SYM) {
        int t = blockIdx.x;
        bx = (int)((sqrtf(8.0f * (float)t + 1.0f) - 1.0f) * 0.5f);
        while ((bx + 1) * (bx + 2) / 2 <= t) ++bx;
        while (bx * (bx + 1) / 2 > t) --bx;
        byy = t - bx * (bx + 1) / 2;          // byy <= bx
    } else {
        bx = blockIdx.x; byy = blockIdx.y;
    }
    int tid  = threadIdx.x;
    int lane = tid & 63;
    int w    = tid >> 6;
    int rowBase = r0 + byy * 128;
    int colBase = bx * 128;
    int wrow = (w >> 1) * 64, wcol = (w & 1) * 64;

    f32x4 acc[4][4];
    #pragma unroll
    for (int m = 0; m < 4; ++m)
        #pragma unroll
        for (int n = 0; n < 4; ++n)
            acc[m][n] = (f32x4){0.f, 0.f, 0.f, 0.f};

    int s0 = w * 128 + lane;
    int s1 = s0 + 64;
    int r0s = s0 >> 2, g0s = s0 & 3, d0s = (g0s - (r0s >> 1)) & 3;
    int r1s = s1 >> 2, g1s = s1 & 3, d1s = (g1s - (r1s >> 1)) & 3;
    const unsigned short* gA0 = xb + (size_t)(rowBase + r0s) * INCH + d0s * 8;
    const unsigned short* gA1 = xb + (size_t)(rowBase + r1s) * INCH + d1s * 8;
    const unsigned short* gB0 = xb + (size_t)(colBase + r0s) * INCH + d0s * 8;
    const unsigned short* gB1 = xb + (size_t)(colBase + r1s) * INCH + d1s * 8;
    int ldsc0 = w * 1024;
    int ldsc1 = w * 1024 + 512;

    int kg = lane >> 4;
    int arq = lane & 15;

    gload16(gA0, &smem.s.A[0][ldsc0]); gload16(gA1, &smem.s.A[0][ldsc1]);
    gload16(gB0, &smem.s.B[0][ldsc0]); gload16(gB1, &smem.s.B[0][ldsc1]);
    __syncthreads();

    #pragma unroll 2
    for (int t = 0; t < 32; ++t) {
        int cur = t & 1;
        if (t < 31) {
            int k0 = (t + 1) * 32;
            gload16(gA0 + k0, &smem.s.A[cur ^ 1][ldsc0]);
            gload16(gA1 + k0, &smem.s.A[cur ^ 1][ldsc1]);
            gload16(gB0 + k0, &smem.s.B[cur ^ 1][ldsc0]);
            gload16(gB1 + k0, &smem.s.B[cur ^ 1][ldsc1]);
        }
        bf16x8 af[4], bfr[4];
        #pragma unroll
        for (int m = 0; m < 4; ++m) {
            int ar = wrow + m * 16 + arq;
            int gp = (kg + (ar >> 1)) & 3;
            af[m] = __builtin_bit_cast(bf16x8, *(const uint4*)&smem.s.A[cur][ar * 32 + gp * 8]);
        }
        #pragma unroll
        for (int n = 0; n < 4; ++n) {
            int br = wcol + n * 16 + arq;
            int gp = (kg + (br >> 1)) & 3;
            bfr[n] = __builtin_bit_cast(bf16x8, *(const uint4*)&smem.s.B[cur][br * 32 + gp * 8]);
        }
        #pragma unroll
        for (int m = 0; m < 4; ++m)
            #pragma unroll
            for (int n = 0; n < 4; ++n)
                acc[m][n] = __builtin_amdgcn_mfma_f32_16x16x32_bf16(af[m], bfr[n],
                                                                    acc[m][n], 0, 0, 0);
        __syncthreads();
    }

    int rg = lane >> 4;
    bool doT = SYM && (byy != bx);
    #pragma unroll
    for (int m = 0; m < 4; ++m) {
        int rloc = wrow + m * 16 + rg * 4;      // tile-local row
        int rl = byy * 128 + rloc;              // chunk-local row
        float sa0 = sq[r0 + rl + 0], sa1 = sq[r0 + rl + 1];
        float sa2 = sq[r0 + rl + 2], sa3 = sq[r0 + rl + 3];
        #pragma unroll
        for (int n = 0; n < 4; ++n) {
            int cl = wcol + n * 16 + (lane & 15);
            int c = colBase + cl;
            float sb = sq[c];
            _Float16 h0 = (_Float16)fmaxf((sa0 + sb - 2.f * acc[m][n][0]) * 0.25f, 0.f);
            _Float16 h1 = (_Float16)fmaxf((sa1 + sb - 2.f * acc[m][n][1]) * 0.25f, 0.f);
            _Float16 h2 = (_Float16)fmaxf((sa2 + sb - 2.f * acc[m][n][2]) * 0.25f, 0.f);
            _Float16 h3 = (_Float16)fmaxf((sa3 + sb - 2.f * acc[m][n][3]) * 0.25f, 0.f);
            _Float16* dp = Dh + (size_t)rl * NPTS + c;
            dp[0 * NPTS] = h0;
            dp[1 * NPTS] = h1;
            dp[2 * NPTS] = h2;
            dp[3 * NPTS] = h3;
            if (doT) {
                f16x4 tv; tv[0] = h0; tv[1] = h1; tv[2] = h2; tv[3] = h3;
                *(f16x4*)&smem.T[cl * 136 + rloc] = tv;
            }
        }
    }
    if (doT) {
        __syncthreads();
        int cl = tid >> 1, half = tid & 1;
        const unsigned short* src = (const unsigned short*)&smem.T[cl * 136 + half * 64];
        unsigned short* gdst = (unsigned short*)Dh +
                               (size_t)(colBase + cl) * NPTS + byy * 128 + half * 64;
        #pragma unroll
        for (int i = 0; i < 8; ++i)
            *(uint4*)(gdst + i * 8) = *(const uint4*)(src + i * 8);
    }
}

// ---------------------------------------------------------------------------
// Per row: exact top-16 (on f16 keys) candidate indices.
// One WAVE per row, zero barriers. All stored f16 >= 0 -> raw bits sortable:
// u32 key = (bits << 13) | col   (one v_lshl_or per element).
// ---------------------------------------------------------------------------
__global__ __launch_bounds__(256) void topk16_kernel(const _Float16* __restrict__ Dh,
                                                     int* __restrict__ cand, int r0) {
    int wid  = threadIdx.x >> 6;
    int lane = threadIdx.x & 63;
    int row  = blockIdx.x * 4 + wid;   // chunk-local row
    const unsigned short* dr = (const unsigned short*)(Dh + (size_t)row * NPTS);

    unsigned kv[16];
    #pragma unroll
    for (int p = 0; p < 16; ++p) kv[p] = 0xffffffffu;

    for (int g = 0; g < 16; ++g) {
        int j0 = (g * 64 + lane) * 8;
        us8 v = *(const us8*)(dr + j0);
        unsigned s[8];
        #pragma unroll
        for (int e = 0; e < 8; ++e)
            s[e] = ((unsigned)v[e] << 13) | (unsigned)(j0 + e);
        // Batcher sort-8 ascending (19 CE, branchless)
        CE32(s[0],s[1]); CE32(s[2],s[3]); CE32(s[4],s[5]); CE32(s[6],s[7]);
        CE32(s[0],s[2]); CE32(s[1],s[3]); CE32(s[4],s[6]); CE32(s[5],s[7]);
        CE32(s[1],s[2]); CE32(s[5],s[6]);
        CE32(s[0],s[4]); CE32(s[1],s[5]); CE32(s[2],s[6]); CE32(s[3],s[7]);
        CE32(s[2],s[4]); CE32(s[3],s[5]);
        CE32(s[1],s[2]); CE32(s[3],s[4]); CE32(s[5],s[6]);

        if (s[0] < kv[15]) {
            unsigned M[16];
            #pragma unroll
            for (int q = 0; q < 8; ++q) M[q] = kv[q];
            #pragma unroll
            for (int q = 8; q < 16; ++q) M[q] = min(kv[q], s[15 - q]);
            #pragma unroll
            for (int d = 8; d; d >>= 1)
                #pragma unroll
                for (int q = 0; q < 16; ++q)
                    if (!(q & d)) CE32(M[q], M[q + d]);
            #pragma unroll
            for (int q = 0; q < 16; ++q) kv[q] = M[q];
        }
    }

    #pragma unroll
    for (int st = 0; st < 6; ++st) {
        unsigned M[16];
        #pragma unroll
        for (int q = 0; q < 16; ++q) {
            unsigned pv = (unsigned)__shfl_xor((int)kv[15 - q], 1 << st);
            M[q] = min(kv[q], pv);
        }
        #pragma unroll
        for (int d = 8; d; d >>= 1)
            #pragma unroll
            for (int q = 0; q < 16; ++q)
                if (!(q & d)) CE32(M[q], M[q + d]);
        #pragma unroll
        for (int q = 0; q < 16; ++q) kv[q] = M[q];
    }

    if (lane == 0) {
        #pragma unroll
        for (int r = 0; r < 16; ++r)
            cand[(size_t)(r0 + row) * NCAND + r] = (int)(kv[r] & 0x1fffu);
    }
}

// ---------------------------------------------------------------------------
// Exact fp32 rescore of the 16 candidates -> final top-10 + Dv counts.
// ---------------------------------------------------------------------------
__global__ __launch_bounds__(256) void rescore_kernel(const float* __restrict__ x,
                                                      const float* __restrict__ sq,
                                                      const int* __restrict__ cand,
                                                      int* __restrict__ nn,
                                                      int* __restrict__ Dv) {
    __shared__ unsigned long long keys[NCAND];
    int row  = blockIdx.x;
    int wv   = threadIdx.x >> 6;
    int lane = threadIdx.x & 63;
    const float4* xr4 = (const float4*)(x + (size_t)row * INCH);
    float4 xr[4];
    #pragma unroll
    for (int q = 0; q < 4; ++q) xr[q] = xr4[lane + 64 * q];
    float sqr = sq[row];

    #pragma unroll
    for (int i = 0; i < 4; ++i) {
        int c = wv + i * 4;
        int cnd = cand[(size_t)row * NCAND + c];
        const float4* xc4 = (const float4*)(x + (size_t)cnd * INCH);
        float dp = 0.f;
        #pragma unroll
        for (int q = 0; q < 4; ++q) {
            float4 vc = xc4[lane + 64 * q];
            dp += xr[q].x * vc.x + xr[q].y * vc.y + xr[q].z * vc.z + xr[q].w * vc.w;
        }
        #pragma unroll
        for (int o = 32; o; o >>= 1) dp += __shfl_xor(dp, o);
        if (lane == 0) {
            float d = sqr + sq[cnd] - 2.f * dp;
            unsigned u = __float_as_uint(d);
            u = (u & 0x80000000u) ? ~u : (u | 0x80000000u);
            keys[c] = ((unsigned long long)u << 32) | (unsigned)cnd;
        }
    }
    __syncthreads();

    if (wv == 0) {
        unsigned long long v = (lane < NCAND) ? keys[lane] : ~0ull;
        #pragma unroll
        for (int k = 2; k <= 64; k <<= 1) {
            #pragma unroll
            for (int j = k >> 1; j > 0; j >>= 1) {
                unsigned long long pv = __shfl_xor(v, j);
                bool lower = (lane & j) == 0;
                bool asc   = (lane & k) == 0;
                unsigned long long mn = v < pv ? v : pv;
                unsigned long long mx = v < pv ? pv : v;
                v = (lower == asc) ? mn : mx;
            }
        }
        if (lane < KNN) {
            int idx = (int)(v & 0xffffffffu);
            nn[(size_t)row * KNN + lane] = idx;
            atomicAdd(&Dv[idx], 1);
        }
    }
}

// ---------------------------------------------------------------------------
// bf16 MFMA GEMM:  C[M x 128] = A[M x KD] @ Bt[128 x KD]^T   (Bt = theta^T)
// Clone of the dist kernel structure (staging, swizzle, fragments); epilogue
// writes f32.  nk = KD/32 K-steps.  Grid: M/128 blocks.
// ---------------------------------------------------------------------------
__global__ __launch_bounds__(256) void mfma_gemm_kernel(const unsigned short* __restrict__ A,
                                                        const unsigned short* __restrict__ Bt,
                                                        float* __restrict__ C,
                                                        int KD, int nk) {
    __shared__ unsigned short Asm[2][4096];
    __shared__ unsigned short Bsm[2][4096];
    int tid  = threadIdx.x;
    int lane = tid & 63;
    int w    = tid >> 6;
    int rowBase = blockIdx.x * 128;
    int wrow = (w >> 1) * 64, wcol = (w & 1) * 64;

    f32x4 acc[4][4];
    #pragma unroll
    for (int m = 0; m < 4; ++m)
        #pragma unroll
        for (int n = 0; n < 4; ++n)
            acc[m][n] = (f32x4){0.f, 0.f, 0.f, 0.f};

    int s0 = w * 128 + lane;
    int s1 = s0 + 64;
    int r0s = s0 >> 2, g0s = s0 & 3, d0s = (g0s - (r0s >> 1)) & 3;
    int r1s = s1 >> 2, g1s = s1 & 3, d1s = (g1s - (r1s >> 1)) & 3;
    const unsigned short* gA0 = A + (size_t)(rowBase + r0s) * KD + d0s * 8;
    const unsigned short* gA1 = A + (size_t)(rowBase + r1s) * KD + d1s * 8;
    const unsigned short* gB0 = Bt + (size_t)r0s * KD + d0s * 8;
    const unsigned short* gB1 = Bt + (size_t)r1s * KD + d1s * 8;
    int ldsc0 = w * 1024;
    int ldsc1 = w * 1024 + 512;

    int kg = lane >> 4;
    int arq = lane & 15;

    gload16(gA0, &Asm[0][ldsc0]); gload16(gA1, &Asm[0][ldsc1]);
    gload16(gB0, &Bsm[0][ldsc0]); gload16(gB1, &Bsm[0][ldsc1]);
    __syncthreads();

    for (int t = 0; t < nk; ++t) {
        int cur = t & 1;
        if (t < nk - 1) {
            int k0 = (t + 1) * 32;
            gload16(gA0 + k0, &Asm[cur ^ 1][ldsc0]);
            gload16(gA1 + k0, &Asm[cur ^ 1][ldsc1]);
            gload16(gB0 + k0, &Bsm[cur ^ 1][ldsc0]);
            gload16(gB1 + k0, &Bsm[cur ^ 1][ldsc1]);
        }
        bf16x8 af[4], bfr[4];
        #pragma unroll
        for (int m = 0; m < 4; ++m) {
            int ar = wrow + m * 16 + arq;
            int gp = (kg + (ar >> 1)) & 3;
            af[m] = __builtin_bit_cast(bf16x8, *(const uint4*)&Asm[cur][ar * 32 + gp * 8]);
        }
        #pragma unroll
        for (int n = 0; n < 4; ++n) {
            int br = wcol + n * 16 + arq;
            int gp = (kg + (br >> 1)) & 3;
            bfr[n] = __builtin_bit_cast(bf16x8, *(const uint4*)&Bsm[cur][br * 32 + gp * 8]);
        }
        #pragma unroll
        for (int m = 0; m < 4; ++m)
            #pragma unroll
            for (int n = 0; n < 4; ++n)
                acc[m][n] = __builtin_amdgcn_mfma_f32_16x16x32_bf16(af[m], bfr[n],
                                                                    acc[m][n], 0, 0, 0);
        __syncthreads();
    }

    int rg = lane >> 4;
    #pragma unroll
    for (int m = 0; m < 4; ++m) {
        int rl = rowBase + wrow + m * 16 + rg * 4;
        #pragma unroll
        for (int n = 0; n < 4; ++n) {
            int c = wcol + n * 16 + (lane & 15);
            float* cp = C + (size_t)rl * FDIM + c;
            cp[0 * FDIM] = acc[m][n][0];
            cp[1 * FDIM] = acc[m][n][1];
            cp[2 * FDIM] = acc[m][n][2];
            cp[3 * FDIM] = acc[m][n][3];
        }
    }
}

// ---------------------------------------------------------------------------
// Fused edge mean + scatter
// ---------------------------------------------------------------------------
__global__ __launch_bounds__(256) void edge_scatter_kernel(const float* __restrict__ t,
                                                           const int* __restrict__ nn,
                                                           float* __restrict__ acc) {
    int eid = blockIdx.x * 2 + (threadIdx.x >> 7);
    int c = threadIdx.x & 127;
    const int* nnr = nn + (size_t)eid * KNN;
    int idx[KNN];
    #pragma unroll
    for (int k = 0; k < KNN; ++k) idx[k] = nnr[k];
    float s = 0.f;
    #pragma unroll
    for (int k = 0; k < KNN; ++k)
        s += t[(size_t)idx[k] * FDIM + c];
    s *= (1.f / (float)KNN);
    #pragma unroll
    for (int k = 0; k < KNN; ++k)
        atomicAdd(&acc[(size_t)idx[k] * FDIM + c], s);
}

// ---------------------------------------------------------------------------
// node_ft[v][c] = acc[v][c]/max(Dv,1) + bias[c], leaky.
// Writes f32 (outf) or bf16 (outb) depending on which pointer is non-null.
// ---------------------------------------------------------------------------
__global__ __launch_bounds__(256) void finish_kernel(const float* __restrict__ acc,
                                                     const int* __restrict__ Dv,
                                                     const float* __restrict__ bias,
                                                     float* __restrict__ outf,
                                                     unsigned short* __restrict__ outb) {
    int v = blockIdx.x * 2 + (threadIdx.x >> 7);
    int c = threadIdx.x & 127;
    int cnt = Dv[v];
    float dn = cnt > 1 ? (float)cnt : 1.f;
    float s = acc[(size_t)v * FDIM + c] / dn + bias[c];
    s = (s >= 0.f) ? s : 0.01f * s;
    if (outb) outb[(size_t)v * FDIM + c] = f2bf(s);
    else      outf[(size_t)v * FDIM + c] = s;
}

// ---------------------------------------------------------------------------
// pooling partials + final
// ---------------------------------------------------------------------------
__global__ __launch_bounds__(256) void pool_kernel(const float* __restrict__ feats,
                                                   float* __restrict__ part) {
    int c = threadIdx.x & 127;
    int half = threadIdx.x >> 7;
    int r0 = blockIdx.x * 128 + half;
    float s = 0.f;
    for (int i = 0; i < 64; ++i)
        s += feats[(size_t)(r0 + 2 * i) * FDIM + c];
    part[(size_t)(blockIdx.x * 2 + half) * FDIM + c] = s;
}

__global__ __launch_bounds__(128) void final_kernel(const float* __restrict__ part,
                                                    const float* __restrict__ fcw,
                                                    const float* __restrict__ fcb,
                                                    float* __restrict__ out) {
    __shared__ float pool[FDIM];
    int c = threadIdx.x;
    float s = 0.f;
    for (int i = 0; i < 128; ++i)
        s += part[(size_t)i * FDIM + c];
    s *= (1.f / (float)NPTS);
    out[2 + (size_t)NPTS * FDIM + c] = s;
    pool[c] = s;
    __syncthreads();
    if (c < 2) {
        float z = fcb[c];
        for (int k = 0; k < FDIM; ++k)
            z += pool[k] * fcw[c * FDIM + k];
        out[c] = 1.f / (1.f + expf(-z));
    }
}

// ---------------------------------------------------------------------------
extern "C" void kernel_launch(void* const* d_in, const int* in_sizes, int n_in,
                              void* d_out, int out_size, void* d_ws, size_t ws_size,
                              hipStream_t stream) {
    const float* x   = (const float*)d_in[0];
    const float* th0 = (const float*)d_in[1];
    const float* b0  = (const float*)d_in[2];
    const float* th1 = (const float*)d_in[3];
    const float* b1  = (const float*)d_in[4];
    const float* fcw = (const float*)d_in[5];
    const float* fcb = (const float*)d_in[6];
    float* out = (float*)d_out;

    char* w = (char*)d_ws;
    size_t off = 0;
    auto alloc = [&](size_t bytes) -> void* {
        void* p = w + off;
        off = (off + bytes + 255) & ~(size_t)255;
        return p;
    };
    float* sq    = (float*)alloc(NPTS * 4);
    int*   nn    = (int*)  alloc(NPTS * KNN * 4);
    int*   Dv    = (int*)  alloc(NPTS * 4);
    int*   cand  = (int*)  alloc((size_t)NPTS * NCAND * 4);
    float* tbuf  = (float*)alloc((size_t)NPTS * FDIM * 4);
    float* accb  = (float*)alloc((size_t)NPTS * FDIM * 4);
    float* part  = (float*)alloc(128 * FDIM * 4);
    unsigned short* xbf   = (unsigned short*)alloc((size_t)NPTS * INCH * 2);
    unsigned short* hbufb = (unsigned short*)alloc((size_t)NPTS * FDIM * 2);
    unsigned short* th0t  = (unsigned short*)alloc((size_t)FDIM * INCH * 2);
    unsigned short* th1t  = (unsigned short*)alloc((size_t)FDIM * FDIM * 2);

    size_t rem = ws_size > off ? ws_size - off : 0;
    long long chMax = (long long)(rem / ((size_t)NPTS * 2));
    int CH = (int)(chMax > 8192 ? 8192 : chMax);
    CH &= ~127;
    if (CH < 128) CH = 128;
    _Float16* Dh = (_Float16*)(w + off);

    hipMemsetAsync(Dv, 0, NPTS * 4, stream);
    prep_kernel<<<NPTS / 4, 256, 0, stream>>>(x, sq, xbf);
    thT_kernel<<<dim3(INCH / 64, 2), 256, 0, stream>>>(th0, th0t, INCH);
    thT_kernel<<<dim3(FDIM / 64, 2), 256, 0, stream>>>(th1, th1t, FDIM);

    if (CH >= NPTS) {
        mfma_dist_kernel<true><<<NTILE * (NTILE + 1) / 2, 256, 0, stream>>>(xbf, sq, Dh, 0);
        topk16_kernel<<<NPTS / 4, 256, 0, stream>>>(Dh, cand, 0);
    } else {
        for (int r0 = 0; r0 < NPTS; r0 += CH) {
            int ch = NPTS - r0 < CH ? NPTS - r0 : CH;
            mfma_dist_kernel<false><<<dim3(NTILE, ch / 128), 256, 0, stream>>>(xbf, sq, Dh, r0);
            topk16_kernel<<<ch / 4, 256, 0, stream>>>(Dh, cand, r0);
        }
    }

    rescore_kernel<<<NPTS, 256, 0, stream>>>(x, sq, cand, nn, Dv);

    // layer 0 (bf16 MFMA gemm)
    mfma_gemm_kernel<<<NPTS / 128, 256, 0, stream>>>(xbf, th0t, tbuf, INCH, INCH / 32);
    hipMemsetAsync(accb, 0, (size_t)NPTS * FDIM * 4, stream);
    edge_scatter_kernel<<<NPTS / 2, 256, 0, stream>>>(tbuf, nn, accb);
    finish_kernel<<<NPTS / 2, 256, 0, stream>>>(accb, Dv, b0, nullptr, hbufb);

    // layer 1 -> feats written directly into out+2
    mfma_gemm_kernel<<<NPTS / 128, 256, 0, stream>>>(hbufb, th1t, tbuf, FDIM, FDIM / 32);
    hipMemsetAsync(accb, 0, (size_t)NPTS * FDIM * 4, stream);
    edge_scatter_kernel<<<NPTS / 2, 256, 0, stream>>>(tbuf, nn, accb);
    finish_kernel<<<NPTS / 2, 256, 0, stream>>>(accb, Dv, b1, out + 2, nullptr);

    pool_kernel<<<64, 256, 0, stream>>>(out + 2, part);
    final_kernel<<<1, 128, 0, stream>>>(part, fcw, fcb, out);
}

// Round 11
// 428.311 us; speedup vs baseline: 6.2000x; 1.0082x over previous
//
#include <hip/hip_runtime.h>
#include <math.h>

#define NPTS  8192
#define INCH  1024
#define FDIM  128
#define KNN   10
#define NCAND 16
#define NNS   16              // nn row stride (padded)
#define NTILE (NPTS / 128)   // 64
#define NBLK  (NTILE * (NTILE + 1) / 2)   // 2080 triangle blocks

typedef __attribute__((ext_vector_type(8))) __bf16          bf16x8;
typedef __attribute__((ext_vector_type(4))) float           f32x4;
typedef __attribute__((ext_vector_type(8))) unsigned short  us8;
typedef __attribute__((ext_vector_type(4))) unsigned short  us4;
typedef __attribute__((ext_vector_type(4))) _Float16        f16x4;

// u32 compare-exchange: a=min, b=max  (v_min_u32 + v_max_u32)
#define CE32(a,b) do { unsigned lo_ = min((a),(b)); unsigned hi_ = max((a),(b)); \
                       (a)=lo_; (b)=hi_; } while(0)

__device__ __forceinline__ unsigned short f2bf(float f) {
    unsigned u = __float_as_uint(f);
    return (unsigned short)((u + 0x7fffu + ((u >> 16) & 1u)) >> 16);
}

// async global->LDS, 16 bytes per lane (dest = wave-uniform base + lane*16)
__device__ __forceinline__ void gload16(const void* g, void* l) {
    __builtin_amdgcn_global_load_lds(
        (const __attribute__((address_space(1))) unsigned int*)g,
        (__attribute__((address_space(3))) unsigned int*)l, 16, 0, 0);
}

// ---------------------------------------------------------------------------
// prep: sq[i] = sum x[i][d]^2 (bit-identical order) AND xb = bf16(x).
// ---------------------------------------------------------------------------
__global__ __launch_bounds__(256) void prep_kernel(const float* __restrict__ x,
                                                   float* __restrict__ sq,
                                                   unsigned short* __restrict__ xb) {
    int wave = threadIdx.x >> 6;
    int lane = threadIdx.x & 63;
    int row  = blockIdx.x * 4 + wave;
    const float4* xr = (const float4*)(x + (size_t)row * INCH);
    unsigned short* xo = xb + (size_t)row * INCH;
    float s = 0.f;
    #pragma unroll
    for (int i = 0; i < 4; ++i) {
        float4 v = xr[lane + i * 64];
        s += v.x * v.x + v.y * v.y + v.z * v.z + v.w * v.w;
        us4 o; o[0] = f2bf(v.x); o[1] = f2bf(v.y); o[2] = f2bf(v.z); o[3] = f2bf(v.w);
        *(us4*)(xo + (size_t)(lane + i * 64) * 4) = o;
    }
    #pragma unroll
    for (int o = 32; o; o >>= 1) s += __shfl_xor(s, o);
    if (lane == 0) sq[row] = s;
}

// ---------------------------------------------------------------------------
// theta transpose+convert: th[K][128] f32 -> out[128][K] bf16 (64x64 LDS tiles)
// ---------------------------------------------------------------------------
__global__ __launch_bounds__(256) void thT_kernel(const float* __restrict__ th,
                                                  unsigned short* __restrict__ out,
                                                  int K) {
    __shared__ unsigned short T[64][68];
    int k0 = blockIdx.x * 64;
    int n0 = blockIdx.y * 64;
    int t = threadIdx.x;
    int r  = t >> 2;
    int cs = (t & 3) * 16;
    const float* src = th + (size_t)(k0 + r) * FDIM + n0 + cs;
    #pragma unroll
    for (int i = 0; i < 4; ++i) {
        float4 v = *(const float4*)(src + i * 4);
        us4 o; o[0] = f2bf(v.x); o[1] = f2bf(v.y); o[2] = f2bf(v.z); o[3] = f2bf(v.w);
        *(us4*)&T[r][cs + i * 4] = o;
    }
    __syncthreads();
    int n  = t >> 2;
    int ks = (t & 3) * 16;
    unsigned short* dst = out + (size_t)(n0 + n) * K + k0 + ks;
    #pragma unroll
    for (int i = 0; i < 16; ++i)
        dst[i] = T[ks + i][n];
}

// ---------------------------------------------------------------------------
// bf16 MFMA distance tile -> f16 ( max(d,0)*0.25 ) matrix.  Round-11: T1
// XCD-aware swizzle of the triangle block index (2080 % 8 == 0, bijective):
// same-XCD blocks share bx (the B col-tile) -> L2-resident B, lower fetch.
// Everything else identical to round 10 (values bit-identical).
// ---------------------------------------------------------------------------
union SharedU {
    struct { unsigned short A[2][4096], B[2][4096]; } s;   // 32 KB staging
    _Float16 T[128 * 136];                                  // 34.8 KB transpose
};

template <bool SYM>
__global__ __launch_bounds__(256) void mfma_dist_kernel(const unsigned short* __restrict__ xb,
                                                        const float* __restrict__ sq,
                                                        _Float16* __restrict__ Dh,
                                                        int r0) {
    __shared__ SharedU smem;
    int bx, byy;
    if (SYM) {
        int b = blockIdx.x;
        int t = (b & 7) * (NBLK / 8) + (b >> 3);   // XCD swizzle (T1)
        bx = (int)((sqrtf(8.0f * (float)t + 1.0f) - 1.0f) * 0.5f);
        while ((bx + 1) * (bx + 2) / 2 <= t) ++bx;
        while (bx * (bx + 1) / 2 > t) --bx;
        byy = t - bx * (bx + 1) / 2;          // byy <= bx
    } else {
        bx = blockIdx.x; byy = blockIdx.y;
    }
    int tid  = threadIdx.x;
    int lane = tid & 63;
    int w    = tid >> 6;
    int rowBase = r0 + byy * 128;
    int colBase = bx * 128;
    int wrow = (w >> 1) * 64, wcol = (w & 1) * 64;

    f32x4 acc[4][4];
    #pragma unroll
    for (int m = 0; m < 4; ++m)
        #pragma unroll
        for (int n = 0; n < 4; ++n)
            acc[m][n] = (f32x4){0.f, 0.f, 0.f, 0.f};

    int s0 = w * 128 + lane;
    int s1 = s0 + 64;
    int r0s = s0 >> 2, g0s = s0 & 3, d0s = (g0s - (r0s >> 1)) & 3;
    int r1s = s1 >> 2, g1s = s1 & 3, d1s = (g1s - (r1s >> 1)) & 3;
    const unsigned short* gA0 = xb + (size_t)(rowBase + r0s) * INCH + d0s * 8;
    const unsigned short* gA1 = xb + (size_t)(rowBase + r1s) * INCH + d1s * 8;
    const unsigned short* gB0 = xb + (size_t)(colBase + r0s) * INCH + d0s * 8;
    const unsigned short* gB1 = xb + (size_t)(colBase + r1s) * INCH + d1s * 8;
    int ldsc0 = w * 1024;
    int ldsc1 = w * 1024 + 512;

    int kg = lane >> 4;
    int arq = lane & 15;

    gload16(gA0, &smem.s.A[0][ldsc0]); gload16(gA1, &smem.s.A[0][ldsc1]);
    gload16(gB0, &smem.s.B[0][ldsc0]); gload16(gB1, &smem.s.B[0][ldsc1]);
    __syncthreads();

    #pragma unroll 2
    for (int t = 0; t < 32; ++t) {
        int cur = t & 1;
        if (t < 31) {
            int k0 = (t + 1) * 32;
            gload16(gA0 + k0, &smem.s.A[cur ^ 1][ldsc0]);
            gload16(gA1 + k0, &smem.s.A[cur ^ 1][ldsc1]);
            gload16(gB0 + k0, &smem.s.B[cur ^ 1][ldsc0]);
            gload16(gB1 + k0, &smem.s.B[cur ^ 1][ldsc1]);
        }
        bf16x8 af[4], bfr[4];
        #pragma unroll
        for (int m = 0; m < 4; ++m) {
            int ar = wrow + m * 16 + arq;
            int gp = (kg + (ar >> 1)) & 3;
            af[m] = __builtin_bit_cast(bf16x8, *(const uint4*)&smem.s.A[cur][ar * 32 + gp * 8]);
        }
        #pragma unroll
        for (int n = 0; n < 4; ++n) {
            int br = wcol + n * 16 + arq;
            int gp = (kg + (br >> 1)) & 3;
            bfr[n] = __builtin_bit_cast(bf16x8, *(const uint4*)&smem.s.B[cur][br * 32 + gp * 8]);
        }
        #pragma unroll
        for (int m = 0; m < 4; ++m)
            #pragma unroll
            for (int n = 0; n < 4; ++n)
                acc[m][n] = __builtin_amdgcn_mfma_f32_16x16x32_bf16(af[m], bfr[n],
                                                                    acc[m][n], 0, 0, 0);
        __syncthreads();
    }

    int rg = lane >> 4;
    bool doT = SYM && (byy != bx);
    #pragma unroll
    for (int m = 0; m < 4; ++m) {
        int rloc = wrow + m * 16 + rg * 4;
        int rl = byy * 128 + rloc;
        float sa0 = sq[r0 + rl + 0], sa1 = sq[r0 + rl + 1];
        float sa2 = sq[r0 + rl + 2], sa3 = sq[r0 + rl + 3];
        #pragma unroll
        for (int n = 0; n < 4; ++n) {
            int cl = wcol + n * 16 + (lane & 15);
            int c = colBase + cl;
            float sb = sq[c];
            _Float16 h0 = (_Float16)fmaxf((sa0 + sb - 2.f * acc[m][n][0]) * 0.25f, 0.f);
            _Float16 h1 = (_Float16)fmaxf((sa1 + sb - 2.f * acc[m][n][1]) * 0.25f, 0.f);
            _Float16 h2 = (_Float16)fmaxf((sa2 + sb - 2.f * acc[m][n][2]) * 0.25f, 0.f);
            _Float16 h3 = (_Float16)fmaxf((sa3 + sb - 2.f * acc[m][n][3]) * 0.25f, 0.f);
            _Float16* dp = Dh + (size_t)rl * NPTS + c;
            dp[0 * NPTS] = h0;
            dp[1 * NPTS] = h1;
            dp[2 * NPTS] = h2;
            dp[3 * NPTS] = h3;
            if (doT) {
                f16x4 tv; tv[0] = h0; tv[1] = h1; tv[2] = h2; tv[3] = h3;
                *(f16x4*)&smem.T[cl * 136 + rloc] = tv;
            }
        }
    }
    if (doT) {
        __syncthreads();
        int cl = tid >> 1, half = tid & 1;
        const unsigned short* src = (const unsigned short*)&smem.T[cl * 136 + half * 64];
        unsigned short* gdst = (unsigned short*)Dh +
                               (size_t)(colBase + cl) * NPTS + byy * 128 + half * 64;
        #pragma unroll
        for (int i = 0; i < 8; ++i)
            *(uint4*)(gdst + i * 8) = *(const uint4*)(src + i * 8);
    }
}

// ---------------------------------------------------------------------------
// Per row: exact top-16 (on f16 keys) candidate indices.
// One WAVE per row, zero barriers. All stored f16 >= 0 -> raw bits sortable.
// ---------------------------------------------------------------------------
__global__ __launch_bounds__(256) void topk16_kernel(const _Float16* __restrict__ Dh,
                                                     int* __restrict__ cand, int r0) {
    int wid  = threadIdx.x >> 6;
    int lane = threadIdx.x & 63;
    int row  = blockIdx.x * 4 + wid;
    const unsigned short* dr = (const unsigned short*)(Dh + (size_t)row * NPTS);

    unsigned kv[16];
    #pragma unroll
    for (int p = 0; p < 16; ++p) kv[p] = 0xffffffffu;

    for (int g = 0; g < 16; ++g) {
        int j0 = (g * 64 + lane) * 8;
        us8 v = *(const us8*)(dr + j0);
        unsigned s[8];
        #pragma unroll
        for (int e = 0; e < 8; ++e)
            s[e] = ((unsigned)v[e] << 13) | (unsigned)(j0 + e);
        CE32(s[0],s[1]); CE32(s[2],s[3]); CE32(s[4],s[5]); CE32(s[6],s[7]);
        CE32(s[0],s[2]); CE32(s[1],s[3]); CE32(s[4],s[6]); CE32(s[5],s[7]);
        CE32(s[1],s[2]); CE32(s[5],s[6]);
        CE32(s[0],s[4]); CE32(s[1],s[5]); CE32(s[2],s[6]); CE32(s[3],s[7]);
        CE32(s[2],s[4]); CE32(s[3],s[5]);
        CE32(s[1],s[2]); CE32(s[3],s[4]); CE32(s[5],s[6]);

        if (s[0] < kv[15]) {
            unsigned M[16];
            #pragma unroll
            for (int q = 0; q < 8; ++q) M[q] = kv[q];
            #pragma unroll
            for (int q = 8; q < 16; ++q) M[q] = min(kv[q], s[15 - q]);
            #pragma unroll
            for (int d = 8; d; d >>= 1)
                #pragma unroll
                for (int q = 0; q < 16; ++q)
                    if (!(q & d)) CE32(M[q], M[q + d]);
            #pragma unroll
            for (int q = 0; q < 16; ++q) kv[q] = M[q];
        }
    }

    #pragma unroll
    for (int st = 0; st < 6; ++st) {
        unsigned M[16];
        #pragma unroll
        for (int q = 0; q < 16; ++q) {
            unsigned pv = (unsigned)__shfl_xor((int)kv[15 - q], 1 << st);
            M[q] = min(kv[q], pv);
        }
        #pragma unroll
        for (int d = 8; d; d >>= 1)
            #pragma unroll
            for (int q = 0; q < 16; ++q)
                if (!(q & d)) CE32(M[q], M[q + d]);
        #pragma unroll
        for (int q = 0; q < 16; ++q) kv[q] = M[q];
    }

    if (lane == 0) {
        #pragma unroll
        for (int r = 0; r < 16; ++r)
            cand[(size_t)(r0 + row) * NCAND + r] = (int)(kv[r] & 0x1fffu);
    }
}

// ---------------------------------------------------------------------------
// Exact fp32 rescore, round-11: all 16 candidates in parallel (16 lanes each),
// x-row staged once in LDS, coalesced candidate reads (lane q reads chunk
// i*16+q -> 256B contiguous per step).  fp32 dot; ordering/tie-break keys
// unchanged -> same selection.  Also emits Dv counts and nn (stride NNS).
// ---------------------------------------------------------------------------
__global__ __launch_bounds__(256) void rescore_kernel(const float* __restrict__ x,
                                                      const float* __restrict__ sq,
                                                      const int* __restrict__ cand,
                                                      int* __restrict__ nn,
                                                      int* __restrict__ Dv) {
    __shared__ float xs[INCH];
    __shared__ unsigned long long keys[NCAND];
    int row = blockIdx.x;
    int tid = threadIdx.x;

    *(float4*)&xs[tid * 4] = *(const float4*)(x + (size_t)row * INCH + tid * 4);
    __syncthreads();

    int grp = tid >> 4;          // candidate id 0..15
    int q   = tid & 15;
    int cnd = cand[(size_t)row * NCAND + grp];
    const float4* cp = (const float4*)(x + (size_t)cnd * INCH);
    float dp = 0.f;
    #pragma unroll
    for (int i = 0; i < 16; ++i) {
        int idx = i * 16 + q;        // float4 chunk
        float4 a = *(const float4*)&xs[idx * 4];
        float4 b = cp[idx];
        dp += a.x * b.x + a.y * b.y + a.z * b.z + a.w * b.w;
    }
    #pragma unroll
    for (int o = 8; o; o >>= 1) dp += __shfl_xor(dp, o);   // within 16-lane group
    if (q == 0) {
        float d = sq[row] + sq[cnd] - 2.f * dp;
        unsigned u = __float_as_uint(d);
        u = (u & 0x80000000u) ? ~u : (u | 0x80000000u);
        keys[grp] = ((unsigned long long)u << 32) | (unsigned)cnd;
    }
    __syncthreads();

    if (tid < 64) {
        int lane = tid;
        unsigned long long v = (lane < NCAND) ? keys[lane] : ~0ull;
        #pragma unroll
        for (int k = 2; k <= 64; k <<= 1) {
            #pragma unroll
            for (int j = k >> 1; j > 0; j >>= 1) {
                unsigned long long pv = __shfl_xor(v, j);
                bool lower = (lane & j) == 0;
                bool asc   = (lane & k) == 0;
                unsigned long long mn = v < pv ? v : pv;
                unsigned long long mx = v < pv ? pv : v;
                v = (lower == asc) ? mn : mx;
            }
        }
        if (lane < KNN) {
            int idx = (int)(v & 0xffffffffu);
            nn[(size_t)row * NNS + lane] = idx;
            atomicAdd(&Dv[idx], 1);
        }
    }
}

// ---------------------------------------------------------------------------
// bf16 MFMA GEMM:  C[M x 128] = A[M x KD] @ Bt[128 x KD]^T
// ---------------------------------------------------------------------------
__global__ __launch_bounds__(256) void mfma_gemm_kernel(const unsigned short* __restrict__ A,
                                                        const unsigned short* __restrict__ Bt,
                                                        float* __restrict__ C,
                                                        int KD, int nk) {
    __shared__ unsigned short Asm[2][4096];
    __shared__ unsigned short Bsm[2][4096];
    int tid  = threadIdx.x;
    int lane = tid & 63;
    int w    = tid >> 6;
    int rowBase = blockIdx.x * 128;
    int wrow = (w >> 1) * 64, wcol = (w & 1) * 64;

    f32x4 acc[4][4];
    #pragma unroll
    for (int m = 0; m < 4; ++m)
        #pragma unroll
        for (int n = 0; n < 4; ++n)
            acc[m][n] = (f32x4){0.f, 0.f, 0.f, 0.f};

    int s0 = w * 128 + lane;
    int s1 = s0 + 64;
    int r0s = s0 >> 2, g0s = s0 & 3, d0s = (g0s - (r0s >> 1)) & 3;
    int r1s = s1 >> 2, g1s = s1 & 3, d1s = (g1s - (r1s >> 1)) & 3;
    const unsigned short* gA0 = A + (size_t)(rowBase + r0s) * KD + d0s * 8;
    const unsigned short* gA1 = A + (size_t)(rowBase + r1s) * KD + d1s * 8;
    const unsigned short* gB0 = Bt + (size_t)r0s * KD + d0s * 8;
    const unsigned short* gB1 = Bt + (size_t)r1s * KD + d1s * 8;
    int ldsc0 = w * 1024;
    int ldsc1 = w * 1024 + 512;

    int kg = lane >> 4;
    int arq = lane & 15;

    gload16(gA0, &Asm[0][ldsc0]); gload16(gA1, &Asm[0][ldsc1]);
    gload16(gB0, &Bsm[0][ldsc0]); gload16(gB1, &Bsm[0][ldsc1]);
    __syncthreads();

    for (int t = 0; t < nk; ++t) {
        int cur = t & 1;
        if (t < nk - 1) {
            int k0 = (t + 1) * 32;
            gload16(gA0 + k0, &Asm[cur ^ 1][ldsc0]);
            gload16(gA1 + k0, &Asm[cur ^ 1][ldsc1]);
            gload16(gB0 + k0, &Bsm[cur ^ 1][ldsc0]);
            gload16(gB1 + k0, &Bsm[cur ^ 1][ldsc1]);
        }
        bf16x8 af[4], bfr[4];
        #pragma unroll
        for (int m = 0; m < 4; ++m) {
            int ar = wrow + m * 16 + arq;
            int gp = (kg + (ar >> 1)) & 3;
            af[m] = __builtin_bit_cast(bf16x8, *(const uint4*)&Asm[cur][ar * 32 + gp * 8]);
        }
        #pragma unroll
        for (int n = 0; n < 4; ++n) {
            int br = wcol + n * 16 + arq;
            int gp = (kg + (br >> 1)) & 3;
            bfr[n] = __builtin_bit_cast(bf16x8, *(const uint4*)&Bsm[cur][br * 32 + gp * 8]);
        }
        #pragma unroll
        for (int m = 0; m < 4; ++m)
            #pragma unroll
            for (int n = 0; n < 4; ++n)
                acc[m][n] = __builtin_amdgcn_mfma_f32_16x16x32_bf16(af[m], bfr[n],
                                                                    acc[m][n], 0, 0, 0);
        __syncthreads();
    }

    int rg = lane >> 4;
    #pragma unroll
    for (int m = 0; m < 4; ++m) {
        int rl = rowBase + wrow + m * 16 + rg * 4;
        #pragma unroll
        for (int n = 0; n < 4; ++n) {
            int c = wcol + n * 16 + (lane & 15);
            float* cp = C + (size_t)rl * FDIM + c;
            cp[0 * FDIM] = acc[m][n][0];
            cp[1 * FDIM] = acc[m][n][1];
            cp[2 * FDIM] = acc[m][n][2];
            cp[3 * FDIM] = acc[m][n][3];
        }
    }
}

// ---------------------------------------------------------------------------
// Fused edge mean + scatter  (nn stride NNS, aligned)
// ---------------------------------------------------------------------------
__global__ __launch_bounds__(256) void edge_scatter_kernel(const float* __restrict__ t,
                                                           const int* __restrict__ nn,
                                                           float* __restrict__ acc) {
    int eid = blockIdx.x * 2 + (threadIdx.x >> 7);
    int c = threadIdx.x & 127;
    const int* nnr = nn + (size_t)eid * NNS;
    int idx[KNN];
    #pragma unroll
    for (int k = 0; k < KNN; ++k) idx[k] = nnr[k];
    float s = 0.f;
    #pragma unroll
    for (int k = 0; k < KNN; ++k)
        s += t[(size_t)idx[k] * FDIM + c];
    s *= (1.f / (float)KNN);
    #pragma unroll
    for (int k = 0; k < KNN; ++k)
        atomicAdd(&acc[(size_t)idx[k] * FDIM + c], s);
}

// ---------------------------------------------------------------------------
// layer-0 finish: node_ft -> bf16, and ZEROES acc for the next scatter
// ---------------------------------------------------------------------------
__global__ __launch_bounds__(256) void finish_kernel(float* __restrict__ acc,
                                                     const int* __restrict__ Dv,
                                                     const float* __restrict__ bias,
                                                     unsigned short* __restrict__ outb) {
    int v = blockIdx.x * 2 + (threadIdx.x >> 7);
    int c = threadIdx.x & 127;
    int cnt = Dv[v];
    float dn = cnt > 1 ? (float)cnt : 1.f;
    size_t o = (size_t)v * FDIM + c;
    float s = acc[o] / dn + bias[c];
    acc[o] = 0.f;                       // reset for layer-1 scatter
    s = (s >= 0.f) ? s : 0.01f * s;
    outb[o] = f2bf(s);
}

// ---------------------------------------------------------------------------
// layer-1 finish fused with pooling partials: 64 blocks x 128 rows.
// Partial-sum order matches the old pool_kernel exactly (rows half+2i).
// ---------------------------------------------------------------------------
__global__ __launch_bounds__(256) void finish_pool_kernel(const float* __restrict__ acc,
                                                          const int* __restrict__ Dv,
                                                          const float* __restrict__ bias,
                                                          float* __restrict__ out,
                                                          float* __restrict__ part) {
    int c = threadIdx.x & 127;
    int half = threadIdx.x >> 7;
    int r0 = blockIdx.x * 128 + half;
    float b = bias[c];
    float ps = 0.f;
    for (int i = 0; i < 64; ++i) {
        int v = r0 + 2 * i;
        int cnt = Dv[v];
        float dn = cnt > 1 ? (float)cnt : 1.f;
        float s = acc[(size_t)v * FDIM + c] / dn + b;
        s = (s >= 0.f) ? s : 0.01f * s;
        out[(size_t)v * FDIM + c] = s;
        ps += s;
    }
    part[(size_t)(blockIdx.x * 2 + half) * FDIM + c] = ps;
}

__global__ __launch_bounds__(128) void final_kernel(const float* __restrict__ part,
                                                    const float* __restrict__ fcw,
                                                    const float* __restrict__ fcb,
                                                    float* __restrict__ out) {
    __shared__ float pool[FDIM];
    int c = threadIdx.x;
    float s = 0.f;
    for (int i = 0; i < 128; ++i)
        s += part[(size_t)i * FDIM + c];
    s *= (1.f / (float)NPTS);
    out[2 + (size_t)NPTS * FDIM + c] = s;
    pool[c] = s;
    __syncthreads();
    if (c < 2) {
        float z = fcb[c];
        for (int k = 0; k < FDIM; ++k)
            z += pool[k] * fcw[c * FDIM + k];
        out[c] = 1.f / (1.f + expf(-z));
    }
}

// ---------------------------------------------------------------------------
extern "C" void kernel_launch(void* const* d_in, const int* in_sizes, int n_in,
                              void* d_out, int out_size, void* d_ws, size_t ws_size,
                              hipStream_t stream) {
    const float* x   = (const float*)d_in[0];
    const float* th0 = (const float*)d_in[1];
    const float* b0  = (const float*)d_in[2];
    const float* th1 = (const float*)d_in[3];
    const float* b1  = (const float*)d_in[4];
    const float* fcw = (const float*)d_in[5];
    const float* fcb = (const float*)d_in[6];
    float* out = (float*)d_out;

    char* w = (char*)d_ws;
    size_t off = 0;
    auto alloc = [&](size_t bytes) -> void* {
        void* p = w + off;
        off = (off + bytes + 255) & ~(size_t)255;
        return p;
    };
    float* sq    = (float*)alloc(NPTS * 4);
    int*   nn    = (int*)  alloc(NPTS * NNS * 4);
    int*   Dv    = (int*)  alloc(NPTS * 4);
    int*   cand  = (int*)  alloc((size_t)NPTS * NCAND * 4);
    float* tbuf  = (float*)alloc((size_t)NPTS * FDIM * 4);
    float* accb  = (float*)alloc((size_t)NPTS * FDIM * 4);
    float* part  = (float*)alloc(128 * FDIM * 4);
    unsigned short* xbf   = (unsigned short*)alloc((size_t)NPTS * INCH * 2);
    unsigned short* hbufb = (unsigned short*)alloc((size_t)NPTS * FDIM * 2);
    unsigned short* th0t  = (unsigned short*)alloc((size_t)FDIM * INCH * 2);
    unsigned short* th1t  = (unsigned short*)alloc((size_t)FDIM * FDIM * 2);

    size_t rem = ws_size > off ? ws_size - off : 0;
    long long chMax = (long long)(rem / ((size_t)NPTS * 2));
    int CH = (int)(chMax > 8192 ? 8192 : chMax);
    CH &= ~127;
    if (CH < 128) CH = 128;
    _Float16* Dh = (_Float16*)(w + off);

    hipMemsetAsync(Dv, 0, NPTS * 4, stream);
    prep_kernel<<<NPTS / 4, 256, 0, stream>>>(x, sq, xbf);
    thT_kernel<<<dim3(INCH / 64, 2), 256, 0, stream>>>(th0, th0t, INCH);
    thT_kernel<<<dim3(FDIM / 64, 2), 256, 0, stream>>>(th1, th1t, FDIM);

    if (CH >= NPTS) {
        mfma_dist_kernel<true><<<NBLK, 256, 0, stream>>>(xbf, sq, Dh, 0);
        topk16_kernel<<<NPTS / 4, 256, 0, stream>>>(Dh, cand, 0);
    } else {
        for (int r0 = 0; r0 < NPTS; r0 += CH) {
            int ch = NPTS - r0 < CH ? NPTS - r0 : CH;
            mfma_dist_kernel<false><<<dim3(NTILE, ch / 128), 256, 0, stream>>>(xbf, sq, Dh, r0);
            topk16_kernel<<<ch / 4, 256, 0, stream>>>(Dh, cand, r0);
        }
    }

    rescore_kernel<<<NPTS, 256, 0, stream>>>(x, sq, cand, nn, Dv);

    // layer 0 (bf16 MFMA gemm)
    mfma_gemm_kernel<<<NPTS / 128, 256, 0, stream>>>(xbf, th0t, tbuf, INCH, INCH / 32);
    hipMemsetAsync(accb, 0, (size_t)NPTS * FDIM * 4, stream);
    edge_scatter_kernel<<<NPTS / 2, 256, 0, stream>>>(tbuf, nn, accb);
    finish_kernel<<<NPTS / 2, 256, 0, stream>>>(accb, Dv, b0, hbufb);

    // layer 1 -> feats into out+2, pooling partials fused
    mfma_gemm_kernel<<<NPTS / 128, 256, 0, stream>>>(hbufb, th1t, tbuf, FDIM, FDIM / 32);
    edge_scatter_kernel<<<NPTS / 2, 256, 0, stream>>>(tbuf, nn, accb);
    finish_pool_kernel<<<64, 256, 0, stream>>>(accb, Dv, b1, out + 2, part);

    final_kernel<<<1, 128, 0, stream>>>(part, fcw, fcb, out);
}